// Round 2
// baseline (31464.444 us; speedup 1.0000x reference)
//
#include <hip/hip_runtime.h>

#define NBLK 256
#define NTHR 512
#define BB 64
#define TT 200
#define SS 1024
#define DD 512
#define VV 30
#define BBDD (BB*DD)          // 32768
#define CPN  (BB*3*DD)        // cpart per parity: 98304
#define MLN  (BB*3*2)         // ml per parity: 384

// ---- workspace layout (float offsets) ----
// uint slots first: gslot[257*16] (incl gflag at slot 256), wslot[65*16] (incl wflag)
#define WS_SLOTS_UINTS (257*16 + 65*16)     // 5152
#define WS_H0  5152
#define WS_H1  (WS_H0 + 2*BBDD)             // 70688
#define WS_CB  (WS_H1 + 2*BBDD)             // 136224
#define WS_CP  (WS_CB + BBDD)               // 168992
#define WS_ML  (WS_CP + 2*CPN)              // 365600
// total 366368 floats (~1.47 MB)

__device__ __forceinline__ float dot4(float4 a, float4 b) {
  return a.x*b.x + a.y*b.y + a.z*b.z + a.w*b.w;
}
__device__ __forceinline__ float sigmoidf_(float x) { return 1.f/(1.f + __expf(-x)); }
__device__ __forceinline__ int minI(int a, int b) { return a < b ? a : b; }

// async global->LDS, 16B per lane. LDS dest = uniform base + lane*16.
__device__ __forceinline__ void gl_lds16(const float* g, float* l) {
  __builtin_amdgcn_global_load_lds(
      (const __attribute__((address_space(1))) unsigned int*)(const void*)g,
      (__attribute__((address_space(3))) unsigned int*)(void*)l,
      16, 0, 0);
}

// stage [64][512] row-major global into LDS [64][516] (padded rows)
__device__ __forceinline__ void stage64(const float* src, float* TILE, int wv, int lane) {
  #pragma unroll
  for (int rr = 0; rr < 8; ++rr) {
    const int row = wv*8 + rr;
    const float* g = src + (size_t)row*DD + lane*4;
    gl_lds16(g,       TILE + row*516);
    gl_lds16(g + 256, TILE + row*516 + 256);
  }
}

// stage up to 32 rows x 512 into linear LDS [32][512]
__device__ __forceinline__ void stage_att(float* dst, const float* src, int R, int wv, int lane) {
  #pragma unroll
  for (int rr = 0; rr < 4; ++rr) {
    const int row = wv*4 + rr;
    if (row < R) {
      const float* g = src + (size_t)row*DD + lane*4;
      gl_lds16(g,       dst + row*DD);
      gl_lds16(g + 256, dst + row*DD + 256);
    }
  }
}

// wave-column GRU dot: wave wv computes 3 gate-columns; TILE is [64][516] h.
__device__ __forceinline__ void wave_dots(const float* TILE, const float* W, const float* bias,
                                          float* GH, int w_id, int wv, int lane) {
  const int c0 = wv*3, c1 = c0+1, c2 = c0+2;
  const int R0 = __builtin_amdgcn_readfirstlane(((c0>>3)<<9) + w_id*8 + (c0&7));
  const int R1 = __builtin_amdgcn_readfirstlane(((c1>>3)<<9) + w_id*8 + (c1&7));
  const int R2 = __builtin_amdgcn_readfirstlane(((c2>>3)<<9) + w_id*8 + (c2&7));
  const float4* w0 = (const float4*)(W + (size_t)R0*DD);
  const float4* w1 = (const float4*)(W + (size_t)R1*DD);
  const float4* w2 = (const float4*)(W + (size_t)R2*DD);
  const float4* hv4 = (const float4*)TILE + (size_t)lane*129;
  float a0=0.f, a1=0.f, a2=0.f;
  #pragma unroll 4
  for (int kq = 0; kq < 128; ++kq) {
    float4 h = hv4[kq];
    a0 += dot4(h, w0[kq]); a1 += dot4(h, w1[kq]); a2 += dot4(h, w2[kq]);
  }
  GH[c0*64 + lane] = a0 + bias[R0];
  GH[c1*64 + lane] = a1 + bias[R1];
  GH[c2*64 + lane] = a2 + bias[R2];
}

// grid barrier: per-block flag store (no RMW), block 0 aggregates, flag broadcast.
__device__ __forceinline__ void gridbar(unsigned* gslot, unsigned* gflag,
                                        int bid, int tid, unsigned target) {
  __syncthreads();
  if (tid == 0) {
    __threadfence();
    __hip_atomic_store(&gslot[bid*16], target, __ATOMIC_RELAXED, __HIP_MEMORY_SCOPE_AGENT);
  }
  if (bid == 0) {
    if (tid < 64) {
      for (;;) {
        unsigned v0 = __hip_atomic_load(&gslot[(tid      )*16], __ATOMIC_RELAXED, __HIP_MEMORY_SCOPE_AGENT);
        unsigned v1 = __hip_atomic_load(&gslot[(tid +  64)*16], __ATOMIC_RELAXED, __HIP_MEMORY_SCOPE_AGENT);
        unsigned v2 = __hip_atomic_load(&gslot[(tid + 128)*16], __ATOMIC_RELAXED, __HIP_MEMORY_SCOPE_AGENT);
        unsigned v3 = __hip_atomic_load(&gslot[(tid + 192)*16], __ATOMIC_RELAXED, __HIP_MEMORY_SCOPE_AGENT);
        if (__all(v0 >= target && v1 >= target && v2 >= target && v3 >= target)) break;
        __builtin_amdgcn_s_sleep(2);
      }
      if (tid == 0)
        __hip_atomic_store(gflag, target, __ATOMIC_RELAXED, __HIP_MEMORY_SCOPE_AGENT);
    }
  } else if (tid == 0) {
    while (__hip_atomic_load(gflag, __ATOMIC_RELAXED, __HIP_MEMORY_SCOPE_AGENT) < target)
      __builtin_amdgcn_s_sleep(2);
  }
  if (tid == 0) __threadfence();
  __syncthreads();
}

// 64-worker barrier (blocks 192..255), same scheme, aggregator bid==192.
__device__ __forceinline__ void groupbar(unsigned* wslot, unsigned* wflag,
                                         int bid, int tid, unsigned target) {
  __syncthreads();
  if (tid == 0) {
    __threadfence();
    __hip_atomic_store(&wslot[(bid-192)*16], target, __ATOMIC_RELAXED, __HIP_MEMORY_SCOPE_AGENT);
  }
  if (bid == 192) {
    if (tid < 64) {
      for (;;) {
        unsigned v = __hip_atomic_load(&wslot[tid*16], __ATOMIC_RELAXED, __HIP_MEMORY_SCOPE_AGENT);
        if (__all(v >= target)) break;
        __builtin_amdgcn_s_sleep(2);
      }
      if (tid == 0)
        __hip_atomic_store(wflag, target, __ATOMIC_RELAXED, __HIP_MEMORY_SCOPE_AGENT);
    }
  } else if (tid == 0) {
    while (__hip_atomic_load(wflag, __ATOMIC_RELAXED, __HIP_MEMORY_SCOPE_AGENT) < target)
      __builtin_amdgcn_s_sleep(2);
  }
  if (tid == 0) __threadfence();
  __syncthreads();
}

__launch_bounds__(NTHR, 1)
__global__ void speller_kernel(const float* __restrict__ h_init,
                               const int*   __restrict__ targets,
                               const float* __restrict__ mem,
                               const float* __restrict__ W_ih0,
                               const float* __restrict__ W_hh0,
                               const float* __restrict__ b_ih0,
                               const float* __restrict__ b_hh0,
                               const float* __restrict__ W_ih1,
                               const float* __restrict__ W_hh1,
                               const float* __restrict__ b_ih1,
                               const float* __restrict__ b_hh1,
                               const float* __restrict__ W_out,
                               const float* __restrict__ W_tok,
                               const float* __restrict__ b_tok,
                               float*       __restrict__ out,
                               float*       __restrict__ ws)
{
  // LDS union: attention: AT[2][32*512]=32768, CP[8*512]=4096, ML2[16]
  //            worker:    TILE[64*516]=33024, GH1[1536], GHX[1536], AH[512], TOK[64]
  __shared__ float SM[36896];
  float* const GH1 = SM + 33024;
  float* const GHX = SM + 34560;
  float* const AH  = SM + 36096;
  int*   const TOK = (int*)(SM + 36608);
  float* const CP  = SM + 32768;
  float* const ML2 = SM + 36864;

  const int tid  = threadIdx.x;
  const int bid  = blockIdx.x;
  const int lane = tid & 63;
  const int wv   = tid >> 6;

  unsigned* const gslot = (unsigned*)ws;
  unsigned* const gflag = gslot + 256*16;
  unsigned* const wslot = gslot + 257*16;
  unsigned* const wflag = wslot + 64*16;

  float* const h0b   = ws + WS_H0;
  float* const h1b   = ws + WS_H1;
  float* const cb    = ws + WS_CB;
  float* const cpart = ws + WS_CP;
  float* const mlp   = ws + WS_ML;

  // zero LDS once (guards NaN garbage in unstaged partial-tile rows)
  for (int i = tid; i < 36896; i += NTHR) SM[i] = 0.f;
  __syncthreads();

  for (int t = -1; t <= TT; ++t) {
    if (bid < 192) {
      // ================= ATTENTION BLOCKS =================
      if (t >= 0 && t < TT) {
        const int b  = bid / 3;
        const int ch = bid - 3*b;
        const int r0 = (ch == 0) ? 0 : 342 + (ch-1)*341;
        const int CNT = (ch == 0) ? 342 : 341;
        const int NTL = (CNT + 31) >> 5;
        const float* msrc = mem + ((size_t)b*SS + r0)*DD;
        const int qpar = t & 1;
        const int seg = lane & 15;
        const int rr4 = lane >> 4;
        const float* qsrc = h1b + (size_t)qpar*BBDD + (size_t)b*DD;
        float4 q4[8];
        #pragma unroll
        for (int jj = 0; jj < 8; ++jj) q4[jj] = *(const float4*)&qsrc[(seg + 16*jj)*4];

        float m_run = -3e38f, l_run = 0.f;
        float cacc[8];
        #pragma unroll
        for (int j = 0; j < 8; ++j) cacc[j] = 0.f;

        int buf = 0;
        stage_att(SM, msrc, minI(32, CNT), wv, lane);
        __syncthreads();

        for (int tl = 0; tl < NTL; ++tl) {
          const int Rcur = minI(32, CNT - tl*32);
          if (tl + 1 < NTL)
            stage_att(SM + (buf^1)*16384, msrc + (size_t)(tl+1)*32*DD,
                      minI(32, CNT - (tl+1)*32), wv, lane);
          const float* bbuf = SM + buf*16384;
          const int r = wv*4 + rr4;
          float sc = 0.f;
          if (r < Rcur) {
            const float4* rb = (const float4*)(bbuf + (size_t)r*DD);
            #pragma unroll
            for (int jj = 0; jj < 8; ++jj) sc += dot4(rb[seg + 16*jj], q4[jj]);
          }
          sc += __shfl_xor(sc, 1);
          sc += __shfl_xor(sc, 2);
          sc += __shfl_xor(sc, 4);
          sc += __shfl_xor(sc, 8);
          const int rb0 = wv*4;
          float s0 = __shfl(sc, 0), s1 = __shfl(sc, 16), s2 = __shfl(sc, 32), s3 = __shfl(sc, 48);
          float sv0 = (rb0+0 < Rcur) ? s0 : -3e38f;
          float sv1 = (rb0+1 < Rcur) ? s1 : -3e38f;
          float sv2 = (rb0+2 < Rcur) ? s2 : -3e38f;
          float sv3 = (rb0+3 < Rcur) ? s3 : -3e38f;
          float m_tile = fmaxf(fmaxf(sv0, sv1), fmaxf(sv2, sv3));
          float m_new  = fmaxf(m_run, m_tile);
          float esc    = __expf(m_run - m_new);
          float w0 = (rb0+0 < Rcur) ? __expf(s0 - m_new) : 0.f;
          float w1 = (rb0+1 < Rcur) ? __expf(s1 - m_new) : 0.f;
          float w2 = (rb0+2 < Rcur) ? __expf(s2 - m_new) : 0.f;
          float w3 = (rb0+3 < Rcur) ? __expf(s3 - m_new) : 0.f;
          l_run = l_run*esc + (w0 + w1) + (w2 + w3);
          m_run = m_new;
          #pragma unroll
          for (int j = 0; j < 8; ++j) {
            const int kk = j*64 + lane;
            float a = cacc[j]*esc;
            a += w0*bbuf[(rb0+0)*DD + kk];
            a += w1*bbuf[(rb0+1)*DD + kk];
            a += w2*bbuf[(rb0+2)*DD + kk];
            a += w3*bbuf[(rb0+3)*DD + kk];
            cacc[j] = a;
          }
          __syncthreads();
          buf ^= 1;
        }
        // merge 8 per-wave partials
        #pragma unroll
        for (int j = 0; j < 8; ++j) CP[wv*DD + j*64 + lane] = cacc[j];
        if (lane == 0) { ML2[wv*2] = m_run; ML2[wv*2+1] = l_run; }
        __syncthreads();
        float M = -3e38f;
        #pragma unroll
        for (int w = 0; w < 8; ++w) M = fmaxf(M, ML2[w*2]);
        float lsum = 0.f, ck = 0.f;
        #pragma unroll
        for (int w = 0; w < 8; ++w) {
          float ew = __expf(ML2[w*2] - M);
          lsum += ew*ML2[w*2+1];
          ck   += ew*CP[w*DD + tid];
        }
        const int par = t & 1;
        cpart[(size_t)par*CPN + ((size_t)(b*3+ch))*DD + tid] = ck;
        if (tid == 0) {
          mlp[par*MLN + (b*3+ch)*2]     = M;
          mlp[par*MLN + (b*3+ch)*2 + 1] = lsum;
        }
        __syncthreads();
      }
      gridbar(gslot, gflag, bid, tid, (unsigned)(t + 2));
    } else {
      // ================= WORKER BLOCKS (192..255) =================
      const int w_id = bid - 192;
      const int s  = t + 1;   // GRU step computed this phase
      const int te = t - 1;   // emit step finalized this phase
      const int dl = tid >> 6;
      const int bb_ = tid & 63;
      float h1old = 0.f;

      // (A) combine(te): c for batch w_id + init out row with bias
      if (te >= 0) {
        const int par2 = te & 1;
        const float* mm = mlp + par2*MLN + (size_t)w_id*6;
        float m0 = mm[0], l0 = mm[1], m1 = mm[2], l1 = mm[3], m2 = mm[4], l2 = mm[5];
        float M = fmaxf(fmaxf(m0, m1), m2);
        float e0 = __expf(m0 - M), e1 = __expf(m1 - M), e2 = __expf(m2 - M);
        float invL = 1.f / (e0*l0 + e1*l1 + e2*l2);
        const float* cp = cpart + (size_t)par2*CPN + (size_t)w_id*3*DD;
        float c = (e0*cp[tid] + e1*cp[DD + tid] + e2*cp[2*DD + tid]) * invL;
        cb[(size_t)w_id*DD + tid] = c;
        if (tid < VV) out[((size_t)w_id*TT + te)*VV + tid] = b_tok[tid];
      }

      // (B) gh1 for step s (uses h1(s-1)); save h1old
      if (s < TT) {
        if (tid < 64) TOK[tid] = targets[tid*TT + (s == 0 ? 0 : s - 1)];
        const float* h1src = (s == 0) ? (h_init + BBDD) : (h1b + (size_t)((s-1)&1)*BBDD);
        stage64(h1src, SM, wv, lane);
        __syncthreads();
        wave_dots(SM, W_hh1, b_hh1, GH1, w_id, wv, lane);
        h1old = SM[bb_*516 + w_id*8 + dl];
      }

      groupbar(wslot, wflag, bid, tid, (unsigned)(2*(t+1) + 1));

      // (C) output(te): attn_h rows o0..o0+7, logits via atomicAdd
      if (te >= 0) {
        stage64(cb, SM, wv, lane);
        __syncthreads();
        float acc = 0.f;
        const float4* hv4 = (const float4*)SM + (size_t)lane*129;
        const int orow = __builtin_amdgcn_readfirstlane(w_id*8 + wv);
        const float4* wo = (const float4*)(W_out + (size_t)orow*(2*DD));
        #pragma unroll 4
        for (int kq = 0; kq < 128; ++kq) acc += dot4(hv4[kq], wo[kq]);
        __syncthreads();
        stage64(h1b + (size_t)(te&1)*BBDD, SM, wv, lane);
        __syncthreads();
        #pragma unroll 4
        for (int kq = 0; kq < 128; ++kq) acc += dot4(hv4[kq], wo[128 + kq]);
        AH[wv*64 + lane] = tanhf(acc);
        __syncthreads();
        if (s < TT) {
          const float* h0src = (s == 0) ? h_init : (h0b + (size_t)((s-1)&1)*BBDD);
          stage64(h0src, SM, wv, lane);   // prefetch under logits
        }
        for (int v = wv; v < VV; v += 8) {
          const int vv = __builtin_amdgcn_readfirstlane(v);
          const float* wt = W_tok + (size_t)vv*DD + w_id*8;
          float s8 = 0.f;
          #pragma unroll
          for (int q8 = 0; q8 < 8; ++q8) s8 += AH[q8*64 + lane] * wt[q8];
          atomicAdd(&out[((size_t)lane*TT + te)*VV + vv], s8);
        }
      } else if (s < TT) {
        const float* h0src = (s == 0) ? h_init : (h0b + (size_t)((s-1)&1)*BBDD);
        stage64(h0src, SM, wv, lane);
      }

      // (D) GRU0(s): h0(s)
      if (s < TT) {
        __syncthreads();
        wave_dots(SM, W_hh0, b_hh0, GHX, w_id, wv, lane);
        __syncthreads();
        const int d = w_id*8 + dl;
        const int tok = TOK[bb_];
        float gir = W_ih0[(size_t)d*VV + tok]        + b_ih0[d];
        float giz = W_ih0[(size_t)(DD + d)*VV + tok] + b_ih0[DD + d];
        float gin = W_ih0[(size_t)(2*DD + d)*VV + tok] + b_ih0[2*DD + d];
        float ghr = GHX[(0*8 + dl)*64 + bb_];
        float ghz = GHX[(1*8 + dl)*64 + bb_];
        float ghn = GHX[(2*8 + dl)*64 + bb_];
        float r_ = sigmoidf_(gir + ghr), z_ = sigmoidf_(giz + ghz);
        float n_ = tanhf(gin + r_*ghn);
        float h0old = SM[bb_*516 + d];
        h0b[(size_t)(s&1)*BBDD + (size_t)bb_*DD + d] = (1.f - z_)*n_ + z_*h0old;
      }

      groupbar(wslot, wflag, bid, tid, (unsigned)(2*(t+1) + 2));

      // (E) GRU1(s): h1(s) using gi1 = h0(s) @ W_ih1^T and saved gh1
      if (s < TT) {
        stage64(h0b + (size_t)(s&1)*BBDD, SM, wv, lane);
        __syncthreads();
        wave_dots(SM, W_ih1, b_ih1, GHX, w_id, wv, lane);
        __syncthreads();
        const int d = w_id*8 + dl;
        float gir = GHX[(0*8 + dl)*64 + bb_], ghr = GH1[(0*8 + dl)*64 + bb_];
        float giz = GHX[(1*8 + dl)*64 + bb_], ghz = GH1[(1*8 + dl)*64 + bb_];
        float gin = GHX[(2*8 + dl)*64 + bb_], ghn = GH1[(2*8 + dl)*64 + bb_];
        float r_ = sigmoidf_(gir + ghr), z_ = sigmoidf_(giz + ghz);
        float n_ = tanhf(gin + r_*ghn);
        h1b[(size_t)(s&1)*BBDD + (size_t)bb_*DD + d] = (1.f - z_)*n_ + z_*h1old;
      }

      gridbar(gslot, gflag, bid, tid, (unsigned)(t + 2));
    }
  }
}

extern "C" void kernel_launch(void* const* d_in, const int* in_sizes, int n_in,
                              void* d_out, int out_size, void* d_ws, size_t ws_size,
                              hipStream_t stream) {
  const float* h_init = (const float*)d_in[0];
  const int*   targets= (const int*)d_in[1];
  const float* mem    = (const float*)d_in[2];
  const float* W_ih0  = (const float*)d_in[3];
  const float* W_hh0  = (const float*)d_in[4];
  const float* b_ih0  = (const float*)d_in[5];
  const float* b_hh0  = (const float*)d_in[6];
  const float* W_ih1  = (const float*)d_in[7];
  const float* W_hh1  = (const float*)d_in[8];
  const float* b_ih1  = (const float*)d_in[9];
  const float* b_hh1  = (const float*)d_in[10];
  const float* W_out  = (const float*)d_in[11];
  const float* W_tok  = (const float*)d_in[12];
  const float* b_tok  = (const float*)d_in[13];
  float* out = (float*)d_out;
  float* ws  = (float*)d_ws;

  // reset barrier slots/flags (re-armed every launch; graph-capture safe)
  hipMemsetAsync(d_ws, 0, WS_SLOTS_UINTS * sizeof(unsigned), stream);

  void* args[] = { (void*)&h_init, (void*)&targets, (void*)&mem,
                   (void*)&W_ih0, (void*)&W_hh0, (void*)&b_ih0, (void*)&b_hh0,
                   (void*)&W_ih1, (void*)&W_hh1, (void*)&b_ih1, (void*)&b_hh1,
                   (void*)&W_out, (void*)&W_tok, (void*)&b_tok,
                   (void*)&out, (void*)&ws };
  hipError_t err = hipLaunchCooperativeKernel((const void*)speller_kernel,
                                              dim3(NBLK), dim3(NTHR), args, 0, stream);
  if (err != hipSuccess) {
    hipLaunchKernelGGL(speller_kernel, dim3(NBLK), dim3(NTHR), 0, stream,
                       h_init, targets, mem, W_ih0, W_hh0, b_ih0, b_hh0,
                       W_ih1, W_hh1, b_ih1, b_hh1, W_out, W_tok, b_tok, out, ws);
  }
}

// Round 3
// 28001.608 us; speedup vs baseline: 1.1237x; 1.1237x over previous
//
#include <hip/hip_runtime.h>

#define NBLK 256
#define NTHR 512
#define BB 64
#define TT 200
#define SS 1024
#define DD 512
#define VV 30
#define BBDD (BB*DD)          // 32768
#define CPN  (BB*3*DD)        // cpart per parity: 98304
#define MLN  (BB*8)           // ml per parity: 512 (8 floats per batch: m0,l0,m1,l1,m2,l2,pad,pad)

// ---- workspace layout (float offsets) ----
#define WS_SLOTS_UINTS (257*16 + 65*16)     // 5152
#define WS_H0  5152
#define WS_H1  (WS_H0 + 2*BBDD)
#define WS_CB  (WS_H1 + 2*BBDD)
#define WS_CP  (WS_CB + BBDD)
#define WS_ML  (WS_CP + 2*CPN)
// total WS_ML + 2*MLN floats (~1.5 MB)

typedef __attribute__((ext_vector_type(4))) float f4;

__device__ __forceinline__ float dot4(f4 a, f4 b) {
  return a.x*b.x + a.y*b.y + a.z*b.z + a.w*b.w;
}
__device__ __forceinline__ float sigmoidf_(float x) { return 1.f/(1.f + __expf(-x)); }
__device__ __forceinline__ int minI(int a, int b) { return a < b ? a : b; }

// ======== coherent (agent-scope, L2-bypass, L3-served) access helpers ========
__device__ __forceinline__ void coh_store1(float* p, float v) {
  asm volatile("global_store_dword %0, %1, off sc0 sc1" :: "v"(p), "v"(v) : "memory");
}
__device__ __forceinline__ void coh_load3(const float* p0, const float* p1, const float* p2,
                                          float& r0, float& r1, float& r2) {
  asm volatile(
    "global_load_dword %0, %3, off sc0 sc1\n\t"
    "global_load_dword %1, %4, off sc0 sc1\n\t"
    "global_load_dword %2, %5, off sc0 sc1\n\t"
    "s_waitcnt vmcnt(0)"
    : "=&v"(r0), "=&v"(r1), "=&v"(r2)
    : "v"(p0), "v"(p1), "v"(p2) : "memory");
}
__device__ __forceinline__ void coh_load2x4(const float* p, f4& a, f4& b) {
  asm volatile(
    "global_load_dwordx4 %0, %2, off sc0 sc1\n\t"
    "global_load_dwordx4 %1, %3, off sc0 sc1\n\t"
    "s_waitcnt vmcnt(0)"
    : "=&v"(a), "=&v"(b)
    : "v"(p), "v"(p + 4) : "memory");
}
__device__ __forceinline__ void coh_load8x4(const float* g, int stridef, f4 (&r)[8]) {
  const float *a1 = g +   (size_t)stridef, *a2 = g + 2*(size_t)stridef,
              *a3 = g + 3*(size_t)stridef, *a4 = g + 4*(size_t)stridef,
              *a5 = g + 5*(size_t)stridef, *a6 = g + 6*(size_t)stridef,
              *a7 = g + 7*(size_t)stridef;
  asm volatile(
    "global_load_dwordx4 %0, %8, off sc0 sc1\n\t"
    "global_load_dwordx4 %1, %9, off sc0 sc1\n\t"
    "global_load_dwordx4 %2, %10, off sc0 sc1\n\t"
    "global_load_dwordx4 %3, %11, off sc0 sc1\n\t"
    "global_load_dwordx4 %4, %12, off sc0 sc1\n\t"
    "global_load_dwordx4 %5, %13, off sc0 sc1\n\t"
    "global_load_dwordx4 %6, %14, off sc0 sc1\n\t"
    "global_load_dwordx4 %7, %15, off sc0 sc1\n\t"
    "s_waitcnt vmcnt(0)"
    : "=&v"(r[0]), "=&v"(r[1]), "=&v"(r[2]), "=&v"(r[3]),
      "=&v"(r[4]), "=&v"(r[5]), "=&v"(r[6]), "=&v"(r[7])
    : "v"(g), "v"(a1), "v"(a2), "v"(a3), "v"(a4), "v"(a5), "v"(a6), "v"(a7)
    : "memory");
}

// coherent reg-staged copy: global [64][512] -> LDS [64][516]
__device__ __forceinline__ void stage64_coh(const float* __restrict__ src, float* TILE, int tid) {
  f4 r[8];
  const int c4 = (tid & 127) * 4;
  const int rb = tid >> 7;
  coh_load8x4(src + (size_t)tid*4, 2048, r);
  #pragma unroll
  for (int k = 0; k < 8; ++k) *(f4*)&TILE[(rb + 4*k)*516 + c4] = r[k];
  coh_load8x4(src + (size_t)tid*4 + 8*2048, 2048, r);
  #pragma unroll
  for (int k = 0; k < 8; ++k) *(f4*)&TILE[(rb + 4*(k+8))*516 + c4] = r[k];
}

// ======== plain cached async staging for READ-ONLY mem ========
__device__ __forceinline__ void gl_lds16(const float* g, float* l) {
  __builtin_amdgcn_global_load_lds(
      (const __attribute__((address_space(1))) unsigned int*)(const void*)g,
      (__attribute__((address_space(3))) unsigned int*)(void*)l,
      16, 0, 0);
}
__device__ __forceinline__ void stage_att(float* dst, const float* src, int R, int wv, int lane) {
  #pragma unroll
  for (int rr = 0; rr < 4; ++rr) {
    const int row = wv*4 + rr;
    if (row < R) {
      const float* g = src + (size_t)row*DD + lane*4;
      gl_lds16(g,       dst + row*DD);
      gl_lds16(g + 256, dst + row*DD + 256);
    }
  }
}

// wave-column GRU dot: wave wv computes 3 gate-columns from LDS h-tile.
__device__ __forceinline__ void wave_dots(const float* TILE, const float* W, const float* bias,
                                          float* GH, int w_id, int wv, int lane) {
  const int c0 = wv*3, c1 = c0+1, c2 = c0+2;
  const int R0 = __builtin_amdgcn_readfirstlane(((c0>>3)<<9) + w_id*8 + (c0&7));
  const int R1 = __builtin_amdgcn_readfirstlane(((c1>>3)<<9) + w_id*8 + (c1&7));
  const int R2 = __builtin_amdgcn_readfirstlane(((c2>>3)<<9) + w_id*8 + (c2&7));
  const f4* w0 = (const f4*)(W + (size_t)R0*DD);
  const f4* w1 = (const f4*)(W + (size_t)R1*DD);
  const f4* w2 = (const f4*)(W + (size_t)R2*DD);
  const f4* hv4 = (const f4*)TILE + (size_t)lane*129;
  float a0=0.f, a1=0.f, a2=0.f;
  #pragma unroll 4
  for (int kq = 0; kq < 128; ++kq) {
    f4 h = hv4[kq];
    a0 += dot4(h, w0[kq]); a1 += dot4(h, w1[kq]); a2 += dot4(h, w2[kq]);
  }
  GH[c0*64 + lane] = a0 + bias[R0];
  GH[c1*64 + lane] = a1 + bias[R1];
  GH[c2*64 + lane] = a2 + bias[R2];
}

// ======== fence-free barriers (relaxed agent atomics; NO threadfence/wbl2/inv) ========
__device__ __forceinline__ void gridbar(unsigned* gslot, unsigned* gflag,
                                        int bid, int tid, unsigned target) {
  __syncthreads();   // drains this wave's vmcnt (incl. coherent stores) before slot store
  if (tid == 0)
    __hip_atomic_store(&gslot[bid*16], target, __ATOMIC_RELAXED, __HIP_MEMORY_SCOPE_AGENT);
  if (bid == 0) {
    if (tid < 64) {
      for (;;) {
        unsigned v0 = __hip_atomic_load(&gslot[(tid      )*16], __ATOMIC_RELAXED, __HIP_MEMORY_SCOPE_AGENT);
        unsigned v1 = __hip_atomic_load(&gslot[(tid +  64)*16], __ATOMIC_RELAXED, __HIP_MEMORY_SCOPE_AGENT);
        unsigned v2 = __hip_atomic_load(&gslot[(tid + 128)*16], __ATOMIC_RELAXED, __HIP_MEMORY_SCOPE_AGENT);
        unsigned v3 = __hip_atomic_load(&gslot[(tid + 192)*16], __ATOMIC_RELAXED, __HIP_MEMORY_SCOPE_AGENT);
        if (__all(v0 >= target && v1 >= target && v2 >= target && v3 >= target)) break;
        __builtin_amdgcn_s_sleep(2);
      }
      if (tid == 0)
        __hip_atomic_store(gflag, target, __ATOMIC_RELAXED, __HIP_MEMORY_SCOPE_AGENT);
    }
  } else if (tid == 0) {
    while (__hip_atomic_load(gflag, __ATOMIC_RELAXED, __HIP_MEMORY_SCOPE_AGENT) < target)
      __builtin_amdgcn_s_sleep(2);
  }
  __syncthreads();
}

__device__ __forceinline__ void groupbar(unsigned* wslot, unsigned* wflag,
                                         int bid, int tid, unsigned target) {
  __syncthreads();
  if (tid == 0)
    __hip_atomic_store(&wslot[(bid-192)*16], target, __ATOMIC_RELAXED, __HIP_MEMORY_SCOPE_AGENT);
  if (bid == 192) {
    if (tid < 64) {
      for (;;) {
        unsigned v = __hip_atomic_load(&wslot[tid*16], __ATOMIC_RELAXED, __HIP_MEMORY_SCOPE_AGENT);
        if (__all(v >= target)) break;
        __builtin_amdgcn_s_sleep(2);
      }
      if (tid == 0)
        __hip_atomic_store(wflag, target, __ATOMIC_RELAXED, __HIP_MEMORY_SCOPE_AGENT);
    }
  } else if (tid == 0) {
    while (__hip_atomic_load(wflag, __ATOMIC_RELAXED, __HIP_MEMORY_SCOPE_AGENT) < target)
      __builtin_amdgcn_s_sleep(2);
  }
  __syncthreads();
}

__launch_bounds__(NTHR, 1)
__global__ void speller_kernel(const float* __restrict__ h_init,
                               const int*   __restrict__ targets,
                               const float* __restrict__ mem,
                               const float* __restrict__ W_ih0,
                               const float* __restrict__ W_hh0,
                               const float* __restrict__ b_ih0,
                               const float* __restrict__ b_hh0,
                               const float* __restrict__ W_ih1,
                               const float* __restrict__ W_hh1,
                               const float* __restrict__ b_ih1,
                               const float* __restrict__ b_hh1,
                               const float* __restrict__ W_out,
                               const float* __restrict__ W_tok,
                               const float* __restrict__ b_tok,
                               float*       __restrict__ out,
                               float*       __restrict__ ws)
{
  __shared__ float SM[36896];
  float* const GH1 = SM + 33024;
  float* const GHX = SM + 34560;
  float* const AH  = SM + 36096;
  int*   const TOK = (int*)(SM + 36608);
  float* const CP  = SM + 32768;
  float* const ML2 = SM + 36864;

  const int tid  = threadIdx.x;
  const int bid  = blockIdx.x;
  const int lane = tid & 63;
  const int wv   = tid >> 6;

  unsigned* const gslot = (unsigned*)ws;
  unsigned* const gflag = gslot + 256*16;
  unsigned* const wslot = gslot + 257*16;
  unsigned* const wflag = wslot + 64*16;

  float* const h0b   = ws + WS_H0;
  float* const h1b   = ws + WS_H1;
  float* const cb    = ws + WS_CB;
  float* const cpart = ws + WS_CP;
  float* const mlp   = ws + WS_ML;

  for (int i = tid; i < 36896; i += NTHR) SM[i] = 0.f;
  __syncthreads();

  for (int t = -1; t <= TT; ++t) {
    if (bid < 192) {
      // ================= ATTENTION BLOCKS =================
      if (t >= 0 && t < TT) {
        const int b  = bid / 3;
        const int ch = bid - 3*b;
        const int r0 = (ch == 0) ? 0 : 342 + (ch-1)*341;
        const int CNT = (ch == 0) ? 342 : 341;
        const int NTL = (CNT + 31) >> 5;
        const float* msrc = mem + ((size_t)b*SS + r0)*DD;
        const int qpar = t & 1;
        const int seg = lane & 15;
        const int rr4 = lane >> 4;
        const float* qsrc = h1b + (size_t)qpar*BBDD + (size_t)b*DD;
        f4 q4[8];
        coh_load8x4(qsrc + seg*4, 64, q4);   // coherent q read (h1 is mutable shared state)

        float m_run = -3e38f, l_run = 0.f;
        float cacc[8];
        #pragma unroll
        for (int j = 0; j < 8; ++j) cacc[j] = 0.f;

        int buf = 0;
        stage_att(SM, msrc, minI(32, CNT), wv, lane);
        __syncthreads();

        for (int tl = 0; tl < NTL; ++tl) {
          const int Rcur = minI(32, CNT - tl*32);
          if (tl + 1 < NTL)
            stage_att(SM + (buf^1)*16384, msrc + (size_t)(tl+1)*32*DD,
                      minI(32, CNT - (tl+1)*32), wv, lane);
          const float* bbuf = SM + buf*16384;
          const int r = wv*4 + rr4;
          float sc = 0.f;
          if (r < Rcur) {
            const f4* rb = (const f4*)(bbuf + (size_t)r*DD);
            #pragma unroll
            for (int jj = 0; jj < 8; ++jj) sc += dot4(rb[seg + 16*jj], q4[jj]);
          }
          sc += __shfl_xor(sc, 1);
          sc += __shfl_xor(sc, 2);
          sc += __shfl_xor(sc, 4);
          sc += __shfl_xor(sc, 8);
          const int rb0 = wv*4;
          float s0 = __shfl(sc, 0), s1 = __shfl(sc, 16), s2 = __shfl(sc, 32), s3 = __shfl(sc, 48);
          float sv0 = (rb0+0 < Rcur) ? s0 : -3e38f;
          float sv1 = (rb0+1 < Rcur) ? s1 : -3e38f;
          float sv2 = (rb0+2 < Rcur) ? s2 : -3e38f;
          float sv3 = (rb0+3 < Rcur) ? s3 : -3e38f;
          float m_tile = fmaxf(fmaxf(sv0, sv1), fmaxf(sv2, sv3));
          float m_new  = fmaxf(m_run, m_tile);
          float esc    = __expf(m_run - m_new);
          float w0 = (rb0+0 < Rcur) ? __expf(s0 - m_new) : 0.f;
          float w1 = (rb0+1 < Rcur) ? __expf(s1 - m_new) : 0.f;
          float w2 = (rb0+2 < Rcur) ? __expf(s2 - m_new) : 0.f;
          float w3 = (rb0+3 < Rcur) ? __expf(s3 - m_new) : 0.f;
          l_run = l_run*esc + (w0 + w1) + (w2 + w3);
          m_run = m_new;
          #pragma unroll
          for (int j = 0; j < 8; ++j) {
            const int kk = j*64 + lane;
            float a = cacc[j]*esc;
            a += w0*bbuf[(rb0+0)*DD + kk];
            a += w1*bbuf[(rb0+1)*DD + kk];
            a += w2*bbuf[(rb0+2)*DD + kk];
            a += w3*bbuf[(rb0+3)*DD + kk];
            cacc[j] = a;
          }
          __syncthreads();
          buf ^= 1;
        }
        #pragma unroll
        for (int j = 0; j < 8; ++j) CP[wv*DD + j*64 + lane] = cacc[j];
        if (lane == 0) { ML2[wv*2] = m_run; ML2[wv*2+1] = l_run; }
        __syncthreads();
        float M = -3e38f;
        #pragma unroll
        for (int w = 0; w < 8; ++w) M = fmaxf(M, ML2[w*2]);
        float lsum = 0.f, ck = 0.f;
        #pragma unroll
        for (int w = 0; w < 8; ++w) {
          float ew = __expf(ML2[w*2] - M);
          lsum += ew*ML2[w*2+1];
          ck   += ew*CP[w*DD + tid];
        }
        const int par = t & 1;
        coh_store1(&cpart[(size_t)par*CPN + ((size_t)(b*3+ch))*DD + tid], ck);
        if (tid == 0) {
          coh_store1(&mlp[par*MLN + b*8 + ch*2],     M);
          coh_store1(&mlp[par*MLN + b*8 + ch*2 + 1], lsum);
        }
      }
      gridbar(gslot, gflag, bid, tid, (unsigned)(t + 2));
    } else {
      // ================= WORKER BLOCKS (192..255) =================
      const int w_id = bid - 192;
      const int s  = t + 1;
      const int te = t - 1;
      const int dl = tid >> 6;
      const int bb_ = tid & 63;
      float h1old = 0.f;

      // (A) combine(te) + out bias init
      if (te >= 0) {
        const int par2 = te & 1;
        f4 mA, mB;
        coh_load2x4(mlp + par2*MLN + w_id*8, mA, mB);
        float M = fmaxf(fmaxf(mA.x, mA.z), mB.x);
        float e0 = __expf(mA.x - M), e1 = __expf(mA.z - M), e2 = __expf(mB.x - M);
        float invL = 1.f / (e0*mA.y + e1*mA.w + e2*mB.y);
        const float* cp = cpart + (size_t)par2*CPN + (size_t)w_id*3*DD;
        float c0, c1, c2;
        coh_load3(cp + tid, cp + DD + tid, cp + 2*DD + tid, c0, c1, c2);
        float c = (e0*c0 + e1*c1 + e2*c2) * invL;
        coh_store1(&cb[(size_t)w_id*DD + tid], c);
        if (tid < VV) coh_store1(&out[((size_t)w_id*TT + te)*VV + tid], b_tok[tid]);
      }

      // (B) gh1 for step s
      if (s < TT) {
        if (tid < 64) TOK[tid] = targets[tid*TT + (s == 0 ? 0 : s - 1)];
        const float* h1src = (s == 0) ? (h_init + BBDD) : (h1b + (size_t)((s-1)&1)*BBDD);
        stage64_coh(h1src, SM, tid);
        __syncthreads();
        wave_dots(SM, W_hh1, b_hh1, GH1, w_id, wv, lane);
        h1old = SM[bb_*516 + w_id*8 + dl];
      }

      groupbar(wslot, wflag, bid, tid, (unsigned)(2*(t+1) + 1));

      // (C) output(te): attn_h rows + logits atomics
      if (te >= 0) {
        stage64_coh(cb, SM, tid);
        __syncthreads();
        float acc = 0.f;
        const f4* hv4 = (const f4*)SM + (size_t)lane*129;
        const int orow = __builtin_amdgcn_readfirstlane(w_id*8 + wv);
        const f4* wo = (const f4*)(W_out + (size_t)orow*(2*DD));
        #pragma unroll 4
        for (int kq = 0; kq < 128; ++kq) acc += dot4(hv4[kq], wo[kq]);
        __syncthreads();
        stage64_coh(h1b + (size_t)(te&1)*BBDD, SM, tid);
        __syncthreads();
        #pragma unroll 4
        for (int kq = 0; kq < 128; ++kq) acc += dot4(hv4[kq], wo[128 + kq]);
        AH[wv*64 + lane] = tanhf(acc);
        __syncthreads();
        if (s < TT) {
          const float* h0src = (s == 0) ? h_init : (h0b + (size_t)((s-1)&1)*BBDD);
          stage64_coh(h0src, SM, tid);
        }
        for (int v = wv; v < VV; v += 8) {
          const int vv = __builtin_amdgcn_readfirstlane(v);
          const float* wt = W_tok + (size_t)vv*DD + w_id*8;
          float s8 = 0.f;
          #pragma unroll
          for (int q8 = 0; q8 < 8; ++q8) s8 += AH[q8*64 + lane] * wt[q8];
          atomicAdd(&out[((size_t)lane*TT + te)*VV + vv], s8);
        }
      } else if (s < TT) {
        const float* h0src = (s == 0) ? h_init : (h0b + (size_t)((s-1)&1)*BBDD);
        stage64_coh(h0src, SM, tid);
      }

      // (D) GRU0(s)
      if (s < TT) {
        __syncthreads();
        wave_dots(SM, W_hh0, b_hh0, GHX, w_id, wv, lane);
        __syncthreads();
        const int d = w_id*8 + dl;
        const int tok = TOK[bb_];
        float gir = W_ih0[(size_t)d*VV + tok]          + b_ih0[d];
        float giz = W_ih0[(size_t)(DD + d)*VV + tok]   + b_ih0[DD + d];
        float gin = W_ih0[(size_t)(2*DD + d)*VV + tok] + b_ih0[2*DD + d];
        float ghr = GHX[(0*8 + dl)*64 + bb_];
        float ghz = GHX[(1*8 + dl)*64 + bb_];
        float ghn = GHX[(2*8 + dl)*64 + bb_];
        float r_ = sigmoidf_(gir + ghr), z_ = sigmoidf_(giz + ghz);
        float n_ = tanhf(gin + r_*ghn);
        float h0old = SM[bb_*516 + d];
        coh_store1(&h0b[(size_t)(s&1)*BBDD + (size_t)bb_*DD + d], (1.f - z_)*n_ + z_*h0old);
      }

      groupbar(wslot, wflag, bid, tid, (unsigned)(2*(t+1) + 2));

      // (E) GRU1(s)
      if (s < TT) {
        stage64_coh(h0b + (size_t)(s&1)*BBDD, SM, tid);
        __syncthreads();
        wave_dots(SM, W_ih1, b_ih1, GHX, w_id, wv, lane);
        __syncthreads();
        const int d = w_id*8 + dl;
        float gir = GHX[(0*8 + dl)*64 + bb_], ghr = GH1[(0*8 + dl)*64 + bb_];
        float giz = GHX[(1*8 + dl)*64 + bb_], ghz = GH1[(1*8 + dl)*64 + bb_];
        float gin = GHX[(2*8 + dl)*64 + bb_], ghn = GH1[(2*8 + dl)*64 + bb_];
        float r_ = sigmoidf_(gir + ghr), z_ = sigmoidf_(giz + ghz);
        float n_ = tanhf(gin + r_*ghn);
        coh_store1(&h1b[(size_t)(s&1)*BBDD + (size_t)bb_*DD + d], (1.f - z_)*n_ + z_*h1old);
      }

      gridbar(gslot, gflag, bid, tid, (unsigned)(t + 2));
    }
  }
}

extern "C" void kernel_launch(void* const* d_in, const int* in_sizes, int n_in,
                              void* d_out, int out_size, void* d_ws, size_t ws_size,
                              hipStream_t stream) {
  const float* h_init = (const float*)d_in[0];
  const int*   targets= (const int*)d_in[1];
  const float* mem    = (const float*)d_in[2];
  const float* W_ih0  = (const float*)d_in[3];
  const float* W_hh0  = (const float*)d_in[4];
  const float* b_ih0  = (const float*)d_in[5];
  const float* b_hh0  = (const float*)d_in[6];
  const float* W_ih1  = (const float*)d_in[7];
  const float* W_hh1  = (const float*)d_in[8];
  const float* b_ih1  = (const float*)d_in[9];
  const float* b_hh1  = (const float*)d_in[10];
  const float* W_out  = (const float*)d_in[11];
  const float* W_tok  = (const float*)d_in[12];
  const float* b_tok  = (const float*)d_in[13];
  float* out = (float*)d_out;
  float* ws  = (float*)d_ws;

  hipMemsetAsync(d_ws, 0, WS_SLOTS_UINTS * sizeof(unsigned), stream);

  void* args[] = { (void*)&h_init, (void*)&targets, (void*)&mem,
                   (void*)&W_ih0, (void*)&W_hh0, (void*)&b_ih0, (void*)&b_hh0,
                   (void*)&W_ih1, (void*)&W_hh1, (void*)&b_ih1, (void*)&b_hh1,
                   (void*)&W_out, (void*)&W_tok, (void*)&b_tok,
                   (void*)&out, (void*)&ws };
  hipError_t err = hipLaunchCooperativeKernel((const void*)speller_kernel,
                                              dim3(NBLK), dim3(NTHR), args, 0, stream);
  if (err != hipSuccess) {
    hipLaunchKernelGGL(speller_kernel, dim3(NBLK), dim3(NTHR), 0, stream,
                       h_init, targets, mem, W_ih0, W_hh0, b_ih0, b_hh0,
                       W_ih1, W_hh1, b_ih1, b_hh1, W_out, W_tok, b_tok, out, ws);
  }
}

// Round 4
// 27900.000 us; speedup vs baseline: 1.1278x; 1.0036x over previous
//
#include <hip/hip_runtime.h>

#define NBLK 256
#define NTHR 512
#define BB 64
#define TT 200
#define SS 1024
#define DD 512
#define VV 30
#define BBDD (BB*DD)          // 32768
#define CPN  (BB*3*DD)        // 98304
#define MLNF 512              // ml floats per parity

// ---- workspace float offsets ----
#define WS_SLOTS_UINTS (257*16 + 65*16)     // 5152 uints
#define WS_H0   5152                        // [2][64][512]
#define WS_H1   (WS_H0 + 2*BBDD)            // [3][64][512]  (triple buffer)
#define WS_CB   (WS_H1 + 3*BBDD)            // [64][512]
#define WS_CP   (WS_CB + BBDD)              // [2][64*3][512]
#define WS_ML   (WS_CP + 2*CPN)             // [2][512]
#define WS_MB16 400000                      // bf16 mem mirror (ushort), byte off 1.6e6
#define WS_BF16_BYTES ((size_t)WS_MB16*4 + (size_t)BB*SS*DD*2)

typedef __attribute__((ext_vector_type(4))) float f4;
typedef __attribute__((ext_vector_type(4))) unsigned int u4v;
typedef unsigned short ushortT;

__device__ __forceinline__ float dot4(f4 a, f4 b) {
  return a.x*b.x + a.y*b.y + a.z*b.z + a.w*b.w;
}
__device__ __forceinline__ float sigmoidf_(float x) { return 1.f/(1.f + __expf(-x)); }
__device__ __forceinline__ int minI(int a, int b) { return a < b ? a : b; }
__device__ __forceinline__ float bf2f(unsigned int u) { return __uint_as_float(u << 16); }

// ======== coherent (agent-scope, L2-bypass) access helpers ========
__device__ __forceinline__ void coh_store1(float* p, float v) {
  asm volatile("global_store_dword %0, %1, off sc0 sc1" :: "v"(p), "v"(v) : "memory");
}
__device__ __forceinline__ void coh_store16(void* p, u4v v) {
  asm volatile("global_store_dwordx4 %0, %1, off sc0 sc1" :: "v"(p), "v"(v) : "memory");
}
__device__ __forceinline__ void coh_load3(const float* p0, const float* p1, const float* p2,
                                          float& r0, float& r1, float& r2) {
  asm volatile(
    "global_load_dword %0, %3, off sc0 sc1\n\t"
    "global_load_dword %1, %4, off sc0 sc1\n\t"
    "global_load_dword %2, %5, off sc0 sc1\n\t"
    "s_waitcnt vmcnt(0)"
    : "=&v"(r0), "=&v"(r1), "=&v"(r2)
    : "v"(p0), "v"(p1), "v"(p2) : "memory");
}
__device__ __forceinline__ void coh_load2x4(const float* p, f4& a, f4& b) {
  asm volatile(
    "global_load_dwordx4 %0, %2, off sc0 sc1\n\t"
    "global_load_dwordx4 %1, %3, off sc0 sc1\n\t"
    "s_waitcnt vmcnt(0)"
    : "=&v"(a), "=&v"(b)
    : "v"(p), "v"(p + 4) : "memory");
}
__device__ __forceinline__ void coh_load8x4(const float* g, int stridef, f4 (&r)[8]) {
  const float *a1 = g +   (size_t)stridef, *a2 = g + 2*(size_t)stridef,
              *a3 = g + 3*(size_t)stridef, *a4 = g + 4*(size_t)stridef,
              *a5 = g + 5*(size_t)stridef, *a6 = g + 6*(size_t)stridef,
              *a7 = g + 7*(size_t)stridef;
  asm volatile(
    "global_load_dwordx4 %0, %8, off sc0 sc1\n\t"
    "global_load_dwordx4 %1, %9, off sc0 sc1\n\t"
    "global_load_dwordx4 %2, %10, off sc0 sc1\n\t"
    "global_load_dwordx4 %3, %11, off sc0 sc1\n\t"
    "global_load_dwordx4 %4, %12, off sc0 sc1\n\t"
    "global_load_dwordx4 %5, %13, off sc0 sc1\n\t"
    "global_load_dwordx4 %6, %14, off sc0 sc1\n\t"
    "global_load_dwordx4 %7, %15, off sc0 sc1\n\t"
    "s_waitcnt vmcnt(0)"
    : "=&v"(r[0]), "=&v"(r[1]), "=&v"(r[2]), "=&v"(r[3]),
      "=&v"(r[4]), "=&v"(r[5]), "=&v"(r[6]), "=&v"(r[7])
    : "v"(g), "v"(a1), "v"(a2), "v"(a3), "v"(a4), "v"(a5), "v"(a6), "v"(a7)
    : "memory");
}

// coherent reg-staged copy: global [64][512] -> LDS [64][516]
__device__ __forceinline__ void stage64_coh(const float* __restrict__ src, float* TILE, int tid) {
  f4 r[8];
  const int c4 = (tid & 127) * 4;
  const int rb = tid >> 7;
  coh_load8x4(src + (size_t)tid*4, 2048, r);
  #pragma unroll
  for (int k = 0; k < 8; ++k) *(f4*)&TILE[(rb + 4*k)*516 + c4] = r[k];
  coh_load8x4(src + (size_t)tid*4 + 8*2048, 2048, r);
  #pragma unroll
  for (int k = 0; k < 8; ++k) *(f4*)&TILE[(rb + 4*(k+8))*516 + c4] = r[k];
}

// ======== cached async staging (read-only data) ========
__device__ __forceinline__ void gl_lds16(const void* g, void* l) {
  __builtin_amdgcn_global_load_lds(
      (const __attribute__((address_space(1))) unsigned int*)g,
      (__attribute__((address_space(3))) unsigned int*)l,
      16, 0, 0);
}
__device__ __forceinline__ void stage_att_f32(float* dst, const float* src, int R, int wv, int lane) {
  #pragma unroll
  for (int rr = 0; rr < 4; ++rr) {
    const int row = wv*4 + rr;
    if (row < R) {
      const float* g = src + (size_t)row*DD + lane*4;
      gl_lds16(g,       dst + row*DD);
      gl_lds16(g + 256, dst + row*DD + 256);
    }
  }
}
__device__ __forceinline__ void stage_att_bf(char* dstb, const ushortT* src, int R, int wv, int lane) {
  #pragma unroll
  for (int rr = 0; rr < 4; ++rr) {
    const int row = wv*4 + rr;
    if (row < R)
      gl_lds16(src + (size_t)row*512 + lane*8, dstb + row*1024);
  }
}

// wave-column GRU dot
__device__ __forceinline__ void wave_dots(const float* TILE, const float* W, const float* bias,
                                          float* GH, int w_id, int wv, int lane) {
  const int c0 = wv*3, c1 = c0+1, c2 = c0+2;
  const int R0 = __builtin_amdgcn_readfirstlane(((c0>>3)<<9) + w_id*8 + (c0&7));
  const int R1 = __builtin_amdgcn_readfirstlane(((c1>>3)<<9) + w_id*8 + (c1&7));
  const int R2 = __builtin_amdgcn_readfirstlane(((c2>>3)<<9) + w_id*8 + (c2&7));
  const f4* w0 = (const f4*)(W + (size_t)R0*DD);
  const f4* w1 = (const f4*)(W + (size_t)R1*DD);
  const f4* w2 = (const f4*)(W + (size_t)R2*DD);
  const f4* hv4 = (const f4*)TILE + (size_t)lane*129;
  float a0=0.f, a1=0.f, a2=0.f;
  #pragma unroll 4
  for (int kq = 0; kq < 128; ++kq) {
    f4 h = hv4[kq];
    a0 += dot4(h, w0[kq]); a1 += dot4(h, w1[kq]); a2 += dot4(h, w2[kq]);
  }
  GH[c0*64 + lane] = a0 + bias[R0];
  GH[c1*64 + lane] = a1 + bias[R1];
  GH[c2*64 + lane] = a2 + bias[R2];
}

// ======== fence-free barriers ========
__device__ __forceinline__ void gridbar(unsigned* gslot, unsigned* gflag,
                                        int bid, int tid, unsigned target) {
  __syncthreads();
  if (tid == 0)
    __hip_atomic_store(&gslot[bid*16], target, __ATOMIC_RELAXED, __HIP_MEMORY_SCOPE_AGENT);
  if (bid == 0) {
    if (tid < 64) {
      for (;;) {
        unsigned v0 = __hip_atomic_load(&gslot[(tid      )*16], __ATOMIC_RELAXED, __HIP_MEMORY_SCOPE_AGENT);
        unsigned v1 = __hip_atomic_load(&gslot[(tid +  64)*16], __ATOMIC_RELAXED, __HIP_MEMORY_SCOPE_AGENT);
        unsigned v2 = __hip_atomic_load(&gslot[(tid + 128)*16], __ATOMIC_RELAXED, __HIP_MEMORY_SCOPE_AGENT);
        unsigned v3 = __hip_atomic_load(&gslot[(tid + 192)*16], __ATOMIC_RELAXED, __HIP_MEMORY_SCOPE_AGENT);
        if (__all(v0 >= target && v1 >= target && v2 >= target && v3 >= target)) break;
        __builtin_amdgcn_s_sleep(2);
      }
      if (tid == 0)
        __hip_atomic_store(gflag, target, __ATOMIC_RELAXED, __HIP_MEMORY_SCOPE_AGENT);
    }
  } else if (tid == 0) {
    while (__hip_atomic_load(gflag, __ATOMIC_RELAXED, __HIP_MEMORY_SCOPE_AGENT) < target)
      __builtin_amdgcn_s_sleep(2);
  }
  __syncthreads();
}

__device__ __forceinline__ void groupbar(unsigned* wslot, unsigned* wflag,
                                         int bid, int tid, unsigned target) {
  __syncthreads();
  if (tid == 0)
    __hip_atomic_store(&wslot[(bid-192)*16], target, __ATOMIC_RELAXED, __HIP_MEMORY_SCOPE_AGENT);
  if (bid == 192) {
    if (tid < 64) {
      for (;;) {
        unsigned v = __hip_atomic_load(&wslot[tid*16], __ATOMIC_RELAXED, __HIP_MEMORY_SCOPE_AGENT);
        if (__all(v >= target)) break;
        __builtin_amdgcn_s_sleep(2);
      }
      if (tid == 0)
        __hip_atomic_store(wflag, target, __ATOMIC_RELAXED, __HIP_MEMORY_SCOPE_AGENT);
    }
  } else if (tid == 0) {
    while (__hip_atomic_load(wflag, __ATOMIC_RELAXED, __HIP_MEMORY_SCOPE_AGENT) < target)
      __builtin_amdgcn_s_sleep(2);
  }
  __syncthreads();
}

__device__ __forceinline__ unsigned bfr_(float x) {
  unsigned u = __float_as_uint(x);
  return (u + 0x7fffu + ((u >> 16) & 1u)) >> 16;   // RNE f32->bf16
}

template<int MB16>
__launch_bounds__(NTHR, 1)
__global__ void speller_kernel(const float* __restrict__ h_init,
                               const int*   __restrict__ targets,
                               const float* __restrict__ mem,
                               const float* __restrict__ W_ih0,
                               const float* __restrict__ W_hh0,
                               const float* __restrict__ b_ih0,
                               const float* __restrict__ b_hh0,
                               const float* __restrict__ W_ih1,
                               const float* __restrict__ W_hh1,
                               const float* __restrict__ b_ih1,
                               const float* __restrict__ b_hh1,
                               const float* __restrict__ W_out,
                               const float* __restrict__ W_tok,
                               const float* __restrict__ b_tok,
                               float*       __restrict__ out,
                               float*       __restrict__ ws)
{
  __shared__ float SM[36896];
  float* const GH1 = SM + 33024;   // gh1 columns [24][64]
  float* const GHX = SM + 34560;   // scratch gate columns [24][64]
  float* const AH  = SM + 36096;   // attn_h components [8][64]
  int*   const TOK = (int*)(SM + 36608);
  float* const CP  = SM + 32768;   // attention per-wave partials [8][512]
  float* const ML2 = SM + 36864;

  const int tid  = threadIdx.x;
  const int bid  = blockIdx.x;
  const int lane = tid & 63;
  const int wv   = tid >> 6;

  unsigned* const gslot = (unsigned*)ws;
  unsigned* const gflag = gslot + 256*16;
  unsigned* const wslot = gslot + 257*16;
  unsigned* const wflag = wslot + 64*16;

  float* const h0b   = ws + WS_H0;
  float* const h1b   = ws + WS_H1;
  float* const cb    = ws + WS_CB;
  float* const cpart = ws + WS_CP;
  float* const mlp   = ws + WS_ML;
  ushortT* const mb16 = (ushortT*)(ws + WS_MB16);

  for (int i = tid; i < 36896; i += NTHR) SM[i] = 0.f;
  __syncthreads();

  // ---- prologue: convert mem -> bf16 mirror (write-through) ----
  if (MB16) {
    const size_t total = (size_t)BB*SS*DD;
    for (size_t i = ((size_t)bid*NTHR + tid)*8; i < total; i += (size_t)NBLK*NTHR*8) {
      f4 a = *(const f4*)(mem + i);
      f4 b = *(const f4*)(mem + i + 4);
      u4v d;
      d.x = bfr_(a.x) | (bfr_(a.y) << 16);
      d.y = bfr_(a.z) | (bfr_(a.w) << 16);
      d.z = bfr_(b.x) | (bfr_(b.y) << 16);
      d.w = bfr_(b.z) | (bfr_(b.w) << 16);
      coh_store16(mb16 + i, d);
    }
  }
  gridbar(gslot, gflag, bid, tid, 1u);
  if (MB16) {
    asm volatile("s_waitcnt vmcnt(0) lgkmcnt(0)\n\tbuffer_inv" ::: "memory");
    __syncthreads();
  }

  for (int t = -1; t <= TT; ++t) {
    if (bid < 192) {
      // ================= ATTENTION BLOCKS (step t) =================
      if (t >= 0 && t < TT) {
        const int b  = bid / 3;
        const int ch = bid - 3*b;
        const int r0 = (ch == 0) ? 0 : 342 + (ch-1)*341;
        const int CNT = (ch == 0) ? 342 : 341;
        const int NTL = (CNT + 31) >> 5;
        const int seg = lane & 15;
        const int rr4 = lane >> 4;
        const float* qsrc = h1b + (size_t)(t % 3)*BBDD + (size_t)b*DD;
        f4 q4[8];
        if (MB16) coh_load8x4(qsrc + seg*32, 4, q4);     // contiguous 32 floats
        else      coh_load8x4(qsrc + seg*4, 64, q4);     // strided (f32 layout)

        float m_run = -3e38f, l_run = 0.f;
        float cacc[8];
        #pragma unroll
        for (int j = 0; j < 8; ++j) cacc[j] = 0.f;

        int buf = 0;
        const float*   msrcF = mem  + ((size_t)b*SS + r0)*DD;
        const ushortT* msrcB = mb16 + ((size_t)b*SS + r0)*DD;
        if (MB16) stage_att_bf((char*)SM, msrcB, minI(32, CNT), wv, lane);
        else      stage_att_f32(SM, msrcF, minI(32, CNT), wv, lane);
        __syncthreads();

        for (int tl = 0; tl < NTL; ++tl) {
          const int Rcur = minI(32, CNT - tl*32);
          if (tl + 1 < NTL) {
            if (MB16) stage_att_bf((char*)SM + (buf^1)*32768, msrcB + (size_t)(tl+1)*32*DD,
                                   minI(32, CNT - (tl+1)*32), wv, lane);
            else      stage_att_f32(SM + (buf^1)*16384, msrcF + (size_t)(tl+1)*32*DD,
                                    minI(32, CNT - (tl+1)*32), wv, lane);
          }
          const int r = wv*4 + rr4;
          float sc = 0.f;
          if (MB16) {
            const char* bbufb = (const char*)SM + buf*32768;
            if (r < Rcur) {
              const u4v* rp = (const u4v*)(bbufb + r*1024 + seg*64);
              const float* qq = (const float*)q4;
              #pragma unroll
              for (int jj = 0; jj < 4; ++jj) {
                u4v u = rp[jj];
                sc += __uint_as_float(u.x << 16)           * qq[jj*8+0]
                    + __uint_as_float(u.x & 0xffff0000u)   * qq[jj*8+1]
                    + __uint_as_float(u.y << 16)           * qq[jj*8+2]
                    + __uint_as_float(u.y & 0xffff0000u)   * qq[jj*8+3]
                    + __uint_as_float(u.z << 16)           * qq[jj*8+4]
                    + __uint_as_float(u.z & 0xffff0000u)   * qq[jj*8+5]
                    + __uint_as_float(u.w << 16)           * qq[jj*8+6]
                    + __uint_as_float(u.w & 0xffff0000u)   * qq[jj*8+7];
              }
            }
          } else {
            const float* bbuf = SM + buf*16384;
            if (r < Rcur) {
              const f4* rb = (const f4*)(bbuf + (size_t)r*DD);
              #pragma unroll
              for (int jj = 0; jj < 8; ++jj) sc += dot4(rb[seg + 16*jj], q4[jj]);
            }
          }
          sc += __shfl_xor(sc, 1);
          sc += __shfl_xor(sc, 2);
          sc += __shfl_xor(sc, 4);
          sc += __shfl_xor(sc, 8);
          const int rb0 = wv*4;
          float s0 = __shfl(sc, 0), s1 = __shfl(sc, 16), s2 = __shfl(sc, 32), s3 = __shfl(sc, 48);
          float sv0 = (rb0+0 < Rcur) ? s0 : -3e38f;
          float sv1 = (rb0+1 < Rcur) ? s1 : -3e38f;
          float sv2 = (rb0+2 < Rcur) ? s2 : -3e38f;
          float sv3 = (rb0+3 < Rcur) ? s3 : -3e38f;
          float m_tile = fmaxf(fmaxf(sv0, sv1), fmaxf(sv2, sv3));
          float m_new  = fmaxf(m_run, m_tile);
          float esc    = __expf(m_run - m_new);
          float w0 = (rb0+0 < Rcur) ? __expf(s0 - m_new) : 0.f;
          float w1 = (rb0+1 < Rcur) ? __expf(s1 - m_new) : 0.f;
          float w2 = (rb0+2 < Rcur) ? __expf(s2 - m_new) : 0.f;
          float w3 = (rb0+3 < Rcur) ? __expf(s3 - m_new) : 0.f;
          l_run = l_run*esc + (w0 + w1) + (w2 + w3);
          m_run = m_new;
          if (MB16) {
            const ushortT* bu = (const ushortT*)((const char*)SM + buf*32768);
            #pragma unroll
            for (int j = 0; j < 8; ++j) {
              const int kk = j*64 + lane;
              float a = cacc[j]*esc;
              a += w0 * bf2f(bu[(rb0+0)*512 + kk]);
              a += w1 * bf2f(bu[(rb0+1)*512 + kk]);
              a += w2 * bf2f(bu[(rb0+2)*512 + kk]);
              a += w3 * bf2f(bu[(rb0+3)*512 + kk]);
              cacc[j] = a;
            }
          } else {
            const float* bbuf = SM + buf*16384;
            #pragma unroll
            for (int j = 0; j < 8; ++j) {
              const int kk = j*64 + lane;
              float a = cacc[j]*esc;
              a += w0*bbuf[(rb0+0)*DD + kk];
              a += w1*bbuf[(rb0+1)*DD + kk];
              a += w2*bbuf[(rb0+2)*DD + kk];
              a += w3*bbuf[(rb0+3)*DD + kk];
              cacc[j] = a;
            }
          }
          __syncthreads();
          buf ^= 1;
        }
        #pragma unroll
        for (int j = 0; j < 8; ++j) CP[wv*DD + j*64 + lane] = cacc[j];
        if (lane == 0) { ML2[wv*2] = m_run; ML2[wv*2+1] = l_run; }
        __syncthreads();
        float M = -3e38f;
        #pragma unroll
        for (int w = 0; w < 8; ++w) M = fmaxf(M, ML2[w*2]);
        float lsum = 0.f, ck = 0.f;
        #pragma unroll
        for (int w = 0; w < 8; ++w) {
          float ew = __expf(ML2[w*2] - M);
          lsum += ew*ML2[w*2+1];
          ck   += ew*CP[w*DD + tid];
        }
        const int par = t & 1;
        coh_store1(&cpart[(size_t)par*CPN + ((size_t)(b*3+ch))*DD + tid], ck);
        if (tid == 0) {
          coh_store1(&mlp[par*MLNF + b*8 + ch*2],     M);
          coh_store1(&mlp[par*MLNF + b*8 + ch*2 + 1], lsum);
        }
      }
      gridbar(gslot, gflag, bid, tid, (unsigned)(t + 3));
    } else {
      // ================= WORKER BLOCKS (192..255) =================
      const int w_id = bid - 192;
      const int s  = t + 1;   // GRU step produced this iteration
      const int te = t - 1;   // emit step finalized this iteration
      const int dl = tid >> 6;
      const int bb_ = tid & 63;
      float h1old = 0.f;

      // (A) combine(te) -> cb, out bias init
      if (te >= 0) {
        const int par2 = te & 1;
        f4 mA, mB;
        coh_load2x4(mlp + par2*MLNF + w_id*8, mA, mB);
        float M = fmaxf(fmaxf(mA.x, mA.z), mB.x);
        float e0 = __expf(mA.x - M), e1 = __expf(mA.z - M), e2 = __expf(mB.x - M);
        float invL = 1.f / (e0*mA.y + e1*mA.w + e2*mB.y);
        const float* cp = cpart + (size_t)par2*CPN + (size_t)w_id*3*DD;
        float c0, c1, c2;
        coh_load3(cp + tid, cp + DD + tid, cp + 2*DD + tid, c0, c1, c2);
        float c = (e0*c0 + e1*c1 + e2*c2) * invL;
        coh_store1(&cb[(size_t)w_id*DD + tid], c);
        if (tid < VV) coh_store1(&out[((size_t)w_id*TT + te)*VV + tid], b_tok[tid]);
      }

      // (B) gh1(s) from h1(s-1)
      if (s < TT) {
        if (tid < 64) TOK[tid] = targets[tid*TT + (s == 0 ? 0 : s - 1)];
        const float* h1src = (s == 0) ? (h_init + BBDD) : (h1b + (size_t)(((s-1) % 3))*BBDD);
        stage64_coh(h1src, SM, tid);
        __syncthreads();
        wave_dots(SM, W_hh1, b_hh1, GH1, w_id, wv, lane);
        h1old = SM[bb_*516 + w_id*8 + dl];
        __syncthreads();
      }

      // (D) GRU0(s) -> h0(s)
      if (s < TT) {
        const float* h0src = (s == 0) ? h_init : (h0b + (size_t)((s-1)&1)*BBDD);
        stage64_coh(h0src, SM, tid);
        __syncthreads();
        wave_dots(SM, W_hh0, b_hh0, GHX, w_id, wv, lane);
        __syncthreads();
        const int d = w_id*8 + dl;
        const int tok = TOK[bb_];
        float gir = W_ih0[(size_t)d*VV + tok]          + b_ih0[d];
        float giz = W_ih0[(size_t)(DD + d)*VV + tok]   + b_ih0[DD + d];
        float gin = W_ih0[(size_t)(2*DD + d)*VV + tok] + b_ih0[2*DD + d];
        float ghr = GHX[(0*8 + dl)*64 + bb_];
        float ghz = GHX[(1*8 + dl)*64 + bb_];
        float ghn = GHX[(2*8 + dl)*64 + bb_];
        float r_ = sigmoidf_(gir + ghr), z_ = sigmoidf_(giz + ghz);
        float n_ = tanhf(gin + r_*ghn);
        float h0old = SM[bb_*516 + d];
        coh_store1(&h0b[(size_t)(s&1)*BBDD + (size_t)bb_*DD + d], (1.f - z_)*n_ + z_*h0old);
      }

      groupbar(wslot, wflag, bid, tid, (unsigned)(t + 2));

      // (C) output(te)
      if (te >= 0) {
        stage64_coh(cb, SM, tid);
        __syncthreads();
        float acc = 0.f;
        const f4* hv4 = (const f4*)SM + (size_t)lane*129;
        const int orow = __builtin_amdgcn_readfirstlane(w_id*8 + wv);
        const f4* wo = (const f4*)(W_out + (size_t)orow*(2*DD));
        #pragma unroll 4
        for (int kq = 0; kq < 128; ++kq) acc += dot4(hv4[kq], wo[kq]);
        __syncthreads();
        stage64_coh(h1b + (size_t)(te % 3)*BBDD, SM, tid);
        __syncthreads();
        #pragma unroll 4
        for (int kq = 0; kq < 128; ++kq) acc += dot4(hv4[kq], wo[128 + kq]);
        AH[wv*64 + lane] = tanhf(acc);
        __syncthreads();
        for (int v = wv; v < VV; v += 8) {
          const int vv = __builtin_amdgcn_readfirstlane(v);
          const float* wt = W_tok + (size_t)vv*DD + w_id*8;
          float s8 = 0.f;
          #pragma unroll
          for (int q8 = 0; q8 < 8; ++q8) s8 += AH[q8*64 + lane] * wt[q8];
          atomicAdd(&out[((size_t)lane*TT + te)*VV + vv], s8);
        }
        __syncthreads();
      }

      // (E) GRU1(s) -> h1(s)
      if (s < TT) {
        stage64_coh(h0b + (size_t)(s&1)*BBDD, SM, tid);
        __syncthreads();
        wave_dots(SM, W_ih1, b_ih1, GHX, w_id, wv, lane);
        __syncthreads();
        const int d = w_id*8 + dl;
        float gir = GHX[(0*8 + dl)*64 + bb_], ghr = GH1[(0*8 + dl)*64 + bb_];
        float giz = GHX[(1*8 + dl)*64 + bb_], ghz = GH1[(1*8 + dl)*64 + bb_];
        float gin = GHX[(2*8 + dl)*64 + bb_], ghn = GH1[(2*8 + dl)*64 + bb_];
        float r_ = sigmoidf_(gir + ghr), z_ = sigmoidf_(giz + ghz);
        float n_ = tanhf(gin + r_*ghn);
        coh_store1(&h1b[(size_t)(s % 3)*BBDD + (size_t)bb_*DD + d], (1.f - z_)*n_ + z_*h1old);
      }

      gridbar(gslot, gflag, bid, tid, (unsigned)(t + 3));
    }
  }
}

extern "C" void kernel_launch(void* const* d_in, const int* in_sizes, int n_in,
                              void* d_out, int out_size, void* d_ws, size_t ws_size,
                              hipStream_t stream) {
  const float* h_init = (const float*)d_in[0];
  const int*   targets= (const int*)d_in[1];
  const float* mem    = (const float*)d_in[2];
  const float* W_ih0  = (const float*)d_in[3];
  const float* W_hh0  = (const float*)d_in[4];
  const float* b_ih0  = (const float*)d_in[5];
  const float* b_hh0  = (const float*)d_in[6];
  const float* W_ih1  = (const float*)d_in[7];
  const float* W_hh1  = (const float*)d_in[8];
  const float* b_ih1  = (const float*)d_in[9];
  const float* b_hh1  = (const float*)d_in[10];
  const float* W_out  = (const float*)d_in[11];
  const float* W_tok  = (const float*)d_in[12];
  const float* b_tok  = (const float*)d_in[13];
  float* out = (float*)d_out;
  float* ws  = (float*)d_ws;

  hipMemsetAsync(d_ws, 0, WS_SLOTS_UINTS * sizeof(unsigned), stream);

  void* args[] = { (void*)&h_init, (void*)&targets, (void*)&mem,
                   (void*)&W_ih0, (void*)&W_hh0, (void*)&b_ih0, (void*)&b_hh0,
                   (void*)&W_ih1, (void*)&W_hh1, (void*)&b_ih1, (void*)&b_hh1,
                   (void*)&W_out, (void*)&W_tok, (void*)&b_tok,
                   (void*)&out, (void*)&ws };
  if (ws_size >= WS_BF16_BYTES) {
    hipError_t err = hipLaunchCooperativeKernel((const void*)&speller_kernel<1>,
                                                dim3(NBLK), dim3(NTHR), args, 0, stream);
    if (err != hipSuccess)
      hipLaunchKernelGGL(speller_kernel<1>, dim3(NBLK), dim3(NTHR), 0, stream,
                         h_init, targets, mem, W_ih0, W_hh0, b_ih0, b_hh0,
                         W_ih1, W_hh1, b_ih1, b_hh1, W_out, W_tok, b_tok, out, ws);
  } else {
    hipError_t err = hipLaunchCooperativeKernel((const void*)&speller_kernel<0>,
                                                dim3(NBLK), dim3(NTHR), args, 0, stream);
    if (err != hipSuccess)
      hipLaunchKernelGGL(speller_kernel<0>, dim3(NBLK), dim3(NTHR), 0, stream,
                         h_init, targets, mem, W_ih0, W_hh0, b_ih0, b_hh0,
                         W_ih1, W_hh1, b_ih1, b_hh1, W_out, W_tok, b_tok, out, ws);
  }
}

// Round 5
// 27822.818 us; speedup vs baseline: 1.1309x; 1.0028x over previous
//
#include <hip/hip_runtime.h>

#define NBLK 256
#define NTHR 512
#define BB 64
#define TT 200
#define SS 1024
#define DD 512
#define VV 30
#define BBDD (BB*DD)          // 32768
#define CPN  (BB*3*DD)        // 98304
#define MLNF 512              // ml floats per parity

// ---- workspace uint/float offsets ----
// gslot[256*32], gbf[256*32], wslot[64*32], wbf[64*32]  (128B-spaced slots)
#define WS_GSLOT 0
#define WS_GBF   (256*32)
#define WS_WSLOT (512*32)
#define WS_WBF   (576*32)
#define WS_SLOTS_UINTS (640*32)             // 20480
#define WS_H0   20480                       // [2][64][512]
#define WS_H1   (WS_H0 + 2*BBDD)            // [3][64][512]
#define WS_CB   (WS_H1 + 3*BBDD)            // [64][512]
#define WS_CP   (WS_CB + BBDD)              // [2][64*3][512]
#define WS_ML   (WS_CP + 2*CPN)             // [2][512]
#define WS_MB16 416000                      // bf16 mem mirror (ushort)
#define WS_BF16_BYTES ((size_t)WS_MB16*4 + (size_t)BB*SS*DD*2)

typedef __attribute__((ext_vector_type(4))) float f4;
typedef __attribute__((ext_vector_type(4))) unsigned int u4v;
typedef unsigned short ushortT;

__device__ __forceinline__ float dot4(f4 a, f4 b) {
  return a.x*b.x + a.y*b.y + a.z*b.z + a.w*b.w;
}
__device__ __forceinline__ float sigmoidf_(float x) { return 1.f/(1.f + __expf(-x)); }
__device__ __forceinline__ int minI(int a, int b) { return a < b ? a : b; }
__device__ __forceinline__ float bf2f(unsigned int u) { return __uint_as_float(u << 16); }

// ======== coherent (agent-scope, L2-bypass) access helpers ========
__device__ __forceinline__ void coh_store1(float* p, float v) {
  asm volatile("global_store_dword %0, %1, off sc0 sc1" :: "v"(p), "v"(v) : "memory");
}
__device__ __forceinline__ void coh_store16(void* p, u4v v) {
  asm volatile("global_store_dwordx4 %0, %1, off sc0 sc1" :: "v"(p), "v"(v) : "memory");
}
__device__ __forceinline__ void coh_load3(const float* p0, const float* p1, const float* p2,
                                          float& r0, float& r1, float& r2) {
  asm volatile(
    "global_load_dword %0, %3, off sc0 sc1\n\t"
    "global_load_dword %1, %4, off sc0 sc1\n\t"
    "global_load_dword %2, %5, off sc0 sc1\n\t"
    "s_waitcnt vmcnt(0)"
    : "=&v"(r0), "=&v"(r1), "=&v"(r2)
    : "v"(p0), "v"(p1), "v"(p2) : "memory");
}
__device__ __forceinline__ void coh_load2x4(const float* p, f4& a, f4& b) {
  asm volatile(
    "global_load_dwordx4 %0, %2, off sc0 sc1\n\t"
    "global_load_dwordx4 %1, %3, off sc0 sc1\n\t"
    "s_waitcnt vmcnt(0)"
    : "=&v"(a), "=&v"(b)
    : "v"(p), "v"(p + 4) : "memory");
}
__device__ __forceinline__ void coh_load8x4(const float* g, int stridef, f4 (&r)[8]) {
  const float *a1 = g +   (size_t)stridef, *a2 = g + 2*(size_t)stridef,
              *a3 = g + 3*(size_t)stridef, *a4 = g + 4*(size_t)stridef,
              *a5 = g + 5*(size_t)stridef, *a6 = g + 6*(size_t)stridef,
              *a7 = g + 7*(size_t)stridef;
  asm volatile(
    "global_load_dwordx4 %0, %8, off sc0 sc1\n\t"
    "global_load_dwordx4 %1, %9, off sc0 sc1\n\t"
    "global_load_dwordx4 %2, %10, off sc0 sc1\n\t"
    "global_load_dwordx4 %3, %11, off sc0 sc1\n\t"
    "global_load_dwordx4 %4, %12, off sc0 sc1\n\t"
    "global_load_dwordx4 %5, %13, off sc0 sc1\n\t"
    "global_load_dwordx4 %6, %14, off sc0 sc1\n\t"
    "global_load_dwordx4 %7, %15, off sc0 sc1\n\t"
    "s_waitcnt vmcnt(0)"
    : "=&v"(r[0]), "=&v"(r[1]), "=&v"(r[2]), "=&v"(r[3]),
      "=&v"(r[4]), "=&v"(r[5]), "=&v"(r[6]), "=&v"(r[7])
    : "v"(g), "v"(a1), "v"(a2), "v"(a3), "v"(a4), "v"(a5), "v"(a6), "v"(a7)
    : "memory");
}

// coherent reg-staged copy: global [64][512] -> LDS [64][516]
__device__ __forceinline__ void stage64_coh(const float* __restrict__ src, float* TILE, int tid) {
  f4 r[8];
  const int c4 = (tid & 127) * 4;
  const int rb = tid >> 7;
  coh_load8x4(src + (size_t)tid*4, 2048, r);
  #pragma unroll
  for (int k = 0; k < 8; ++k) *(f4*)&TILE[(rb + 4*k)*516 + c4] = r[k];
  coh_load8x4(src + (size_t)tid*4 + 8*2048, 2048, r);
  #pragma unroll
  for (int k = 0; k < 8; ++k) *(f4*)&TILE[(rb + 4*(k+8))*516 + c4] = r[k];
}

// ======== cached async staging (read-only data) ========
__device__ __forceinline__ void gl_lds16(const void* g, void* l) {
  __builtin_amdgcn_global_load_lds(
      (const __attribute__((address_space(1))) unsigned int*)g,
      (__attribute__((address_space(3))) unsigned int*)l,
      16, 0, 0);
}
__device__ __forceinline__ void stage_att_f32(float* dst, const float* src, int R, int wv, int lane) {
  #pragma unroll
  for (int rr = 0; rr < 4; ++rr) {
    const int row = wv*4 + rr;
    if (row < R) {
      const float* g = src + (size_t)row*DD + lane*4;
      gl_lds16(g,       dst + row*DD);
      gl_lds16(g + 256, dst + row*DD + 256);
    }
  }
}
__device__ __forceinline__ void stage_att_bf(char* dstb, const ushortT* src, int R, int wv, int lane) {
  #pragma unroll
  for (int rr = 0; rr < 4; ++rr) {
    const int row = wv*4 + rr;
    if (row < R)
      gl_lds16(src + (size_t)row*512 + lane*8, dstb + row*1024);
  }
}

// wave-column GRU dot
__device__ __forceinline__ void wave_dots(const float* TILE, const float* W, const float* bias,
                                          float* GH, int w_id, int wv, int lane) {
  const int c0 = wv*3, c1 = c0+1, c2 = c0+2;
  const int R0 = __builtin_amdgcn_readfirstlane(((c0>>3)<<9) + w_id*8 + (c0&7));
  const int R1 = __builtin_amdgcn_readfirstlane(((c1>>3)<<9) + w_id*8 + (c1&7));
  const int R2 = __builtin_amdgcn_readfirstlane(((c2>>3)<<9) + w_id*8 + (c2&7));
  const f4* w0 = (const f4*)(W + (size_t)R0*DD);
  const f4* w1 = (const f4*)(W + (size_t)R1*DD);
  const f4* w2 = (const f4*)(W + (size_t)R2*DD);
  const f4* hv4 = (const f4*)TILE + (size_t)lane*129;
  float a0=0.f, a1=0.f, a2=0.f;
  #pragma unroll 4
  for (int kq = 0; kq < 128; ++kq) {
    f4 h = hv4[kq];
    a0 += dot4(h, w0[kq]); a1 += dot4(h, w1[kq]); a2 += dot4(h, w2[kq]);
  }
  GH[c0*64 + lane] = a0 + bias[R0];
  GH[c1*64 + lane] = a1 + bias[R1];
  GH[c2*64 + lane] = a2 + bias[R2];
}

// ======== contention-free barriers: per-waiter flag lines + fan-out broadcast ========
// gridbar: block 0 aggregates 256 arrival slots, then threads 1..255 each store the
// release to waiter bid's PRIVATE flag line (128B spacing -> no same-line polling).
__device__ __forceinline__ void gridbar(unsigned* gslot, unsigned* gbf,
                                        int bid, int tid, unsigned target) {
  __syncthreads();
  if (tid == 0)
    __hip_atomic_store(&gslot[bid*32], target, __ATOMIC_RELAXED, __HIP_MEMORY_SCOPE_AGENT);
  if (bid == 0) {
    if (tid < 64) {
      for (;;) {
        unsigned v0 = __hip_atomic_load(&gslot[(tid      )*32], __ATOMIC_RELAXED, __HIP_MEMORY_SCOPE_AGENT);
        unsigned v1 = __hip_atomic_load(&gslot[(tid +  64)*32], __ATOMIC_RELAXED, __HIP_MEMORY_SCOPE_AGENT);
        unsigned v2 = __hip_atomic_load(&gslot[(tid + 128)*32], __ATOMIC_RELAXED, __HIP_MEMORY_SCOPE_AGENT);
        unsigned v3 = __hip_atomic_load(&gslot[(tid + 192)*32], __ATOMIC_RELAXED, __HIP_MEMORY_SCOPE_AGENT);
        if (__all(v0 >= target && v1 >= target && v2 >= target && v3 >= target)) break;
        __builtin_amdgcn_s_sleep(2);
      }
    }
    __syncthreads();
    if (tid >= 1 && tid < 256)
      __hip_atomic_store(&gbf[tid*32], target, __ATOMIC_RELAXED, __HIP_MEMORY_SCOPE_AGENT);
  } else if (tid == 0) {
    while (__hip_atomic_load(&gbf[bid*32], __ATOMIC_RELAXED, __HIP_MEMORY_SCOPE_AGENT) < target)
      __builtin_amdgcn_s_sleep(4);
  }
  __syncthreads();
}

// groupbar among worker blocks 192..255 (aggregator = 192), same scheme.
__device__ __forceinline__ void groupbar(unsigned* wslot, unsigned* wbf,
                                         int bid, int tid, unsigned target) {
  __syncthreads();
  if (tid == 0)
    __hip_atomic_store(&wslot[(bid-192)*32], target, __ATOMIC_RELAXED, __HIP_MEMORY_SCOPE_AGENT);
  if (bid == 192) {
    if (tid < 64) {
      for (;;) {
        unsigned v = __hip_atomic_load(&wslot[tid*32], __ATOMIC_RELAXED, __HIP_MEMORY_SCOPE_AGENT);
        if (__all(v >= target)) break;
        __builtin_amdgcn_s_sleep(2);
      }
    }
    __syncthreads();
    if (tid >= 1 && tid < 64)
      __hip_atomic_store(&wbf[tid*32], target, __ATOMIC_RELAXED, __HIP_MEMORY_SCOPE_AGENT);
  } else if (tid == 0) {
    while (__hip_atomic_load(&wbf[(bid-192)*32], __ATOMIC_RELAXED, __HIP_MEMORY_SCOPE_AGENT) < target)
      __builtin_amdgcn_s_sleep(4);
  }
  __syncthreads();
}

__device__ __forceinline__ unsigned bfr_(float x) {
  unsigned u = __float_as_uint(x);
  return (u + 0x7fffu + ((u >> 16) & 1u)) >> 16;   // RNE f32->bf16
}

template<int MB16>
__launch_bounds__(NTHR, 1)
__global__ void speller_kernel(const float* __restrict__ h_init,
                               const int*   __restrict__ targets,
                               const float* __restrict__ mem,
                               const float* __restrict__ W_ih0,
                               const float* __restrict__ W_hh0,
                               const float* __restrict__ b_ih0,
                               const float* __restrict__ b_hh0,
                               const float* __restrict__ W_ih1,
                               const float* __restrict__ W_hh1,
                               const float* __restrict__ b_ih1,
                               const float* __restrict__ b_hh1,
                               const float* __restrict__ W_out,
                               const float* __restrict__ W_tok,
                               const float* __restrict__ b_tok,
                               float*       __restrict__ out,
                               float*       __restrict__ ws)
{
  __shared__ float SM[36896];
  float* const GH1 = SM + 33024;   // gh1 columns [24][64]
  float* const GHX = SM + 34560;   // scratch gate columns [24][64]
  float* const AH  = SM + 36096;   // attn_h components [8][64]
  int*   const TOK = (int*)(SM + 36608);
  float* const CP  = SM + 32768;   // attention per-wave partials [8][512]
  float* const ML2 = SM + 36864;

  const int tid  = threadIdx.x;
  const int bid  = blockIdx.x;
  const int lane = tid & 63;
  const int wv   = tid >> 6;

  unsigned* const gslot = (unsigned*)ws + WS_GSLOT;
  unsigned* const gbf   = (unsigned*)ws + WS_GBF;
  unsigned* const wslot = (unsigned*)ws + WS_WSLOT;
  unsigned* const wbf   = (unsigned*)ws + WS_WBF;

  float* const h0b   = ws + WS_H0;
  float* const h1b   = ws + WS_H1;
  float* const cb    = ws + WS_CB;
  float* const cpart = ws + WS_CP;
  float* const mlp   = ws + WS_ML;
  ushortT* const mb16 = (ushortT*)(ws + WS_MB16);

  for (int i = tid; i < 36896; i += NTHR) SM[i] = 0.f;
  __syncthreads();

  // ---- prologue: convert mem -> bf16 mirror (write-through) ----
  if (MB16) {
    const size_t total = (size_t)BB*SS*DD;
    for (size_t i = ((size_t)bid*NTHR + tid)*8; i < total; i += (size_t)NBLK*NTHR*8) {
      f4 a = *(const f4*)(mem + i);
      f4 b = *(const f4*)(mem + i + 4);
      u4v d;
      d.x = bfr_(a.x) | (bfr_(a.y) << 16);
      d.y = bfr_(a.z) | (bfr_(a.w) << 16);
      d.z = bfr_(b.x) | (bfr_(b.y) << 16);
      d.w = bfr_(b.z) | (bfr_(b.w) << 16);
      coh_store16(mb16 + i, d);
    }
  }
  gridbar(gslot, gbf, bid, tid, 1u);
  if (MB16) {
    asm volatile("s_waitcnt vmcnt(0) lgkmcnt(0)\n\tbuffer_inv" ::: "memory");
    __syncthreads();
  }

  for (int t = -1; t <= TT; ++t) {
    if (bid < 192) {
      // ================= ATTENTION BLOCKS (step t) =================
      if (t >= 0 && t < TT) {
        const int b  = bid / 3;
        const int ch = bid - 3*b;
        const int r0 = (ch == 0) ? 0 : 342 + (ch-1)*341;
        const int CNT = (ch == 0) ? 342 : 341;
        const int NTL = (CNT + 31) >> 5;
        const int seg = lane & 15;
        const int rr4 = lane >> 4;
        const float* qsrc = h1b + (size_t)(t % 3)*BBDD + (size_t)b*DD;
        f4 q4[8];
        if (MB16) coh_load8x4(qsrc + seg*32, 4, q4);     // contiguous 32 floats
        else      coh_load8x4(qsrc + seg*4, 64, q4);     // strided (f32 layout)

        float m_run = -3e38f, l_run = 0.f;
        float cacc[8];
        #pragma unroll
        for (int j = 0; j < 8; ++j) cacc[j] = 0.f;

        int buf = 0;
        const float*   msrcF = mem  + ((size_t)b*SS + r0)*DD;
        const ushortT* msrcB = mb16 + ((size_t)b*SS + r0)*DD;
        if (MB16) stage_att_bf((char*)SM, msrcB, minI(32, CNT), wv, lane);
        else      stage_att_f32(SM, msrcF, minI(32, CNT), wv, lane);
        __syncthreads();

        for (int tl = 0; tl < NTL; ++tl) {
          const int Rcur = minI(32, CNT - tl*32);
          if (tl + 1 < NTL) {
            if (MB16) stage_att_bf((char*)SM + (buf^1)*32768, msrcB + (size_t)(tl+1)*32*DD,
                                   minI(32, CNT - (tl+1)*32), wv, lane);
            else      stage_att_f32(SM + (buf^1)*16384, msrcF + (size_t)(tl+1)*32*DD,
                                    minI(32, CNT - (tl+1)*32), wv, lane);
          }
          const int r = wv*4 + rr4;
          float sc = 0.f;
          if (MB16) {
            const char* bbufb = (const char*)SM + buf*32768;
            if (r < Rcur) {
              const u4v* rp = (const u4v*)(bbufb + r*1024 + seg*64);
              const float* qq = (const float*)q4;
              #pragma unroll
              for (int jj = 0; jj < 4; ++jj) {
                u4v u = rp[jj];
                sc += __uint_as_float(u.x << 16)           * qq[jj*8+0]
                    + __uint_as_float(u.x & 0xffff0000u)   * qq[jj*8+1]
                    + __uint_as_float(u.y << 16)           * qq[jj*8+2]
                    + __uint_as_float(u.y & 0xffff0000u)   * qq[jj*8+3]
                    + __uint_as_float(u.z << 16)           * qq[jj*8+4]
                    + __uint_as_float(u.z & 0xffff0000u)   * qq[jj*8+5]
                    + __uint_as_float(u.w << 16)           * qq[jj*8+6]
                    + __uint_as_float(u.w & 0xffff0000u)   * qq[jj*8+7];
              }
            }
          } else {
            const float* bbuf = SM + buf*16384;
            if (r < Rcur) {
              const f4* rb = (const f4*)(bbuf + (size_t)r*DD);
              #pragma unroll
              for (int jj = 0; jj < 8; ++jj) sc += dot4(rb[seg + 16*jj], q4[jj]);
            }
          }
          sc += __shfl_xor(sc, 1);
          sc += __shfl_xor(sc, 2);
          sc += __shfl_xor(sc, 4);
          sc += __shfl_xor(sc, 8);
          const int rb0 = wv*4;
          float s0 = __shfl(sc, 0), s1 = __shfl(sc, 16), s2 = __shfl(sc, 32), s3 = __shfl(sc, 48);
          float sv0 = (rb0+0 < Rcur) ? s0 : -3e38f;
          float sv1 = (rb0+1 < Rcur) ? s1 : -3e38f;
          float sv2 = (rb0+2 < Rcur) ? s2 : -3e38f;
          float sv3 = (rb0+3 < Rcur) ? s3 : -3e38f;
          float m_tile = fmaxf(fmaxf(sv0, sv1), fmaxf(sv2, sv3));
          float m_new  = fmaxf(m_run, m_tile);
          float esc    = __expf(m_run - m_new);
          float w0 = (rb0+0 < Rcur) ? __expf(s0 - m_new) : 0.f;
          float w1 = (rb0+1 < Rcur) ? __expf(s1 - m_new) : 0.f;
          float w2 = (rb0+2 < Rcur) ? __expf(s2 - m_new) : 0.f;
          float w3 = (rb0+3 < Rcur) ? __expf(s3 - m_new) : 0.f;
          l_run = l_run*esc + (w0 + w1) + (w2 + w3);
          m_run = m_new;
          if (MB16) {
            const ushortT* bu = (const ushortT*)((const char*)SM + buf*32768);
            #pragma unroll
            for (int j = 0; j < 8; ++j) {
              const int kk = j*64 + lane;
              float a = cacc[j]*esc;
              a += w0 * bf2f(bu[(rb0+0)*512 + kk]);
              a += w1 * bf2f(bu[(rb0+1)*512 + kk]);
              a += w2 * bf2f(bu[(rb0+2)*512 + kk]);
              a += w3 * bf2f(bu[(rb0+3)*512 + kk]);
              cacc[j] = a;
            }
          } else {
            const float* bbuf = SM + buf*16384;
            #pragma unroll
            for (int j = 0; j < 8; ++j) {
              const int kk = j*64 + lane;
              float a = cacc[j]*esc;
              a += w0*bbuf[(rb0+0)*DD + kk];
              a += w1*bbuf[(rb0+1)*DD + kk];
              a += w2*bbuf[(rb0+2)*DD + kk];
              a += w3*bbuf[(rb0+3)*DD + kk];
              cacc[j] = a;
            }
          }
          __syncthreads();
          buf ^= 1;
        }
        #pragma unroll
        for (int j = 0; j < 8; ++j) CP[wv*DD + j*64 + lane] = cacc[j];
        if (lane == 0) { ML2[wv*2] = m_run; ML2[wv*2+1] = l_run; }
        __syncthreads();
        float M = -3e38f;
        #pragma unroll
        for (int w = 0; w < 8; ++w) M = fmaxf(M, ML2[w*2]);
        float lsum = 0.f, ck = 0.f;
        #pragma unroll
        for (int w = 0; w < 8; ++w) {
          float ew = __expf(ML2[w*2] - M);
          lsum += ew*ML2[w*2+1];
          ck   += ew*CP[w*DD + tid];
        }
        const int par = t & 1;
        coh_store1(&cpart[(size_t)par*CPN + ((size_t)(b*3+ch))*DD + tid], ck);
        if (tid == 0) {
          coh_store1(&mlp[par*MLNF + b*8 + ch*2],     M);
          coh_store1(&mlp[par*MLNF + b*8 + ch*2 + 1], lsum);
        }
      }
      gridbar(gslot, gbf, bid, tid, (unsigned)(t + 3));
    } else {
      // ================= WORKER BLOCKS (192..255) =================
      const int w_id = bid - 192;
      const int s  = t + 1;   // GRU step produced this iteration
      const int te = t - 1;   // emit step finalized this iteration
      const int dl = tid >> 6;
      const int bb_ = tid & 63;
      float h1old = 0.f;

      // (A) combine(te) -> cb, out bias init
      if (te >= 0) {
        const int par2 = te & 1;
        f4 mA, mB;
        coh_load2x4(mlp + par2*MLNF + w_id*8, mA, mB);
        float M = fmaxf(fmaxf(mA.x, mA.z), mB.x);
        float e0 = __expf(mA.x - M), e1 = __expf(mA.z - M), e2 = __expf(mB.x - M);
        float invL = 1.f / (e0*mA.y + e1*mA.w + e2*mB.y);
        const float* cp = cpart + (size_t)par2*CPN + (size_t)w_id*3*DD;
        float c0, c1, c2;
        coh_load3(cp + tid, cp + DD + tid, cp + 2*DD + tid, c0, c1, c2);
        float c = (e0*c0 + e1*c1 + e2*c2) * invL;
        coh_store1(&cb[(size_t)w_id*DD + tid], c);
        if (tid < VV) coh_store1(&out[((size_t)w_id*TT + te)*VV + tid], b_tok[tid]);
      }

      // (B) gh1(s) from h1(s-1)
      if (s < TT) {
        if (tid < 64) TOK[tid] = targets[tid*TT + (s == 0 ? 0 : s - 1)];
        const float* h1src = (s == 0) ? (h_init + BBDD) : (h1b + (size_t)(((s-1) % 3))*BBDD);
        stage64_coh(h1src, SM, tid);
        __syncthreads();
        wave_dots(SM, W_hh1, b_hh1, GH1, w_id, wv, lane);
        h1old = SM[bb_*516 + w_id*8 + dl];
        __syncthreads();
      }

      // (D) GRU0(s) -> h0(s)
      if (s < TT) {
        const float* h0src = (s == 0) ? h_init : (h0b + (size_t)((s-1)&1)*BBDD);
        stage64_coh(h0src, SM, tid);
        __syncthreads();
        wave_dots(SM, W_hh0, b_hh0, GHX, w_id, wv, lane);
        __syncthreads();
        const int d = w_id*8 + dl;
        const int tok = TOK[bb_];
        float gir = W_ih0[(size_t)d*VV + tok]          + b_ih0[d];
        float giz = W_ih0[(size_t)(DD + d)*VV + tok]   + b_ih0[DD + d];
        float gin = W_ih0[(size_t)(2*DD + d)*VV + tok] + b_ih0[2*DD + d];
        float ghr = GHX[(0*8 + dl)*64 + bb_];
        float ghz = GHX[(1*8 + dl)*64 + bb_];
        float ghn = GHX[(2*8 + dl)*64 + bb_];
        float r_ = sigmoidf_(gir + ghr), z_ = sigmoidf_(giz + ghz);
        float n_ = tanhf(gin + r_*ghn);
        float h0old = SM[bb_*516 + d];
        coh_store1(&h0b[(size_t)(s&1)*BBDD + (size_t)bb_*DD + d], (1.f - z_)*n_ + z_*h0old);
      }

      groupbar(wslot, wbf, bid, tid, (unsigned)(t + 2));

      // (C) output(te)
      if (te >= 0) {
        stage64_coh(cb, SM, tid);
        __syncthreads();
        float acc = 0.f;
        const f4* hv4 = (const f4*)SM + (size_t)lane*129;
        const int orow = __builtin_amdgcn_readfirstlane(w_id*8 + wv);
        const f4* wo = (const f4*)(W_out + (size_t)orow*(2*DD));
        #pragma unroll 4
        for (int kq = 0; kq < 128; ++kq) acc += dot4(hv4[kq], wo[kq]);
        __syncthreads();
        stage64_coh(h1b + (size_t)(te % 3)*BBDD, SM, tid);
        __syncthreads();
        #pragma unroll 4
        for (int kq = 0; kq < 128; ++kq) acc += dot4(hv4[kq], wo[128 + kq]);
        AH[wv*64 + lane] = tanhf(acc);
        __syncthreads();
        for (int v = wv; v < VV; v += 8) {
          const int vv = __builtin_amdgcn_readfirstlane(v);
          const float* wt = W_tok + (size_t)vv*DD + w_id*8;
          float s8 = 0.f;
          #pragma unroll
          for (int q8 = 0; q8 < 8; ++q8) s8 += AH[q8*64 + lane] * wt[q8];
          atomicAdd(&out[((size_t)lane*TT + te)*VV + vv], s8);
        }
        __syncthreads();
      }

      // (E) GRU1(s) -> h1(s)
      if (s < TT) {
        stage64_coh(h0b + (size_t)(s&1)*BBDD, SM, tid);
        __syncthreads();
        wave_dots(SM, W_ih1, b_ih1, GHX, w_id, wv, lane);
        __syncthreads();
        const int d = w_id*8 + dl;
        float gir = GHX[(0*8 + dl)*64 + bb_], ghr = GH1[(0*8 + dl)*64 + bb_];
        float giz = GHX[(1*8 + dl)*64 + bb_], ghz = GH1[(1*8 + dl)*64 + bb_];
        float gin = GHX[(2*8 + dl)*64 + bb_], ghn = GH1[(2*8 + dl)*64 + bb_];
        float r_ = sigmoidf_(gir + ghr), z_ = sigmoidf_(giz + ghz);
        float n_ = tanhf(gin + r_*ghn);
        coh_store1(&h1b[(size_t)(s % 3)*BBDD + (size_t)bb_*DD + d], (1.f - z_)*n_ + z_*h1old);
      }

      gridbar(gslot, gbf, bid, tid, (unsigned)(t + 3));
    }
  }
}

extern "C" void kernel_launch(void* const* d_in, const int* in_sizes, int n_in,
                              void* d_out, int out_size, void* d_ws, size_t ws_size,
                              hipStream_t stream) {
  const float* h_init = (const float*)d_in[0];
  const int*   targets= (const int*)d_in[1];
  const float* mem    = (const float*)d_in[2];
  const float* W_ih0  = (const float*)d_in[3];
  const float* W_hh0  = (const float*)d_in[4];
  const float* b_ih0  = (const float*)d_in[5];
  const float* b_hh0  = (const float*)d_in[6];
  const float* W_ih1  = (const float*)d_in[7];
  const float* W_hh1  = (const float*)d_in[8];
  const float* b_ih1  = (const float*)d_in[9];
  const float* b_hh1  = (const float*)d_in[10];
  const float* W_out  = (const float*)d_in[11];
  const float* W_tok  = (const float*)d_in[12];
  const float* b_tok  = (const float*)d_in[13];
  float* out = (float*)d_out;
  float* ws  = (float*)d_ws;

  hipMemsetAsync(d_ws, 0, WS_SLOTS_UINTS * sizeof(unsigned), stream);

  void* args[] = { (void*)&h_init, (void*)&targets, (void*)&mem,
                   (void*)&W_ih0, (void*)&W_hh0, (void*)&b_ih0, (void*)&b_hh0,
                   (void*)&W_ih1, (void*)&W_hh1, (void*)&b_ih1, (void*)&b_hh1,
                   (void*)&W_out, (void*)&W_tok, (void*)&b_tok,
                   (void*)&out, (void*)&ws };
  if (ws_size >= WS_BF16_BYTES) {
    hipError_t err = hipLaunchCooperativeKernel((const void*)&speller_kernel<1>,
                                                dim3(NBLK), dim3(NTHR), args, 0, stream);
    if (err != hipSuccess)
      hipLaunchKernelGGL(speller_kernel<1>, dim3(NBLK), dim3(NTHR), 0, stream,
                         h_init, targets, mem, W_ih0, W_hh0, b_ih0, b_hh0,
                         W_ih1, W_hh1, b_ih1, b_hh1, W_out, W_tok, b_tok, out, ws);
  } else {
    hipError_t err = hipLaunchCooperativeKernel((const void*)&speller_kernel<0>,
                                                dim3(NBLK), dim3(NTHR), args, 0, stream);
    if (err != hipSuccess)
      hipLaunchKernelGGL(speller_kernel<0>, dim3(NBLK), dim3(NTHR), 0, stream,
                         h_init, targets, mem, W_ih0, W_hh0, b_ih0, b_hh0,
                         W_ih1, W_hh1, b_ih1, b_hh1, W_out, W_tok, b_tok, out, ws);
  }
}

// Round 6
// 27250.143 us; speedup vs baseline: 1.1547x; 1.0210x over previous
//
#include <hip/hip_runtime.h>

#define TT 200
#define SS 1024
#define DD 512
#define VV 30
#define BB 64
#define BBDD (BB*DD)              // 32768

// ---- ws float offsets ----
#define WS_H0 0                   // [2][64][512]
#define WS_H1 (2*BBDD)            // [2][64][512]
#define WS_CP (4*BBDD)            // [64*3][512]
#define WS_ML (WS_CP + 3*BB*DD)   // [64*3][2]
#define WS_MB16 230400            // ushort bf16 mirror of mem
#define WS_NEED_BYTES ((size_t)WS_MB16*4 + (size_t)BB*SS*DD*2)

typedef __attribute__((ext_vector_type(4))) float f4;
typedef __attribute__((ext_vector_type(4))) unsigned int u4v;
typedef unsigned short ushortT;

__device__ __forceinline__ float dot4(f4 a, f4 b) {
  return a.x*b.x + a.y*b.y + a.z*b.z + a.w*b.w;
}
__device__ __forceinline__ float sigmoidf_(float x) { return 1.f/(1.f + __expf(-x)); }
__device__ __forceinline__ int minI(int a, int b) { return a < b ? a : b; }
__device__ __forceinline__ float bf2f(unsigned int u) { return __uint_as_float(u << 16); }
__device__ __forceinline__ unsigned bfr_(float x) {
  unsigned u = __float_as_uint(x);
  return (u + 0x7fffu + ((u >> 16) & 1u)) >> 16;   // RNE f32->bf16
}

__device__ __forceinline__ void gl_lds16(const void* g, void* l) {
  __builtin_amdgcn_global_load_lds(
      (const __attribute__((address_space(1))) unsigned int*)g,
      (__attribute__((address_space(3))) unsigned int*)l,
      16, 0, 0);
}

// async global [64][512] -> LDS [64][516] ; follow with __syncthreads()
__device__ __forceinline__ void stage64(const float* src, float* TILE, int wv, int lane) {
  #pragma unroll
  for (int rr = 0; rr < 8; ++rr) {
    const int row = wv*8 + rr;
    const float* g = src + (size_t)row*DD + lane*4;
    gl_lds16(g,       TILE + row*516);
    gl_lds16(g + 256, TILE + row*516 + 256);
  }
}

// wave-column GRU dots: wave wv computes 3 gate-columns for dims w_id*8..+7
__device__ __forceinline__ void wave_dots(const float* TILE, const float* W, const float* bias,
                                          float* GH, int w_id, int wv, int lane) {
  const int c0 = wv*3, c1 = c0+1, c2 = c0+2;
  const int R0 = __builtin_amdgcn_readfirstlane(((c0>>3)<<9) + w_id*8 + (c0&7));
  const int R1 = __builtin_amdgcn_readfirstlane(((c1>>3)<<9) + w_id*8 + (c1&7));
  const int R2 = __builtin_amdgcn_readfirstlane(((c2>>3)<<9) + w_id*8 + (c2&7));
  const f4* w0 = (const f4*)(W + (size_t)R0*DD);
  const f4* w1 = (const f4*)(W + (size_t)R1*DD);
  const f4* w2 = (const f4*)(W + (size_t)R2*DD);
  const f4* hv4 = (const f4*)TILE + (size_t)lane*129;
  float a0=0.f, a1=0.f, a2=0.f;
  #pragma unroll 4
  for (int kq = 0; kq < 128; ++kq) {
    f4 h = hv4[kq];
    a0 += dot4(h, w0[kq]); a1 += dot4(h, w1[kq]); a2 += dot4(h, w2[kq]);
  }
  GH[c0*64 + lane] = a0 + bias[R0];
  GH[c1*64 + lane] = a1 + bias[R1];
  GH[c2*64 + lane] = a2 + bias[R2];
}

// ================= prologue: bf16 mirror + out bias init =================
template<int MB16>
__launch_bounds__(512, 1)
__global__ void k_prep(const float* __restrict__ mem, ushortT* __restrict__ mb16,
                       const float* __restrict__ b_tok, float* __restrict__ out) {
  const int gid = blockIdx.x*512 + threadIdx.x;
  if (MB16) {
    const size_t total = (size_t)BB*SS*DD;
    for (size_t i = (size_t)gid*8; i < total; i += (size_t)gridDim.x*512*8) {
      f4 a = *(const f4*)(mem + i);
      f4 b = *(const f4*)(mem + i + 4);
      u4v d;
      d.x = bfr_(a.x) | (bfr_(a.y) << 16);
      d.y = bfr_(a.z) | (bfr_(a.w) << 16);
      d.z = bfr_(b.x) | (bfr_(b.y) << 16);
      d.w = bfr_(b.z) | (bfr_(b.w) << 16);
      *(u4v*)(mb16 + i) = d;
    }
  }
  for (int i = gid; i < BB*TT*VV; i += gridDim.x*512)
    out[i] = b_tok[i % VV];
}

// ================= GRU layer 0 (64 blocks x 512) =================
__launch_bounds__(512, 1)
__global__ void k_gru0(const float* __restrict__ h0prev, const int* __restrict__ targets,
                       const float* __restrict__ W_ih0, const float* __restrict__ W_hh0,
                       const float* __restrict__ b_ih0, const float* __restrict__ b_hh0,
                       float* __restrict__ h0out, int tokcol) {
  __shared__ float SM[34560];
  float* const TILE = SM;
  float* const GHX  = SM + 33024;
  const int tid = threadIdx.x, bid = blockIdx.x;
  const int lane = tid & 63, wv = tid >> 6;
  stage64(h0prev, TILE, wv, lane);
  __syncthreads();
  wave_dots(TILE, W_hh0, b_hh0, GHX, bid, wv, lane);
  __syncthreads();
  const int dl = tid >> 6, bb = tid & 63, d = bid*8 + dl;
  const int tok = targets[bb*TT + tokcol];
  float gir = W_ih0[(size_t)d*VV + tok]          + b_ih0[d];
  float giz = W_ih0[(size_t)(DD + d)*VV + tok]   + b_ih0[DD + d];
  float gin = W_ih0[(size_t)(2*DD + d)*VV + tok] + b_ih0[2*DD + d];
  float ghr = GHX[(0*8 + dl)*64 + bb];
  float ghz = GHX[(1*8 + dl)*64 + bb];
  float ghn = GHX[(2*8 + dl)*64 + bb];
  float r_ = sigmoidf_(gir + ghr), z_ = sigmoidf_(giz + ghz);
  float n_ = tanhf(gin + r_*ghn);
  float h0old = TILE[bb*516 + d];
  h0out[(size_t)bb*DD + d] = (1.f - z_)*n_ + z_*h0old;
}

// ================= GRU layer 1 (64 blocks x 512) =================
__launch_bounds__(512, 1)
__global__ void k_gru1(const float* __restrict__ h1prev, const float* __restrict__ h0cur,
                       const float* __restrict__ W_hh1, const float* __restrict__ W_ih1,
                       const float* __restrict__ b_hh1, const float* __restrict__ b_ih1,
                       float* __restrict__ h1out) {
  __shared__ float SM[36096];
  float* const TILE = SM;
  float* const GH1  = SM + 33024;
  float* const GHX  = SM + 34560;
  const int tid = threadIdx.x, bid = blockIdx.x;
  const int lane = tid & 63, wv = tid >> 6;
  const int dl = tid >> 6, bb = tid & 63, d = bid*8 + dl;

  stage64(h1prev, TILE, wv, lane);
  __syncthreads();
  wave_dots(TILE, W_hh1, b_hh1, GH1, bid, wv, lane);
  float h1old = TILE[bb*516 + d];
  __syncthreads();
  stage64(h0cur, TILE, wv, lane);
  __syncthreads();
  wave_dots(TILE, W_ih1, b_ih1, GHX, bid, wv, lane);
  __syncthreads();
  float gir = GHX[(0*8 + dl)*64 + bb], ghr = GH1[(0*8 + dl)*64 + bb];
  float giz = GHX[(1*8 + dl)*64 + bb], ghz = GH1[(1*8 + dl)*64 + bb];
  float gin = GHX[(2*8 + dl)*64 + bb], ghn = GH1[(2*8 + dl)*64 + bb];
  float r_ = sigmoidf_(gir + ghr), z_ = sigmoidf_(giz + ghz);
  float n_ = tanhf(gin + r_*ghn);
  h1out[(size_t)bb*DD + d] = (1.f - z_)*n_ + z_*h1old;
}

// ================= attention partials (192 blocks x 512) =================
template<int MB16>
__launch_bounds__(512, 1)
__global__ void k_attn(const float* __restrict__ h1cur, const float* __restrict__ mem,
                       const ushortT* __restrict__ mb16,
                       float* __restrict__ cpart, float* __restrict__ ml) {
  __shared__ float SM[36896];
  float* const CP  = SM + 32768;   // [8][512]
  float* const ML2 = SM + 36864;
  const int tid = threadIdx.x, bid = blockIdx.x;
  const int lane = tid & 63, wv = tid >> 6;

  const int b  = bid / 3;
  const int ch = bid - 3*b;
  const int r0 = (ch == 0) ? 0 : 342 + (ch-1)*341;
  const int CNT = (ch == 0) ? 342 : 341;
  const int NTL = (CNT + 31) >> 5;
  const int seg = lane & 15;
  const int rr4 = lane >> 4;
  const float* qsrc = h1cur + (size_t)b*DD;
  f4 q4[8];
  if (MB16) {
    #pragma unroll
    for (int j = 0; j < 8; ++j) q4[j] = *(const f4*)(qsrc + seg*32 + j*4);
  } else {
    #pragma unroll
    for (int j = 0; j < 8; ++j) q4[j] = *(const f4*)(qsrc + seg*4 + j*64);
  }

  float m_run = -3e38f, l_run = 0.f;
  float cacc[8];
  #pragma unroll
  for (int j = 0; j < 8; ++j) cacc[j] = 0.f;

  const float*   msrcF = mem  + ((size_t)b*SS + r0)*DD;
  const ushortT* msrcB = mb16 + ((size_t)b*SS + r0)*DD;
  int buf = 0;

  // stage first tile
  {
    const int R = minI(32, CNT);
    #pragma unroll
    for (int rr = 0; rr < 4; ++rr) {
      const int row = wv*4 + rr;
      if (row < R) {
        if (MB16) gl_lds16(msrcB + (size_t)row*DD + lane*8, (char*)SM + row*1024);
        else {
          const float* g = msrcF + (size_t)row*DD + lane*4;
          gl_lds16(g, SM + row*DD); gl_lds16(g + 256, SM + row*DD + 256);
        }
      }
    }
  }
  __syncthreads();

  for (int tl = 0; tl < NTL; ++tl) {
    const int Rcur = minI(32, CNT - tl*32);
    if (tl + 1 < NTL) {
      const int Rn = minI(32, CNT - (tl+1)*32);
      #pragma unroll
      for (int rr = 0; rr < 4; ++rr) {
        const int row = wv*4 + rr;
        if (row < Rn) {
          if (MB16) gl_lds16(msrcB + (size_t)(tl+1)*32*DD + (size_t)row*DD + lane*8,
                             (char*)SM + (buf^1)*32768 + row*1024);
          else {
            const float* g = msrcF + (size_t)(tl+1)*32*DD + (size_t)row*DD + lane*4;
            gl_lds16(g, SM + (buf^1)*16384 + row*DD);
            gl_lds16(g + 256, SM + (buf^1)*16384 + row*DD + 256);
          }
        }
      }
    }
    const int r = wv*4 + rr4;
    float sc = 0.f;
    if (MB16) {
      const char* bbufb = (const char*)SM + buf*32768;
      if (r < Rcur) {
        const u4v* rp = (const u4v*)(bbufb + r*1024 + seg*64);
        const float* qq = (const float*)q4;
        #pragma unroll
        for (int jj = 0; jj < 4; ++jj) {
          u4v u = rp[jj];
          sc += __uint_as_float(u.x << 16)         * qq[jj*8+0]
              + __uint_as_float(u.x & 0xffff0000u) * qq[jj*8+1]
              + __uint_as_float(u.y << 16)         * qq[jj*8+2]
              + __uint_as_float(u.y & 0xffff0000u) * qq[jj*8+3]
              + __uint_as_float(u.z << 16)         * qq[jj*8+4]
              + __uint_as_float(u.z & 0xffff0000u) * qq[jj*8+5]
              + __uint_as_float(u.w << 16)         * qq[jj*8+6]
              + __uint_as_float(u.w & 0xffff0000u) * qq[jj*8+7];
        }
      }
    } else {
      const float* bbuf = SM + buf*16384;
      if (r < Rcur) {
        const f4* rb = (const f4*)(bbuf + (size_t)r*DD);
        #pragma unroll
        for (int jj = 0; jj < 8; ++jj) sc += dot4(rb[seg + 16*jj], q4[jj]);
      }
    }
    sc += __shfl_xor(sc, 1);
    sc += __shfl_xor(sc, 2);
    sc += __shfl_xor(sc, 4);
    sc += __shfl_xor(sc, 8);
    const int rb0 = wv*4;
    float s0 = __shfl(sc, 0), s1 = __shfl(sc, 16), s2 = __shfl(sc, 32), s3 = __shfl(sc, 48);
    float sv0 = (rb0+0 < Rcur) ? s0 : -3e38f;
    float sv1 = (rb0+1 < Rcur) ? s1 : -3e38f;
    float sv2 = (rb0+2 < Rcur) ? s2 : -3e38f;
    float sv3 = (rb0+3 < Rcur) ? s3 : -3e38f;
    float m_tile = fmaxf(fmaxf(sv0, sv1), fmaxf(sv2, sv3));
    float m_new  = fmaxf(m_run, m_tile);
    float esc    = __expf(m_run - m_new);
    float w0 = (rb0+0 < Rcur) ? __expf(s0 - m_new) : 0.f;
    float w1 = (rb0+1 < Rcur) ? __expf(s1 - m_new) : 0.f;
    float w2 = (rb0+2 < Rcur) ? __expf(s2 - m_new) : 0.f;
    float w3 = (rb0+3 < Rcur) ? __expf(s3 - m_new) : 0.f;
    l_run = l_run*esc + (w0 + w1) + (w2 + w3);
    m_run = m_new;
    if (MB16) {
      const ushortT* bu = (const ushortT*)((const char*)SM + buf*32768);
      #pragma unroll
      for (int j = 0; j < 8; ++j) {
        const int kk = j*64 + lane;
        float a = cacc[j]*esc;
        a += w0 * bf2f(bu[(rb0+0)*512 + kk]);
        a += w1 * bf2f(bu[(rb0+1)*512 + kk]);
        a += w2 * bf2f(bu[(rb0+2)*512 + kk]);
        a += w3 * bf2f(bu[(rb0+3)*512 + kk]);
        cacc[j] = a;
      }
    } else {
      const float* bbuf = SM + buf*16384;
      #pragma unroll
      for (int j = 0; j < 8; ++j) {
        const int kk = j*64 + lane;
        float a = cacc[j]*esc;
        a += w0*bbuf[(rb0+0)*DD + kk];
        a += w1*bbuf[(rb0+1)*DD + kk];
        a += w2*bbuf[(rb0+2)*DD + kk];
        a += w3*bbuf[(rb0+3)*DD + kk];
        cacc[j] = a;
      }
    }
    __syncthreads();
    buf ^= 1;
  }

  // merge 8 per-wave partials
  #pragma unroll
  for (int j = 0; j < 8; ++j) CP[wv*DD + j*64 + lane] = cacc[j];
  if (lane == 0) { ML2[wv*2] = m_run; ML2[wv*2+1] = l_run; }
  __syncthreads();
  float M = -3e38f;
  #pragma unroll
  for (int w = 0; w < 8; ++w) M = fmaxf(M, ML2[w*2]);
  float lsum = 0.f, ck = 0.f;
  #pragma unroll
  for (int w = 0; w < 8; ++w) {
    float ew = __expf(ML2[w*2] - M);
    lsum += ew*ML2[w*2+1];
    ck   += ew*CP[w*DD + tid];
  }
  cpart[((size_t)(b*3+ch))*DD + tid] = ck;
  if (tid == 0) {
    ml[(b*3+ch)*2]     = M;
    ml[(b*3+ch)*2 + 1] = lsum;
  }
}

// ================= combine + W_out + logits (64 blocks x 512) =================
__launch_bounds__(512, 1)
__global__ void k_out(const float* __restrict__ h1cur, const float* __restrict__ cpart,
                      const float* __restrict__ ml, const float* __restrict__ W_out,
                      const float* __restrict__ W_tok, float* __restrict__ out, int t) {
  __shared__ float SM[33024 + 512 + 256];
  float* const TILE = SM;
  float* const AH   = SM + 33024;   // [8][64]
  float* const EW   = SM + 33536;   // [64][4]
  const int tid = threadIdx.x, bid = blockIdx.x;
  const int lane = tid & 63, wv = tid >> 6;

  // per-batch combine weights
  if (tid < 64) {
    float m0 = ml[(tid*3+0)*2], l0 = ml[(tid*3+0)*2+1];
    float m1 = ml[(tid*3+1)*2], l1 = ml[(tid*3+1)*2+1];
    float m2 = ml[(tid*3+2)*2], l2 = ml[(tid*3+2)*2+1];
    float M = fmaxf(fmaxf(m0, m1), m2);
    float e0 = __expf(m0 - M), e1 = __expf(m1 - M), e2 = __expf(m2 - M);
    float invL = 1.f / (e0*l0 + e1*l1 + e2*l2);
    EW[tid*4+0] = e0; EW[tid*4+1] = e1; EW[tid*4+2] = e2; EW[tid*4+3] = invL;
  }
  __syncthreads();

  // stage combined context into TILE [64][516]
  for (int it = tid; it < 64*128; it += 512) {
    const int row = it >> 7, c4 = (it & 127) * 4;
    const float* cp = cpart + (size_t)row*3*DD + c4;
    f4 p0 = *(const f4*)cp;
    f4 p1 = *(const f4*)(cp + DD);
    f4 p2 = *(const f4*)(cp + 2*DD);
    float e0 = EW[row*4+0], e1 = EW[row*4+1], e2 = EW[row*4+2], invL = EW[row*4+3];
    f4 c;
    c.x = (e0*p0.x + e1*p1.x + e2*p2.x)*invL;
    c.y = (e0*p0.y + e1*p1.y + e2*p2.y)*invL;
    c.z = (e0*p0.z + e1*p1.z + e2*p2.z)*invL;
    c.w = (e0*p0.w + e1*p1.w + e2*p2.w)*invL;
    *(f4*)&TILE[row*516 + c4] = c;
  }
  __syncthreads();

  // attn_h rows bid*8 + wv : first half over c, second half over q=h1
  float acc = 0.f;
  const f4* hv4 = (const f4*)TILE + (size_t)lane*129;
  const int orow = __builtin_amdgcn_readfirstlane(bid*8 + wv);
  const f4* wo = (const f4*)(W_out + (size_t)orow*(2*DD));
  #pragma unroll 4
  for (int kq = 0; kq < 128; ++kq) acc += dot4(hv4[kq], wo[kq]);
  __syncthreads();
  stage64(h1cur, TILE, wv, lane);
  __syncthreads();
  #pragma unroll 4
  for (int kq = 0; kq < 128; ++kq) acc += dot4(hv4[kq], wo[128 + kq]);
  AH[wv*64 + lane] = tanhf(acc);
  __syncthreads();

  // logits partial contributions (out pre-initialized with b_tok in k_prep)
  for (int v = wv; v < VV; v += 8) {
    const int vv = __builtin_amdgcn_readfirstlane(v);
    const float* wt = W_tok + (size_t)vv*DD + bid*8;
    float s8 = 0.f;
    #pragma unroll
    for (int q8 = 0; q8 < 8; ++q8) s8 += AH[q8*64 + lane] * wt[q8];
    atomicAdd(&out[((size_t)lane*TT + t)*VV + vv], s8);
  }
}

extern "C" void kernel_launch(void* const* d_in, const int* in_sizes, int n_in,
                              void* d_out, int out_size, void* d_ws, size_t ws_size,
                              hipStream_t stream) {
  const float* h_init = (const float*)d_in[0];
  const int*   targets= (const int*)d_in[1];
  const float* mem    = (const float*)d_in[2];
  const float* W_ih0  = (const float*)d_in[3];
  const float* W_hh0  = (const float*)d_in[4];
  const float* b_ih0  = (const float*)d_in[5];
  const float* b_hh0  = (const float*)d_in[6];
  const float* W_ih1  = (const float*)d_in[7];
  const float* W_hh1  = (const float*)d_in[8];
  const float* b_ih1  = (const float*)d_in[9];
  const float* b_hh1  = (const float*)d_in[10];
  const float* W_out  = (const float*)d_in[11];
  const float* W_tok  = (const float*)d_in[12];
  const float* b_tok  = (const float*)d_in[13];
  float* out = (float*)d_out;
  float* ws  = (float*)d_ws;

  float* h0b = ws + WS_H0;
  float* h1b = ws + WS_H1;
  float* cpart = ws + WS_CP;
  float* ml  = ws + WS_ML;
  ushortT* mb16 = (ushortT*)(ws + WS_MB16);
  const bool useBf = (ws_size >= WS_NEED_BYTES);

  if (useBf)
    hipLaunchKernelGGL(k_prep<1>, dim3(1024), dim3(512), 0, stream, mem, mb16, b_tok, out);
  else
    hipLaunchKernelGGL(k_prep<0>, dim3(1024), dim3(512), 0, stream, mem, mb16, b_tok, out);

  // step 0 hidden states
  hipLaunchKernelGGL(k_gru0, dim3(64), dim3(512), 0, stream,
                     h_init, targets, W_ih0, W_hh0, b_ih0, b_hh0, h0b, 0);
  hipLaunchKernelGGL(k_gru1, dim3(64), dim3(512), 0, stream,
                     h_init + BBDD, h0b, W_hh1, W_ih1, b_hh1, b_ih1, h1b);

  for (int t = 0; t < TT; ++t) {
    const float* h1cur = h1b + (size_t)(t & 1)*BBDD;
    const float* h0cur = h0b + (size_t)(t & 1)*BBDD;
    float* h0nxt = h0b + (size_t)((t+1) & 1)*BBDD;
    float* h1nxt = h1b + (size_t)((t+1) & 1)*BBDD;

    if (useBf)
      hipLaunchKernelGGL(k_attn<1>, dim3(192), dim3(512), 0, stream,
                         h1cur, mem, mb16, cpart, ml);
    else
      hipLaunchKernelGGL(k_attn<0>, dim3(192), dim3(512), 0, stream,
                         h1cur, mem, mb16, cpart, ml);

    if (t < TT-1)
      hipLaunchKernelGGL(k_gru0, dim3(64), dim3(512), 0, stream,
                         h0cur, targets, W_ih0, W_hh0, b_ih0, b_hh0, h0nxt, t);

    hipLaunchKernelGGL(k_out, dim3(64), dim3(512), 0, stream,
                       h1cur, cpart, ml, W_out, W_tok, out, t);

    if (t < TT-1)
      hipLaunchKernelGGL(k_gru1, dim3(64), dim3(512), 0, stream,
                         h1cur, h0nxt, W_hh1, W_ih1, b_hh1, b_ih1, h1nxt);
  }
}

// Round 7
// 16924.347 us; speedup vs baseline: 1.8591x; 1.6101x over previous
//
#include <hip/hip_runtime.h>

#define TT 200
#define SS 1024
#define DD 512
#define VV 30
#define BB 64
#define BBDD (BB*DD)              // 32768

// ---- ws float offsets ----
#define WS_H0 0                   // [2][64][512]
#define WS_H1 (2*BBDD)            // [2][64][512]
#define WS_CP (4*BBDD)            // [64*3][512]
#define WS_ML (WS_CP + 3*BB*DD)   // [64*3][2]
#define WS_MB16 230400            // ushort bf16 mirror of mem
#define WS_NEED_BYTES ((size_t)WS_MB16*4 + (size_t)BB*SS*DD*2)

typedef __attribute__((ext_vector_type(4))) float f4;
typedef __attribute__((ext_vector_type(4))) unsigned int u4v;
typedef unsigned short ushortT;

__device__ __forceinline__ float dot4(f4 a, f4 b) {
  return a.x*b.x + a.y*b.y + a.z*b.z + a.w*b.w;
}
__device__ __forceinline__ float sigmoidf_(float x) { return 1.f/(1.f + __expf(-x)); }
__device__ __forceinline__ int minI(int a, int b) { return a < b ? a : b; }
__device__ __forceinline__ float bf2f(unsigned int u) { return __uint_as_float(u << 16); }
__device__ __forceinline__ unsigned bfr_(float x) {
  unsigned u = __float_as_uint(x);
  return (u + 0x7fffu + ((u >> 16) & 1u)) >> 16;   // RNE f32->bf16
}

__device__ __forceinline__ void gl_lds16(const void* g, void* l) {
  __builtin_amdgcn_global_load_lds(
      (const __attribute__((address_space(1))) unsigned int*)g,
      (__attribute__((address_space(3))) unsigned int*)l,
      16, 0, 0);
}

// async global [64][512] -> LDS [64][516] ; follow with __syncthreads()
__device__ __forceinline__ void stage64(const float* src, float* TILE, int wv, int lane) {
  #pragma unroll
  for (int rr = 0; rr < 8; ++rr) {
    const int row = wv*8 + rr;
    const float* g = src + (size_t)row*DD + lane*4;
    gl_lds16(g,       TILE + row*516);
    gl_lds16(g + 256, TILE + row*516 + 256);
  }
}

// wave-column GRU dots: wave wv computes 3 gate-columns for dims w_id*8..+7
__device__ __forceinline__ void wave_dots(const float* TILE, const float* W, const float* bias,
                                          float* GH, int w_id, int wv, int lane) {
  const int c0 = wv*3, c1 = c0+1, c2 = c0+2;
  const int R0 = __builtin_amdgcn_readfirstlane(((c0>>3)<<9) + w_id*8 + (c0&7));
  const int R1 = __builtin_amdgcn_readfirstlane(((c1>>3)<<9) + w_id*8 + (c1&7));
  const int R2 = __builtin_amdgcn_readfirstlane(((c2>>3)<<9) + w_id*8 + (c2&7));
  const f4* w0 = (const f4*)(W + (size_t)R0*DD);
  const f4* w1 = (const f4*)(W + (size_t)R1*DD);
  const f4* w2 = (const f4*)(W + (size_t)R2*DD);
  const f4* hv4 = (const f4*)TILE + (size_t)lane*129;
  float a0=0.f, a1=0.f, a2=0.f;
  #pragma unroll 4
  for (int kq = 0; kq < 128; ++kq) {
    f4 h = hv4[kq];
    a0 += dot4(h, w0[kq]); a1 += dot4(h, w1[kq]); a2 += dot4(h, w2[kq]);
  }
  GH[c0*64 + lane] = a0 + bias[R0];
  GH[c1*64 + lane] = a1 + bias[R1];
  GH[c2*64 + lane] = a2 + bias[R2];
}

// ================= prologue: bf16 mirror + out bias init =================
template<int MB16>
__launch_bounds__(512, 1)
__global__ void k_prep(const float* __restrict__ mem, ushortT* __restrict__ mb16,
                       const float* __restrict__ b_tok, float* __restrict__ out) {
  const int gid = blockIdx.x*512 + threadIdx.x;
  if (MB16) {
    const size_t total = (size_t)BB*SS*DD;
    for (size_t i = (size_t)gid*8; i < total; i += (size_t)gridDim.x*512*8) {
      f4 a = *(const f4*)(mem + i);
      f4 b = *(const f4*)(mem + i + 4);
      u4v d;
      d.x = bfr_(a.x) | (bfr_(a.y) << 16);
      d.y = bfr_(a.z) | (bfr_(a.w) << 16);
      d.z = bfr_(b.x) | (bfr_(b.y) << 16);
      d.w = bfr_(b.z) | (bfr_(b.w) << 16);
      *(u4v*)(mb16 + i) = d;
    }
  }
  for (int i = gid; i < BB*TT*VV; i += gridDim.x*512)
    out[i] = b_tok[i % VV];
}

// ================= GRU layer 0 standalone (prologue only) =================
__launch_bounds__(512, 1)
__global__ void k_gru0(const float* __restrict__ h0prev, const int* __restrict__ targets,
                       const float* __restrict__ W_ih0, const float* __restrict__ W_hh0,
                       const float* __restrict__ b_ih0, const float* __restrict__ b_hh0,
                       float* __restrict__ h0out, int tokcol) {
  __shared__ float SM[34560];
  float* const TILE = SM;
  float* const GHX  = SM + 33024;
  const int tid = threadIdx.x, bid = blockIdx.x;
  const int lane = tid & 63, wv = tid >> 6;
  stage64(h0prev, TILE, wv, lane);
  __syncthreads();
  wave_dots(TILE, W_hh0, b_hh0, GHX, bid, wv, lane);
  __syncthreads();
  const int dl = tid >> 6, bb = tid & 63, d = bid*8 + dl;
  const int tok = targets[bb*TT + tokcol];
  float gir = W_ih0[(size_t)d*VV + tok]          + b_ih0[d];
  float giz = W_ih0[(size_t)(DD + d)*VV + tok]   + b_ih0[DD + d];
  float gin = W_ih0[(size_t)(2*DD + d)*VV + tok] + b_ih0[2*DD + d];
  float ghr = GHX[(0*8 + dl)*64 + bb];
  float ghz = GHX[(1*8 + dl)*64 + bb];
  float ghn = GHX[(2*8 + dl)*64 + bb];
  float r_ = sigmoidf_(gir + ghr), z_ = sigmoidf_(giz + ghz);
  float n_ = tanhf(gin + r_*ghn);
  float h0old = TILE[bb*516 + d];
  h0out[(size_t)bb*DD + d] = (1.f - z_)*n_ + z_*h0old;
}

// ================= GRU layer 1 standalone (prologue only) =================
__launch_bounds__(512, 1)
__global__ void k_gru1(const float* __restrict__ h1prev, const float* __restrict__ h0cur,
                       const float* __restrict__ W_hh1, const float* __restrict__ W_ih1,
                       const float* __restrict__ b_hh1, const float* __restrict__ b_ih1,
                       float* __restrict__ h1out) {
  __shared__ float SM[36096];
  float* const TILE = SM;
  float* const GH1  = SM + 33024;
  float* const GHX  = SM + 34560;
  const int tid = threadIdx.x, bid = blockIdx.x;
  const int lane = tid & 63, wv = tid >> 6;
  const int dl = tid >> 6, bb = tid & 63, d = bid*8 + dl;

  stage64(h1prev, TILE, wv, lane);
  __syncthreads();
  wave_dots(TILE, W_hh1, b_hh1, GH1, bid, wv, lane);
  float h1old = TILE[bb*516 + d];
  __syncthreads();
  stage64(h0cur, TILE, wv, lane);
  __syncthreads();
  wave_dots(TILE, W_ih1, b_ih1, GHX, bid, wv, lane);
  __syncthreads();
  float gir = GHX[(0*8 + dl)*64 + bb], ghr = GH1[(0*8 + dl)*64 + bb];
  float giz = GHX[(1*8 + dl)*64 + bb], ghz = GH1[(1*8 + dl)*64 + bb];
  float gin = GHX[(2*8 + dl)*64 + bb], ghn = GH1[(2*8 + dl)*64 + bb];
  float r_ = sigmoidf_(gir + ghr), z_ = sigmoidf_(giz + ghz);
  float n_ = tanhf(gin + r_*ghn);
  h1out[(size_t)bb*DD + d] = (1.f - z_)*n_ + z_*h1old;
}

// ================= KA: attn(t) [blocks 0..191] + gru0(t+1) [192..255] =================
template<int MB16>
__launch_bounds__(512, 1)
__global__ void k_attn_gru0(const float* __restrict__ h1cur, const float* __restrict__ h0cur,
                            const float* __restrict__ mem, const ushortT* __restrict__ mb16,
                            const int* __restrict__ targets,
                            const float* __restrict__ W_ih0, const float* __restrict__ W_hh0,
                            const float* __restrict__ b_ih0, const float* __restrict__ b_hh0,
                            float* __restrict__ cpart, float* __restrict__ ml,
                            float* __restrict__ h0nxt, int t) {
  __shared__ float SM[36896];
  const int tid = threadIdx.x, bid = blockIdx.x;
  const int lane = tid & 63, wv = tid >> 6;

  if (bid < 192) {
    // ---------------- attention ----------------
    float* const CP  = SM + 32768;   // [8][512]
    float* const ML2 = SM + 36864;
    const int b  = bid / 3;
    const int ch = bid - 3*b;
    const int r0 = (ch == 0) ? 0 : 342 + (ch-1)*341;
    const int CNT = (ch == 0) ? 342 : 341;
    const int seg = lane & 15;
    const int rr4 = lane >> 4;
    const float* qsrc = h1cur + (size_t)b*DD;
    f4 q4[8];
    if (MB16) {
      #pragma unroll
      for (int j = 0; j < 8; ++j) q4[j] = *(const f4*)(qsrc + seg*32 + j*4);
    } else {
      #pragma unroll
      for (int j = 0; j < 8; ++j) q4[j] = *(const f4*)(qsrc + seg*4 + j*64);
    }

    float m_run = -3e38f, l_run = 0.f;
    float cacc[8];
    #pragma unroll
    for (int j = 0; j < 8; ++j) cacc[j] = 0.f;

    if (MB16) {
      // ======== bf16 path: 64-row tiles, 2x64KB double buffer ========
      const int NTL = (CNT + 63) >> 6;
      const ushortT* msrcB = mb16 + ((size_t)b*SS + r0)*DD;
      char* const B0 = (char*)SM;
      char* const B1 = (char*)SM + 65536;
      int buf = 0;
      {
        const int R = minI(64, CNT);
        #pragma unroll
        for (int rr = 0; rr < 8; ++rr) {
          const int row = wv*8 + rr;
          if (row < R) gl_lds16(msrcB + (size_t)row*DD + lane*8, B0 + row*1024);
        }
      }
      __syncthreads();
      for (int tl = 0; tl < NTL; ++tl) {
        const int Rcur = minI(64, CNT - tl*64);
        if (tl + 1 < NTL) {
          const int Rn = minI(64, CNT - (tl+1)*64);
          char* nb = buf ? B0 : B1;
          #pragma unroll
          for (int rr = 0; rr < 8; ++rr) {
            const int row = wv*8 + rr;
            if (row < Rn)
              gl_lds16(msrcB + (size_t)(tl+1)*64*DD + (size_t)row*DD + lane*8, nb + row*1024);
          }
        }
        const char* bb = buf ? B1 : B0;
        float sc[2];
        #pragma unroll
        for (int p = 0; p < 2; ++p) {
          const int r = wv*8 + rr4 + p*4;
          const u4v* rp = (const u4v*)(bb + r*1024 + seg*64);
          const float* qq = (const float*)q4;
          float s = 0.f;
          #pragma unroll
          for (int jj = 0; jj < 4; ++jj) {
            u4v u = rp[jj];
            s += __uint_as_float(u.x << 16)         * qq[jj*8+0]
               + __uint_as_float(u.x & 0xffff0000u) * qq[jj*8+1]
               + __uint_as_float(u.y << 16)         * qq[jj*8+2]
               + __uint_as_float(u.y & 0xffff0000u) * qq[jj*8+3]
               + __uint_as_float(u.z << 16)         * qq[jj*8+4]
               + __uint_as_float(u.z & 0xffff0000u) * qq[jj*8+5]
               + __uint_as_float(u.w << 16)         * qq[jj*8+6]
               + __uint_as_float(u.w & 0xffff0000u) * qq[jj*8+7];
          }
          sc[p] = s;
        }
        #pragma unroll
        for (int p = 0; p < 2; ++p) {
          sc[p] += __shfl_xor(sc[p], 1);
          sc[p] += __shfl_xor(sc[p], 2);
          sc[p] += __shfl_xor(sc[p], 4);
          sc[p] += __shfl_xor(sc[p], 8);
        }
        float s_[8];
        s_[0] = __shfl(sc[0], 0);  s_[1] = __shfl(sc[0], 16);
        s_[2] = __shfl(sc[0], 32); s_[3] = __shfl(sc[0], 48);
        s_[4] = __shfl(sc[1], 0);  s_[5] = __shfl(sc[1], 16);
        s_[6] = __shfl(sc[1], 32); s_[7] = __shfl(sc[1], 48);
        float m_tile = -3e38f;
        #pragma unroll
        for (int i = 0; i < 8; ++i) {
          float v = (wv*8 + i < Rcur) ? s_[i] : -3e38f;
          m_tile = fmaxf(m_tile, v);
        }
        float m_new = fmaxf(m_run, m_tile);
        float esc   = __expf(m_run - m_new);
        float w[8]; float ls = 0.f;
        #pragma unroll
        for (int i = 0; i < 8; ++i) {
          w[i] = (wv*8 + i < Rcur) ? __expf(s_[i] - m_new) : 0.f;
          ls += w[i];
        }
        l_run = l_run*esc + ls;
        m_run = m_new;
        const ushortT* bu = (const ushortT*)bb;
        #pragma unroll
        for (int j = 0; j < 8; ++j) {
          const int kk = j*64 + lane;
          float a = cacc[j]*esc;
          #pragma unroll
          for (int i = 0; i < 8; ++i) a += w[i] * bf2f(bu[(wv*8 + i)*512 + kk]);
          cacc[j] = a;
        }
        __syncthreads();
        buf ^= 1;
      }
    } else {
      // ======== f32 fallback: 32-row tiles (r6 logic) ========
      const int NTL = (CNT + 31) >> 5;
      const float* msrcF = mem + ((size_t)b*SS + r0)*DD;
      int buf = 0;
      {
        const int R = minI(32, CNT);
        #pragma unroll
        for (int rr = 0; rr < 4; ++rr) {
          const int row = wv*4 + rr;
          if (row < R) {
            const float* g = msrcF + (size_t)row*DD + lane*4;
            gl_lds16(g, SM + row*DD); gl_lds16(g + 256, SM + row*DD + 256);
          }
        }
      }
      __syncthreads();
      for (int tl = 0; tl < NTL; ++tl) {
        const int Rcur = minI(32, CNT - tl*32);
        if (tl + 1 < NTL) {
          const int Rn = minI(32, CNT - (tl+1)*32);
          #pragma unroll
          for (int rr = 0; rr < 4; ++rr) {
            const int row = wv*4 + rr;
            if (row < Rn) {
              const float* g = msrcF + (size_t)(tl+1)*32*DD + (size_t)row*DD + lane*4;
              gl_lds16(g, SM + (buf^1)*16384 + row*DD);
              gl_lds16(g + 256, SM + (buf^1)*16384 + row*DD + 256);
            }
          }
        }
        const float* bbuf = SM + buf*16384;
        const int r = wv*4 + rr4;
        float sc = 0.f;
        if (r < Rcur) {
          const f4* rb = (const f4*)(bbuf + (size_t)r*DD);
          #pragma unroll
          for (int jj = 0; jj < 8; ++jj) sc += dot4(rb[seg + 16*jj], q4[jj]);
        }
        sc += __shfl_xor(sc, 1);
        sc += __shfl_xor(sc, 2);
        sc += __shfl_xor(sc, 4);
        sc += __shfl_xor(sc, 8);
        const int rb0 = wv*4;
        float s0 = __shfl(sc, 0), s1 = __shfl(sc, 16), s2 = __shfl(sc, 32), s3 = __shfl(sc, 48);
        float sv0 = (rb0+0 < Rcur) ? s0 : -3e38f;
        float sv1 = (rb0+1 < Rcur) ? s1 : -3e38f;
        float sv2 = (rb0+2 < Rcur) ? s2 : -3e38f;
        float sv3 = (rb0+3 < Rcur) ? s3 : -3e38f;
        float m_tile = fmaxf(fmaxf(sv0, sv1), fmaxf(sv2, sv3));
        float m_new  = fmaxf(m_run, m_tile);
        float esc    = __expf(m_run - m_new);
        float w0 = (rb0+0 < Rcur) ? __expf(s0 - m_new) : 0.f;
        float w1 = (rb0+1 < Rcur) ? __expf(s1 - m_new) : 0.f;
        float w2 = (rb0+2 < Rcur) ? __expf(s2 - m_new) : 0.f;
        float w3 = (rb0+3 < Rcur) ? __expf(s3 - m_new) : 0.f;
        l_run = l_run*esc + (w0 + w1) + (w2 + w3);
        m_run = m_new;
        #pragma unroll
        for (int j = 0; j < 8; ++j) {
          const int kk = j*64 + lane;
          float a = cacc[j]*esc;
          a += w0*bbuf[(rb0+0)*DD + kk];
          a += w1*bbuf[(rb0+1)*DD + kk];
          a += w2*bbuf[(rb0+2)*DD + kk];
          a += w3*bbuf[(rb0+3)*DD + kk];
          cacc[j] = a;
        }
        __syncthreads();
        buf ^= 1;
      }
    }

    // merge 8 per-wave partials
    #pragma unroll
    for (int j = 0; j < 8; ++j) CP[wv*DD + j*64 + lane] = cacc[j];
    if (lane == 0) { ML2[wv*2] = m_run; ML2[wv*2+1] = l_run; }
    __syncthreads();
    float M = -3e38f;
    #pragma unroll
    for (int w = 0; w < 8; ++w) M = fmaxf(M, ML2[w*2]);
    float lsum = 0.f, ck = 0.f;
    #pragma unroll
    for (int w = 0; w < 8; ++w) {
      float ew = __expf(ML2[w*2] - M);
      lsum += ew*ML2[w*2+1];
      ck   += ew*CP[w*DD + tid];
    }
    cpart[((size_t)(b*3+ch))*DD + tid] = ck;
    if (tid == 0) {
      ml[(b*3+ch)*2]     = M;
      ml[(b*3+ch)*2 + 1] = lsum;
    }
  } else if (t + 1 < TT) {
    // ---------------- gru0 for step t+1 ----------------
    float* const TILE = SM;
    float* const GHX  = SM + 33024;
    const int w_id = bid - 192;
    stage64(h0cur, TILE, wv, lane);
    __syncthreads();
    wave_dots(TILE, W_hh0, b_hh0, GHX, w_id, wv, lane);
    __syncthreads();
    const int dl = tid >> 6, bb = tid & 63, d = w_id*8 + dl;
    const int tok = targets[bb*TT + t];
    float gir = W_ih0[(size_t)d*VV + tok]          + b_ih0[d];
    float giz = W_ih0[(size_t)(DD + d)*VV + tok]   + b_ih0[DD + d];
    float gin = W_ih0[(size_t)(2*DD + d)*VV + tok] + b_ih0[2*DD + d];
    float ghr = GHX[(0*8 + dl)*64 + bb];
    float ghz = GHX[(1*8 + dl)*64 + bb];
    float ghn = GHX[(2*8 + dl)*64 + bb];
    float r_ = sigmoidf_(gir + ghr), z_ = sigmoidf_(giz + ghz);
    float n_ = tanhf(gin + r_*ghn);
    float h0old = TILE[bb*516 + d];
    h0nxt[(size_t)bb*DD + d] = (1.f - z_)*n_ + z_*h0old;
  }
}

// ================= KB: out(t) [blocks 0..63] + gru1(t+1) [64..127] =================
__launch_bounds__(512, 1)
__global__ void k_out_gru1(const float* __restrict__ h1cur, const float* __restrict__ cpart,
                           const float* __restrict__ ml, const float* __restrict__ W_out,
                           const float* __restrict__ W_tok, const float* __restrict__ h0nxt,
                           const float* __restrict__ W_hh1, const float* __restrict__ W_ih1,
                           const float* __restrict__ b_hh1, const float* __restrict__ b_ih1,
                           float* __restrict__ h1nxt, float* __restrict__ out, int t) {
  __shared__ float SM[36096];
  const int tid = threadIdx.x, bid = blockIdx.x;
  const int lane = tid & 63, wv = tid >> 6;

  if (bid < 64) {
    // ---------------- out(t) ----------------
    float* const TILE = SM;
    float* const AH   = SM + 33024;   // [8][64]
    float* const EW   = SM + 33536;   // [64][4]
    if (tid < 64) {
      float m0 = ml[(tid*3+0)*2], l0 = ml[(tid*3+0)*2+1];
      float m1 = ml[(tid*3+1)*2], l1 = ml[(tid*3+1)*2+1];
      float m2 = ml[(tid*3+2)*2], l2 = ml[(tid*3+2)*2+1];
      float M = fmaxf(fmaxf(m0, m1), m2);
      float e0 = __expf(m0 - M), e1 = __expf(m1 - M), e2 = __expf(m2 - M);
      float invL = 1.f / (e0*l0 + e1*l1 + e2*l2);
      EW[tid*4+0] = e0; EW[tid*4+1] = e1; EW[tid*4+2] = e2; EW[tid*4+3] = invL;
    }
    __syncthreads();
    for (int it = tid; it < 64*128; it += 512) {
      const int row = it >> 7, c4 = (it & 127) * 4;
      const float* cp = cpart + (size_t)row*3*DD + c4;
      f4 p0 = *(const f4*)cp;
      f4 p1 = *(const f4*)(cp + DD);
      f4 p2 = *(const f4*)(cp + 2*DD);
      float e0 = EW[row*4+0], e1 = EW[row*4+1], e2 = EW[row*4+2], invL = EW[row*4+3];
      f4 c;
      c.x = (e0*p0.x + e1*p1.x + e2*p2.x)*invL;
      c.y = (e0*p0.y + e1*p1.y + e2*p2.y)*invL;
      c.z = (e0*p0.z + e1*p1.z + e2*p2.z)*invL;
      c.w = (e0*p0.w + e1*p1.w + e2*p2.w)*invL;
      *(f4*)&TILE[row*516 + c4] = c;
    }
    __syncthreads();
    float acc = 0.f;
    const f4* hv4 = (const f4*)TILE + (size_t)lane*129;
    const int orow = __builtin_amdgcn_readfirstlane(bid*8 + wv);
    const f4* wo = (const f4*)(W_out + (size_t)orow*(2*DD));
    #pragma unroll 4
    for (int kq = 0; kq < 128; ++kq) acc += dot4(hv4[kq], wo[kq]);
    __syncthreads();
    stage64(h1cur, TILE, wv, lane);
    __syncthreads();
    #pragma unroll 4
    for (int kq = 0; kq < 128; ++kq) acc += dot4(hv4[kq], wo[128 + kq]);
    AH[wv*64 + lane] = tanhf(acc);
    __syncthreads();
    for (int v = wv; v < VV; v += 8) {
      const int vv = __builtin_amdgcn_readfirstlane(v);
      const float* wt = W_tok + (size_t)vv*DD + bid*8;
      float s8 = 0.f;
      #pragma unroll
      for (int q8 = 0; q8 < 8; ++q8) s8 += AH[q8*64 + lane] * wt[q8];
      atomicAdd(&out[((size_t)lane*TT + t)*VV + vv], s8);
    }
  } else if (t + 1 < TT) {
    // ---------------- gru1 for step t+1 ----------------
    float* const TILE = SM;
    float* const GH1  = SM + 33024;
    float* const GHX  = SM + 34560;
    const int w_id = bid - 64;
    const int dl = tid >> 6, bb = tid & 63, d = w_id*8 + dl;
    stage64(h1cur, TILE, wv, lane);
    __syncthreads();
    wave_dots(TILE, W_hh1, b_hh1, GH1, w_id, wv, lane);
    float h1old = TILE[bb*516 + d];
    __syncthreads();
    stage64(h0nxt, TILE, wv, lane);
    __syncthreads();
    wave_dots(TILE, W_ih1, b_ih1, GHX, w_id, wv, lane);
    __syncthreads();
    float gir = GHX[(0*8 + dl)*64 + bb], ghr = GH1[(0*8 + dl)*64 + bb];
    float giz = GHX[(1*8 + dl)*64 + bb], ghz = GH1[(1*8 + dl)*64 + bb];
    float gin = GHX[(2*8 + dl)*64 + bb], ghn = GH1[(2*8 + dl)*64 + bb];
    float r_ = sigmoidf_(gir + ghr), z_ = sigmoidf_(giz + ghz);
    float n_ = tanhf(gin + r_*ghn);
    h1nxt[(size_t)bb*DD + d] = (1.f - z_)*n_ + z_*h1old;
  }
}

extern "C" void kernel_launch(void* const* d_in, const int* in_sizes, int n_in,
                              void* d_out, int out_size, void* d_ws, size_t ws_size,
                              hipStream_t stream) {
  const float* h_init = (const float*)d_in[0];
  const int*   targets= (const int*)d_in[1];
  const float* mem    = (const float*)d_in[2];
  const float* W_ih0  = (const float*)d_in[3];
  const float* W_hh0  = (const float*)d_in[4];
  const float* b_ih0  = (const float*)d_in[5];
  const float* b_hh0  = (const float*)d_in[6];
  const float* W_ih1  = (const float*)d_in[7];
  const float* W_hh1  = (const float*)d_in[8];
  const float* b_ih1  = (const float*)d_in[9];
  const float* b_hh1  = (const float*)d_in[10];
  const float* W_out  = (const float*)d_in[11];
  const float* W_tok  = (const float*)d_in[12];
  const float* b_tok  = (const float*)d_in[13];
  float* out = (float*)d_out;
  float* ws  = (float*)d_ws;

  float* h0b = ws + WS_H0;
  float* h1b = ws + WS_H1;
  float* cpart = ws + WS_CP;
  float* ml  = ws + WS_ML;
  ushortT* mb16 = (ushortT*)(ws + WS_MB16);
  const bool useBf = (ws_size >= WS_NEED_BYTES);

  if (useBf)
    hipLaunchKernelGGL(k_prep<1>, dim3(1024), dim3(512), 0, stream, mem, mb16, b_tok, out);
  else
    hipLaunchKernelGGL(k_prep<0>, dim3(1024), dim3(512), 0, stream, mem, mb16, b_tok, out);

  // step-0 hidden states
  hipLaunchKernelGGL(k_gru0, dim3(64), dim3(512), 0, stream,
                     h_init, targets, W_ih0, W_hh0, b_ih0, b_hh0, h0b, 0);
  hipLaunchKernelGGL(k_gru1, dim3(64), dim3(512), 0, stream,
                     h_init + BBDD, h0b, W_hh1, W_ih1, b_hh1, b_ih1, h1b);

  for (int t = 0; t < TT; ++t) {
    const float* h1cur = h1b + (size_t)(t & 1)*BBDD;
    const float* h0cur = h0b + (size_t)(t & 1)*BBDD;
    float* h0nxt = h0b + (size_t)((t+1) & 1)*BBDD;
    float* h1nxt = h1b + (size_t)((t+1) & 1)*BBDD;

    if (useBf)
      hipLaunchKernelGGL(k_attn_gru0<1>, dim3(256), dim3(512), 0, stream,
                         h1cur, h0cur, mem, mb16, targets,
                         W_ih0, W_hh0, b_ih0, b_hh0, cpart, ml, h0nxt, t);
    else
      hipLaunchKernelGGL(k_attn_gru0<0>, dim3(256), dim3(512), 0, stream,
                         h1cur, h0cur, mem, mb16, targets,
                         W_ih0, W_hh0, b_ih0, b_hh0, cpart, ml, h0nxt, t);

    hipLaunchKernelGGL(k_out_gru1, dim3(128), dim3(512), 0, stream,
                       h1cur, cpart, ml, W_out, W_tok, h0nxt,
                       W_hh1, W_ih1, b_hh1, b_ih1, h1nxt, out, t);
  }
}

// Round 8
// 15175.790 us; speedup vs baseline: 2.0733x; 1.1152x over previous
//
#include <hip/hip_runtime.h>

#define TT 200
#define SS 1024
#define DD 512
#define VV 30
#define BB 64
#define BBDD (BB*DD)              // 32768

// ---- ws float offsets ----
#define WS_H0 0                   // [2][64][512]
#define WS_H1 (2*BBDD)            // [3][64][512]
#define WS_CP (5*BBDD)            // [2][64*2][512]
#define WS_ML (WS_CP + 4*BBDD)    // [2][256]
#define WS_MB16 300000            // ushort bf16 mirror of mem
#define WS_NEED_BYTES ((size_t)WS_MB16*4 + (size_t)BB*SS*DD*2)

typedef __attribute__((ext_vector_type(4))) float f4;
typedef __attribute__((ext_vector_type(4))) unsigned int u4v;
typedef unsigned short ushortT;

__device__ __forceinline__ float dot4(f4 a, f4 b) {
  return a.x*b.x + a.y*b.y + a.z*b.z + a.w*b.w;
}
__device__ __forceinline__ float sigmoidf_(float x) { return 1.f/(1.f + __expf(-x)); }
__device__ __forceinline__ int minI(int a, int b) { return a < b ? a : b; }
__device__ __forceinline__ float bf2f(unsigned int u) { return __uint_as_float(u << 16); }
__device__ __forceinline__ unsigned bfr_(float x) {
  unsigned u = __float_as_uint(x);
  return (u + 0x7fffu + ((u >> 16) & 1u)) >> 16;   // RNE f32->bf16
}

__device__ __forceinline__ void gl_lds16(const void* g, void* l) {
  __builtin_amdgcn_global_load_lds(
      (const __attribute__((address_space(1))) unsigned int*)g,
      (__attribute__((address_space(3))) unsigned int*)l,
      16, 0, 0);
}

// async global [64][512] -> LDS [64][516] ; follow with __syncthreads()
__device__ __forceinline__ void stage64(const float* src, float* TILE, int wv, int lane) {
  #pragma unroll
  for (int rr = 0; rr < 8; ++rr) {
    const int row = wv*8 + rr;
    const float* g = src + (size_t)row*DD + lane*4;
    gl_lds16(g,       TILE + row*516);
    gl_lds16(g + 256, TILE + row*516 + 256);
  }
}

// wave-column GRU dots: wave wv computes 3 gate-columns for dims w_id*8..+7
__device__ __forceinline__ void wave_dots(const float* TILE, const float* W, const float* bias,
                                          float* GH, int w_id, int wv, int lane) {
  const int c0 = wv*3, c1 = c0+1, c2 = c0+2;
  const int R0 = __builtin_amdgcn_readfirstlane(((c0>>3)<<9) + w_id*8 + (c0&7));
  const int R1 = __builtin_amdgcn_readfirstlane(((c1>>3)<<9) + w_id*8 + (c1&7));
  const int R2 = __builtin_amdgcn_readfirstlane(((c2>>3)<<9) + w_id*8 + (c2&7));
  const f4* w0 = (const f4*)(W + (size_t)R0*DD);
  const f4* w1 = (const f4*)(W + (size_t)R1*DD);
  const f4* w2 = (const f4*)(W + (size_t)R2*DD);
  const f4* hv4 = (const f4*)TILE + (size_t)lane*129;
  float a0=0.f, a1=0.f, a2=0.f;
  #pragma unroll 4
  for (int kq = 0; kq < 128; ++kq) {
    f4 h = hv4[kq];
    a0 += dot4(h, w0[kq]); a1 += dot4(h, w1[kq]); a2 += dot4(h, w2[kq]);
  }
  GH[c0*64 + lane] = a0 + bias[R0];
  GH[c1*64 + lane] = a1 + bias[R1];
  GH[c2*64 + lane] = a2 + bias[R2];
}

// ================= prologue: bf16 mirror + out bias init =================
template<int MB16>
__launch_bounds__(512, 1)
__global__ void k_prep(const float* __restrict__ mem, ushortT* __restrict__ mb16,
                       const float* __restrict__ b_tok, float* __restrict__ out) {
  const int gid = blockIdx.x*512 + threadIdx.x;
  if (MB16) {
    const size_t total = (size_t)BB*SS*DD;
    for (size_t i = (size_t)gid*8; i < total; i += (size_t)gridDim.x*512*8) {
      f4 a = *(const f4*)(mem + i);
      f4 b = *(const f4*)(mem + i + 4);
      u4v d;
      d.x = bfr_(a.x) | (bfr_(a.y) << 16);
      d.y = bfr_(a.z) | (bfr_(a.w) << 16);
      d.z = bfr_(b.x) | (bfr_(b.y) << 16);
      d.w = bfr_(b.z) | (bfr_(b.w) << 16);
      *(u4v*)(mb16 + i) = d;
    }
  }
  for (int i = gid; i < BB*TT*VV; i += gridDim.x*512)
    out[i] = b_tok[i % VV];
}

// ================= GRU layer 0 standalone (prologue) =================
__launch_bounds__(512, 1)
__global__ void k_gru0(const float* __restrict__ h0prev, const int* __restrict__ targets,
                       const float* __restrict__ W_ih0, const float* __restrict__ W_hh0,
                       const float* __restrict__ b_ih0, const float* __restrict__ b_hh0,
                       float* __restrict__ h0out, int tokcol) {
  __shared__ float SM[34560];
  float* const TILE = SM;
  float* const GHX  = SM + 33024;
  const int tid = threadIdx.x, bid = blockIdx.x;
  const int lane = tid & 63, wv = tid >> 6;
  stage64(h0prev, TILE, wv, lane);
  __syncthreads();
  wave_dots(TILE, W_hh0, b_hh0, GHX, bid, wv, lane);
  __syncthreads();
  const int dl = tid >> 6, bb = tid & 63, d = bid*8 + dl;
  const int tok = targets[bb*TT + tokcol];
  float gir = W_ih0[(size_t)d*VV + tok]          + b_ih0[d];
  float giz = W_ih0[(size_t)(DD + d)*VV + tok]   + b_ih0[DD + d];
  float gin = W_ih0[(size_t)(2*DD + d)*VV + tok] + b_ih0[2*DD + d];
  float ghr = GHX[(0*8 + dl)*64 + bb];
  float ghz = GHX[(1*8 + dl)*64 + bb];
  float ghn = GHX[(2*8 + dl)*64 + bb];
  float r_ = sigmoidf_(gir + ghr), z_ = sigmoidf_(giz + ghz);
  float n_ = tanhf(gin + r_*ghn);
  float h0old = TILE[bb*516 + d];
  h0out[(size_t)bb*DD + d] = (1.f - z_)*n_ + z_*h0old;
}

// ================= GRU layer 1 standalone (prologue) =================
__launch_bounds__(512, 1)
__global__ void k_gru1(const float* __restrict__ h1prev, const float* __restrict__ h0cur,
                       const float* __restrict__ W_hh1, const float* __restrict__ W_ih1,
                       const float* __restrict__ b_hh1, const float* __restrict__ b_ih1,
                       float* __restrict__ h1out) {
  __shared__ float SM[36096];
  float* const TILE = SM;
  float* const GH1  = SM + 33024;
  float* const GHX  = SM + 34560;
  const int tid = threadIdx.x, bid = blockIdx.x;
  const int lane = tid & 63, wv = tid >> 6;
  const int dl = tid >> 6, bb = tid & 63, d = bid*8 + dl;

  stage64(h1prev, TILE, wv, lane);
  __syncthreads();
  wave_dots(TILE, W_hh1, b_hh1, GH1, bid, wv, lane);
  float h1old = TILE[bb*516 + d];
  __syncthreads();
  stage64(h0cur, TILE, wv, lane);
  __syncthreads();
  wave_dots(TILE, W_ih1, b_ih1, GHX, bid, wv, lane);
  __syncthreads();
  float gir = GHX[(0*8 + dl)*64 + bb], ghr = GH1[(0*8 + dl)*64 + bb];
  float giz = GHX[(1*8 + dl)*64 + bb], ghz = GH1[(1*8 + dl)*64 + bb];
  float gin = GHX[(2*8 + dl)*64 + bb], ghn = GH1[(2*8 + dl)*64 + bb];
  float r_ = sigmoidf_(gir + ghr), z_ = sigmoidf_(giz + ghz);
  float n_ = tanhf(gin + r_*ghn);
  h1out[(size_t)bb*DD + d] = (1.f - z_)*n_ + z_*h1old;
}

// ================= out(t) standalone (epilogue) =================
__launch_bounds__(512, 1)
__global__ void k_outF(const float* __restrict__ h1cur, const float* __restrict__ cpart,
                       const float* __restrict__ ml, const float* __restrict__ W_out,
                       const float* __restrict__ W_tok, float* __restrict__ out, int t) {
  __shared__ float SM[33024 + 512 + 192];
  float* const TILE = SM;
  float* const AH   = SM + 33024;
  float* const EW   = SM + 33536;   // [64][3]
  const int tid = threadIdx.x, bid = blockIdx.x;
  const int lane = tid & 63, wv = tid >> 6;
  if (tid < 64) {
    float m0 = ml[(tid*2+0)*2], l0 = ml[(tid*2+0)*2+1];
    float m1 = ml[(tid*2+1)*2], l1 = ml[(tid*2+1)*2+1];
    float M = fmaxf(m0, m1);
    float e0 = __expf(m0 - M), e1 = __expf(m1 - M);
    float invL = 1.f / (e0*l0 + e1*l1);
    EW[tid*3+0] = e0; EW[tid*3+1] = e1; EW[tid*3+2] = invL;
  }
  __syncthreads();
  for (int it = tid; it < 64*128; it += 512) {
    const int row = it >> 7, c4 = (it & 127) * 4;
    const float* cp = cpart + (size_t)row*2*DD + c4;
    f4 p0 = *(const f4*)cp;
    f4 p1 = *(const f4*)(cp + DD);
    float e0 = EW[row*3+0], e1 = EW[row*3+1], invL = EW[row*3+2];
    f4 c;
    c.x = (e0*p0.x + e1*p1.x)*invL;
    c.y = (e0*p0.y + e1*p1.y)*invL;
    c.z = (e0*p0.z + e1*p1.z)*invL;
    c.w = (e0*p0.w + e1*p1.w)*invL;
    *(f4*)&TILE[row*516 + c4] = c;
  }
  __syncthreads();
  float acc = 0.f;
  const f4* hv4 = (const f4*)TILE + (size_t)lane*129;
  const int orow = __builtin_amdgcn_readfirstlane(bid*8 + wv);
  const f4* wo = (const f4*)(W_out + (size_t)orow*(2*DD));
  #pragma unroll 4
  for (int kq = 0; kq < 128; ++kq) acc += dot4(hv4[kq], wo[kq]);
  __syncthreads();
  stage64(h1cur, TILE, wv, lane);
  __syncthreads();
  #pragma unroll 4
  for (int kq = 0; kq < 128; ++kq) acc += dot4(hv4[kq], wo[128 + kq]);
  AH[wv*64 + lane] = tanhf(acc);
  __syncthreads();
  for (int v = wv; v < VV; v += 8) {
    const int vv = __builtin_amdgcn_readfirstlane(v);
    const float* wt = W_tok + (size_t)vv*DD + bid*8;
    float s8 = 0.f;
    #pragma unroll
    for (int q8 = 0; q8 < 8; ++q8) s8 += AH[q8*64 + lane] * wt[q8];
    atomicAdd(&out[((size_t)lane*TT + t)*VV + vv], s8);
  }
}

// ================= S(t): attn(t) [0..127] | out(t-1) [128..191] | gru1(t+1)+gru0(t+2) [192..255]
template<int MB16>
__launch_bounds__(512, 1)
__global__ void k_step(const float* __restrict__ h1cur,   // h1[t%3]
                       const float* __restrict__ h1prev,  // h1[(t-1)%3]
                       float*       __restrict__ h1nxt,   // h1[(t+1)%3]
                       const float* __restrict__ h0cur,   // h0[(t+1)&1] = h0(t+1)
                       float*       __restrict__ h0nxt,   // h0[t&1] <- h0(t+2)
                       const float* __restrict__ mem, const ushortT* __restrict__ mb16,
                       const int*   __restrict__ targets,
                       const float* __restrict__ W_ih0, const float* __restrict__ W_hh0,
                       const float* __restrict__ b_ih0, const float* __restrict__ b_hh0,
                       const float* __restrict__ W_hh1, const float* __restrict__ W_ih1,
                       const float* __restrict__ b_hh1, const float* __restrict__ b_ih1,
                       const float* __restrict__ W_out, const float* __restrict__ W_tok,
                       float*       __restrict__ cpartW, float* __restrict__ mlW,
                       const float* __restrict__ cpartR, const float* __restrict__ mlR,
                       float*       __restrict__ out, int t) {
  __shared__ float SM[36896];
  const int tid = threadIdx.x, bid = blockIdx.x;
  const int lane = tid & 63, wv = tid >> 6;

  if (bid < 128) {
    // ---------------- attention: batch b, 512-row chunk ch ----------------
    float* const CP  = SM + 32768;   // [8][512]
    float* const ML2 = SM + 36864;
    const int b  = bid >> 1;
    const int ch = bid & 1;
    const int seg = lane & 15;
    const int rr4 = lane >> 4;
    const float* qsrc = h1cur + (size_t)b*DD;
    f4 q4[8];
    if (MB16) {
      #pragma unroll
      for (int j = 0; j < 8; ++j) q4[j] = *(const f4*)(qsrc + seg*32 + j*4);
    } else {
      #pragma unroll
      for (int j = 0; j < 8; ++j) q4[j] = *(const f4*)(qsrc + seg*4 + j*64);
    }

    float m_run = -3e38f, l_run = 0.f;
    float cacc[8];
    #pragma unroll
    for (int j = 0; j < 8; ++j) cacc[j] = 0.f;

    if (MB16) {
      // 8 full tiles of 64 rows, 2x64KB double buffer
      const ushortT* msrcB = mb16 + ((size_t)b*SS + ch*512)*DD;
      char* const B0 = (char*)SM;
      char* const B1 = (char*)SM + 65536;
      int buf = 0;
      #pragma unroll
      for (int rr = 0; rr < 8; ++rr)
        gl_lds16(msrcB + (size_t)(wv*8 + rr)*DD + lane*8, B0 + (wv*8 + rr)*1024);
      __syncthreads();
      for (int tl = 0; tl < 8; ++tl) {
        if (tl + 1 < 8) {
          char* nb = buf ? B0 : B1;
          #pragma unroll
          for (int rr = 0; rr < 8; ++rr)
            gl_lds16(msrcB + (size_t)(tl+1)*64*DD + (size_t)(wv*8 + rr)*DD + lane*8,
                     nb + (wv*8 + rr)*1024);
        }
        const char* bb = buf ? B1 : B0;
        float sc[2];
        #pragma unroll
        for (int p = 0; p < 2; ++p) {
          const int r = wv*8 + rr4 + p*4;
          const u4v* rp = (const u4v*)(bb + r*1024 + seg*64);
          const float* qq = (const float*)q4;
          float s = 0.f;
          #pragma unroll
          for (int jj = 0; jj < 4; ++jj) {
            u4v u = rp[jj];
            s += __uint_as_float(u.x << 16)         * qq[jj*8+0]
               + __uint_as_float(u.x & 0xffff0000u) * qq[jj*8+1]
               + __uint_as_float(u.y << 16)         * qq[jj*8+2]
               + __uint_as_float(u.y & 0xffff0000u) * qq[jj*8+3]
               + __uint_as_float(u.z << 16)         * qq[jj*8+4]
               + __uint_as_float(u.z & 0xffff0000u) * qq[jj*8+5]
               + __uint_as_float(u.w << 16)         * qq[jj*8+6]
               + __uint_as_float(u.w & 0xffff0000u) * qq[jj*8+7];
          }
          sc[p] = s;
        }
        #pragma unroll
        for (int p = 0; p < 2; ++p) {
          sc[p] += __shfl_xor(sc[p], 1);
          sc[p] += __shfl_xor(sc[p], 2);
          sc[p] += __shfl_xor(sc[p], 4);
          sc[p] += __shfl_xor(sc[p], 8);
        }
        float s_[8];
        s_[0] = __shfl(sc[0], 0);  s_[1] = __shfl(sc[0], 16);
        s_[2] = __shfl(sc[0], 32); s_[3] = __shfl(sc[0], 48);
        s_[4] = __shfl(sc[1], 0);  s_[5] = __shfl(sc[1], 16);
        s_[6] = __shfl(sc[1], 32); s_[7] = __shfl(sc[1], 48);
        float m_tile = -3e38f;
        #pragma unroll
        for (int i = 0; i < 8; ++i) m_tile = fmaxf(m_tile, s_[i]);
        float m_new = fmaxf(m_run, m_tile);
        float esc   = __expf(m_run - m_new);
        float w[8]; float ls = 0.f;
        #pragma unroll
        for (int i = 0; i < 8; ++i) { w[i] = __expf(s_[i] - m_new); ls += w[i]; }
        l_run = l_run*esc + ls;
        m_run = m_new;
        const ushortT* bu = (const ushortT*)bb;
        #pragma unroll
        for (int j = 0; j < 8; ++j) {
          const int kk = j*64 + lane;
          float a = cacc[j]*esc;
          #pragma unroll
          for (int i = 0; i < 8; ++i) a += w[i] * bf2f(bu[(wv*8 + i)*512 + kk]);
          cacc[j] = a;
        }
        __syncthreads();
        buf ^= 1;
      }
    } else {
      // f32 fallback: 16 tiles of 32 rows
      const float* msrcF = mem + ((size_t)b*SS + ch*512)*DD;
      int buf = 0;
      #pragma unroll
      for (int rr = 0; rr < 4; ++rr) {
        const int row = wv*4 + rr;
        const float* g = msrcF + (size_t)row*DD + lane*4;
        gl_lds16(g, SM + row*DD); gl_lds16(g + 256, SM + row*DD + 256);
      }
      __syncthreads();
      for (int tl = 0; tl < 16; ++tl) {
        if (tl + 1 < 16) {
          #pragma unroll
          for (int rr = 0; rr < 4; ++rr) {
            const int row = wv*4 + rr;
            const float* g = msrcF + (size_t)(tl+1)*32*DD + (size_t)row*DD + lane*4;
            gl_lds16(g, SM + (buf^1)*16384 + row*DD);
            gl_lds16(g + 256, SM + (buf^1)*16384 + row*DD + 256);
          }
        }
        const float* bbuf = SM + buf*16384;
        const int r = wv*4 + rr4;
        float sc = 0.f;
        {
          const f4* rb = (const f4*)(bbuf + (size_t)r*DD);
          #pragma unroll
          for (int jj = 0; jj < 8; ++jj) sc += dot4(rb[seg + 16*jj], q4[jj]);
        }
        sc += __shfl_xor(sc, 1);
        sc += __shfl_xor(sc, 2);
        sc += __shfl_xor(sc, 4);
        sc += __shfl_xor(sc, 8);
        const int rb0 = wv*4;
        float s0 = __shfl(sc, 0), s1 = __shfl(sc, 16), s2 = __shfl(sc, 32), s3 = __shfl(sc, 48);
        float m_tile = fmaxf(fmaxf(s0, s1), fmaxf(s2, s3));
        float m_new  = fmaxf(m_run, m_tile);
        float esc    = __expf(m_run - m_new);
        float w0 = __expf(s0 - m_new), w1 = __expf(s1 - m_new);
        float w2 = __expf(s2 - m_new), w3 = __expf(s3 - m_new);
        l_run = l_run*esc + (w0 + w1) + (w2 + w3);
        m_run = m_new;
        #pragma unroll
        for (int j = 0; j < 8; ++j) {
          const int kk = j*64 + lane;
          float a = cacc[j]*esc;
          a += w0*bbuf[(rb0+0)*DD + kk];
          a += w1*bbuf[(rb0+1)*DD + kk];
          a += w2*bbuf[(rb0+2)*DD + kk];
          a += w3*bbuf[(rb0+3)*DD + kk];
          cacc[j] = a;
        }
        __syncthreads();
        buf ^= 1;
      }
    }

    // merge 8 per-wave partials
    #pragma unroll
    for (int j = 0; j < 8; ++j) CP[wv*DD + j*64 + lane] = cacc[j];
    if (lane == 0) { ML2[wv*2] = m_run; ML2[wv*2+1] = l_run; }
    __syncthreads();
    float M = -3e38f;
    #pragma unroll
    for (int w = 0; w < 8; ++w) M = fmaxf(M, ML2[w*2]);
    float lsum = 0.f, ck = 0.f;
    #pragma unroll
    for (int w = 0; w < 8; ++w) {
      float ew = __expf(ML2[w*2] - M);
      lsum += ew*ML2[w*2+1];
      ck   += ew*CP[w*DD + tid];
    }
    cpartW[((size_t)(b*2+ch))*DD + tid] = ck;
    if (tid == 0) {
      mlW[(b*2+ch)*2]     = M;
      mlW[(b*2+ch)*2 + 1] = lsum;
    }
  } else if (bid < 192) {
    // ---------------- out(t-1) ----------------
    if (t >= 1) {
      float* const TILE = SM;
      float* const AH   = SM + 33024;
      float* const EW   = SM + 33536;   // [64][3]
      const int obid = bid - 128;
      if (tid < 64) {
        float m0 = mlR[(tid*2+0)*2], l0 = mlR[(tid*2+0)*2+1];
        float m1 = mlR[(tid*2+1)*2], l1 = mlR[(tid*2+1)*2+1];
        float M = fmaxf(m0, m1);
        float e0 = __expf(m0 - M), e1 = __expf(m1 - M);
        float invL = 1.f / (e0*l0 + e1*l1);
        EW[tid*3+0] = e0; EW[tid*3+1] = e1; EW[tid*3+2] = invL;
      }
      __syncthreads();
      for (int it = tid; it < 64*128; it += 512) {
        const int row = it >> 7, c4 = (it & 127) * 4;
        const float* cp = cpartR + (size_t)row*2*DD + c4;
        f4 p0 = *(const f4*)cp;
        f4 p1 = *(const f4*)(cp + DD);
        float e0 = EW[row*3+0], e1 = EW[row*3+1], invL = EW[row*3+2];
        f4 c;
        c.x = (e0*p0.x + e1*p1.x)*invL;
        c.y = (e0*p0.y + e1*p1.y)*invL;
        c.z = (e0*p0.z + e1*p1.z)*invL;
        c.w = (e0*p0.w + e1*p1.w)*invL;
        *(f4*)&TILE[row*516 + c4] = c;
      }
      __syncthreads();
      float acc = 0.f;
      const f4* hv4 = (const f4*)TILE + (size_t)lane*129;
      const int orow = __builtin_amdgcn_readfirstlane(obid*8 + wv);
      const f4* wo = (const f4*)(W_out + (size_t)orow*(2*DD));
      #pragma unroll 4
      for (int kq = 0; kq < 128; ++kq) acc += dot4(hv4[kq], wo[kq]);
      __syncthreads();
      stage64(h1prev, TILE, wv, lane);
      __syncthreads();
      #pragma unroll 4
      for (int kq = 0; kq < 128; ++kq) acc += dot4(hv4[kq], wo[128 + kq]);
      AH[wv*64 + lane] = tanhf(acc);
      __syncthreads();
      for (int v = wv; v < VV; v += 8) {
        const int vv = __builtin_amdgcn_readfirstlane(v);
        const float* wt = W_tok + (size_t)vv*DD + obid*8;
        float s8 = 0.f;
        #pragma unroll
        for (int q8 = 0; q8 < 8; ++q8) s8 += AH[q8*64 + lane] * wt[q8];
        atomicAdd(&out[((size_t)lane*TT + (t-1))*VV + vv], s8);
      }
    }
  } else {
    // ---------------- gru1(t+1) then gru0(t+2) ----------------
    float* const TILE = SM;
    float* const GH1  = SM + 33024;
    float* const GHX  = SM + 34560;
    const int w_id = bid - 192;
    const int dl = tid >> 6, bb = tid & 63, d = w_id*8 + dl;

    if (t + 1 < TT) {
      stage64(h1cur, TILE, wv, lane);
      __syncthreads();
      wave_dots(TILE, W_hh1, b_hh1, GH1, w_id, wv, lane);
      float h1old = TILE[bb*516 + d];
      __syncthreads();
      stage64(h0cur, TILE, wv, lane);
      __syncthreads();
      wave_dots(TILE, W_ih1, b_ih1, GHX, w_id, wv, lane);
      __syncthreads();
      {
        float gir = GHX[(0*8 + dl)*64 + bb], ghr = GH1[(0*8 + dl)*64 + bb];
        float giz = GHX[(1*8 + dl)*64 + bb], ghz = GH1[(1*8 + dl)*64 + bb];
        float gin = GHX[(2*8 + dl)*64 + bb], ghn = GH1[(2*8 + dl)*64 + bb];
        float r_ = sigmoidf_(gir + ghr), z_ = sigmoidf_(giz + ghz);
        float n_ = tanhf(gin + r_*ghn);
        h1nxt[(size_t)bb*DD + d] = (1.f - z_)*n_ + z_*h1old;
      }
      if (t + 2 < TT) {
        __syncthreads();   // GHX reads done before overwrite
        // TILE still holds h0(t+1)
        wave_dots(TILE, W_hh0, b_hh0, GHX, w_id, wv, lane);
        __syncthreads();
        const int tok = targets[bb*TT + (t+1)];
        float gir = W_ih0[(size_t)d*VV + tok]          + b_ih0[d];
        float giz = W_ih0[(size_t)(DD + d)*VV + tok]   + b_ih0[DD + d];
        float gin = W_ih0[(size_t)(2*DD + d)*VV + tok] + b_ih0[2*DD + d];
        float ghr = GHX[(0*8 + dl)*64 + bb];
        float ghz = GHX[(1*8 + dl)*64 + bb];
        float ghn = GHX[(2*8 + dl)*64 + bb];
        float r_ = sigmoidf_(gir + ghr), z_ = sigmoidf_(giz + ghz);
        float n_ = tanhf(gin + r_*ghn);
        float h0old = TILE[bb*516 + d];
        h0nxt[(size_t)bb*DD + d] = (1.f - z_)*n_ + z_*h0old;
      }
    }
  }
}

extern "C" void kernel_launch(void* const* d_in, const int* in_sizes, int n_in,
                              void* d_out, int out_size, void* d_ws, size_t ws_size,
                              hipStream_t stream) {
  const float* h_init = (const float*)d_in[0];
  const int*   targets= (const int*)d_in[1];
  const float* mem    = (const float*)d_in[2];
  const float* W_ih0  = (const float*)d_in[3];
  const float* W_hh0  = (const float*)d_in[4];
  const float* b_ih0  = (const float*)d_in[5];
  const float* b_hh0  = (const float*)d_in[6];
  const float* W_ih1  = (const float*)d_in[7];
  const float* W_hh1  = (const float*)d_in[8];
  const float* b_ih1  = (const float*)d_in[9];
  const float* b_hh1  = (const float*)d_in[10];
  const float* W_out  = (const float*)d_in[11];
  const float* W_tok  = (const float*)d_in[12];
  const float* b_tok  = (const float*)d_in[13];
  float* out = (float*)d_out;
  float* ws  = (float*)d_ws;

  float* h0b   = ws + WS_H0;
  float* h1b   = ws + WS_H1;
  float* cpart = ws + WS_CP;    // [2][64*2][512]
  float* ml    = ws + WS_ML;    // [2][256]
  ushortT* mb16 = (ushortT*)(ws + WS_MB16);
  const bool useBf = (ws_size >= WS_NEED_BYTES);

  if (useBf)
    hipLaunchKernelGGL(k_prep<1>, dim3(1024), dim3(512), 0, stream, mem, mb16, b_tok, out);
  else
    hipLaunchKernelGGL(k_prep<0>, dim3(1024), dim3(512), 0, stream, mem, mb16, b_tok, out);

  // prologue: h0(0)->slot0(temp), h1(0)->h1 slot0, h0(1)->h0 slot1
  hipLaunchKernelGGL(k_gru0, dim3(64), dim3(512), 0, stream,
                     h_init, targets, W_ih0, W_hh0, b_ih0, b_hh0, h0b, 0);
  hipLaunchKernelGGL(k_gru1, dim3(64), dim3(512), 0, stream,
                     h_init + BBDD, h0b, W_hh1, W_ih1, b_hh1, b_ih1, h1b);
  hipLaunchKernelGGL(k_gru0, dim3(64), dim3(512), 0, stream,
                     h0b, targets, W_ih0, W_hh0, b_ih0, b_hh0, h0b + BBDD, 0);

  for (int t = 0; t < TT; ++t) {
    const float* h1cur  = h1b + (size_t)(t % 3)*BBDD;
    const float* h1prev = h1b + (size_t)((t + 2) % 3)*BBDD;
    float*       h1nxt  = h1b + (size_t)((t + 1) % 3)*BBDD;
    const float* h0cur  = h0b + (size_t)((t + 1) & 1)*BBDD;
    float*       h0nxt  = h0b + (size_t)(t & 1)*BBDD;
    float*       cpW    = cpart + (size_t)(t & 1)*2*BBDD;
    float*       mlW    = ml + (size_t)(t & 1)*256;
    const float* cpR    = cpart + (size_t)((t + 1) & 1)*2*BBDD;
    const float* mlR    = ml + (size_t)((t + 1) & 1)*256;

    if (useBf)
      hipLaunchKernelGGL(k_step<1>, dim3(256), dim3(512), 0, stream,
                         h1cur, h1prev, h1nxt, h0cur, h0nxt, mem, mb16, targets,
                         W_ih0, W_hh0, b_ih0, b_hh0, W_hh1, W_ih1, b_hh1, b_ih1,
                         W_out, W_tok, cpW, mlW, cpR, mlR, out, t);
    else
      hipLaunchKernelGGL(k_step<0>, dim3(256), dim3(512), 0, stream,
                         h1cur, h1prev, h1nxt, h0cur, h0nxt, mem, mb16, targets,
                         W_ih0, W_hh0, b_ih0, b_hh0, W_hh1, W_ih1, b_hh1, b_ih1,
                         W_out, W_tok, cpW, mlW, cpR, mlR, out, t);
  }

  // epilogue: out(199)
  hipLaunchKernelGGL(k_outF, dim3(64), dim3(512), 0, stream,
                     h1b + (size_t)(199 % 3)*BBDD, cpart + (size_t)(199 & 1)*2*BBDD,
                     ml + (size_t)(199 & 1)*256, W_out, W_tok, out, 199);
}

// Round 9
// 5579.313 us; speedup vs baseline: 5.6395x; 2.7200x over previous
//
#include <hip/hip_runtime.h>

#define TT 200
#define SS 1024
#define DD 512
#define VV 30
#define BB 64
#define BBDD (BB*DD)              // 32768

// ---- ws float offsets ----
#define WS_H0   0                         // [2][64][512]
#define WS_GI   (2*BBDD)                  // [2][1536][64]
#define WS_H1A  (WS_GI + 2*1536*64)       // [200][64][512]
#define WS_CALL (WS_H1A + 200*BBDD)       // [200][64][512]
// end = 65536 + 196608 + 2*6553600 = 13.37M floats ~= 53.5 MB

typedef __attribute__((ext_vector_type(4))) float f4;

__device__ __forceinline__ float dot4(f4 a, f4 b) {
  return a.x*b.x + a.y*b.y + a.z*b.z + a.w*b.w;
}
__device__ __forceinline__ float sigmoidf_(float x) { return 1.f/(1.f + __expf(-x)); }

__device__ __forceinline__ void gl_lds16(const void* g, void* l) {
  __builtin_amdgcn_global_load_lds(
      (const __attribute__((address_space(1))) unsigned int*)g,
      (__attribute__((address_space(3))) unsigned int*)l,
      16, 0, 0);
}

// async global [64][512] -> LDS [64][516] ; follow with __syncthreads()
__device__ __forceinline__ void stage64(const float* src, float* TILE, int wv, int lane) {
  #pragma unroll
  for (int rr = 0; rr < 8; ++rr) {
    const int row = wv*8 + rr;
    const float* g = src + (size_t)row*DD + lane*4;
    gl_lds16(g,       TILE + row*516);
    gl_lds16(g + 256, TILE + row*516 + 256);
  }
}

// wave-column GRU dots into LOCAL gate buffer GH[24][64]
__device__ __forceinline__ void wave_dots(const float* TILE, const float* W, const float* bias,
                                          float* GH, int w_id, int wv, int lane) {
  const int c0 = wv*3, c1 = c0+1, c2 = c0+2;
  const int R0 = __builtin_amdgcn_readfirstlane(((c0>>3)<<9) + w_id*8 + (c0&7));
  const int R1 = __builtin_amdgcn_readfirstlane(((c1>>3)<<9) + w_id*8 + (c1&7));
  const int R2 = __builtin_amdgcn_readfirstlane(((c2>>3)<<9) + w_id*8 + (c2&7));
  const f4* w0 = (const f4*)(W + (size_t)R0*DD);
  const f4* w1 = (const f4*)(W + (size_t)R1*DD);
  const f4* w2 = (const f4*)(W + (size_t)R2*DD);
  const f4* hv4 = (const f4*)TILE + (size_t)lane*129;
  float a0=0.f, a1=0.f, a2=0.f;
  #pragma unroll 4
  for (int kq = 0; kq < 128; ++kq) {
    f4 h = hv4[kq];
    a0 += dot4(h, w0[kq]); a1 += dot4(h, w1[kq]); a2 += dot4(h, w2[kq]);
  }
  GH[c0*64 + lane] = a0 + bias[R0];
  GH[c1*64 + lane] = a1 + bias[R1];
  GH[c2*64 + lane] = a2 + bias[R2];
}

// wave-column dots writing GLOBAL gi buffer gi[(g*512+d)*64 + lane], bias included
__device__ __forceinline__ void wave_dots_g(const float* TILE, const float* W, const float* bias,
                                            float* gi, int w_id, int wv, int lane) {
  const int c0 = wv*3, c1 = c0+1, c2 = c0+2;
  const int R0 = __builtin_amdgcn_readfirstlane(((c0>>3)<<9) + w_id*8 + (c0&7));
  const int R1 = __builtin_amdgcn_readfirstlane(((c1>>3)<<9) + w_id*8 + (c1&7));
  const int R2 = __builtin_amdgcn_readfirstlane(((c2>>3)<<9) + w_id*8 + (c2&7));
  const f4* w0 = (const f4*)(W + (size_t)R0*DD);
  const f4* w1 = (const f4*)(W + (size_t)R1*DD);
  const f4* w2 = (const f4*)(W + (size_t)R2*DD);
  const f4* hv4 = (const f4*)TILE + (size_t)lane*129;
  float a0=0.f, a1=0.f, a2=0.f;
  #pragma unroll 4
  for (int kq = 0; kq < 128; ++kq) {
    f4 h = hv4[kq];
    a0 += dot4(h, w0[kq]); a1 += dot4(h, w1[kq]); a2 += dot4(h, w2[kq]);
  }
  gi[(size_t)R0*64 + lane] = a0 + bias[R0];
  gi[(size_t)R1*64 + lane] = a1 + bias[R1];
  gi[(size_t)R2*64 + lane] = a2 + bias[R2];
}

// ================= prologue 1: h0(0) =================
__launch_bounds__(512, 1)
__global__ void k_gru0(const float* __restrict__ h0prev, const int* __restrict__ targets,
                       const float* __restrict__ W_ih0, const float* __restrict__ W_hh0,
                       const float* __restrict__ b_ih0, const float* __restrict__ b_hh0,
                       float* __restrict__ h0out, int tokcol) {
  __shared__ float SM[34560];
  float* const TILE = SM;
  float* const GHX  = SM + 33024;
  const int tid = threadIdx.x, bid = blockIdx.x;
  const int lane = tid & 63, wv = tid >> 6;
  stage64(h0prev, TILE, wv, lane);
  __syncthreads();
  wave_dots(TILE, W_hh0, b_hh0, GHX, bid, wv, lane);
  __syncthreads();
  const int dl = tid >> 6, bb = tid & 63, d = bid*8 + dl;
  const int tok = targets[bb*TT + tokcol];
  float gir = W_ih0[(size_t)d*VV + tok]          + b_ih0[d];
  float giz = W_ih0[(size_t)(DD + d)*VV + tok]   + b_ih0[DD + d];
  float gin = W_ih0[(size_t)(2*DD + d)*VV + tok] + b_ih0[2*DD + d];
  float r_ = sigmoidf_(gir + GHX[(0*8 + dl)*64 + bb]);
  float z_ = sigmoidf_(giz + GHX[(1*8 + dl)*64 + bb]);
  float n_ = tanhf(gin + r_*GHX[(2*8 + dl)*64 + bb]);
  float h0old = TILE[bb*516 + d];
  h0out[(size_t)bb*DD + d] = (1.f - z_)*n_ + z_*h0old;
}

// ================= prologue 2: h0(1) [0..63] | GI1(0) [64..127] =================
__launch_bounds__(512, 1)
__global__ void k_pro1(const float* __restrict__ h0buf0, const int* __restrict__ targets,
                       const float* __restrict__ W_ih0, const float* __restrict__ W_hh0,
                       const float* __restrict__ b_ih0, const float* __restrict__ b_hh0,
                       const float* __restrict__ W_ih1, const float* __restrict__ b_ih1,
                       float* __restrict__ h0buf1, float* __restrict__ gibuf0) {
  __shared__ float SM[34560];
  float* const TILE = SM;
  float* const GHX  = SM + 33024;
  const int tid = threadIdx.x, bid = blockIdx.x;
  const int lane = tid & 63, wv = tid >> 6;
  stage64(h0buf0, TILE, wv, lane);
  __syncthreads();
  if (bid < 64) {
    wave_dots(TILE, W_hh0, b_hh0, GHX, bid, wv, lane);
    __syncthreads();
    const int dl = tid >> 6, bb = tid & 63, d = bid*8 + dl;
    const int tok = targets[bb*TT + 0];
    float gir = W_ih0[(size_t)d*VV + tok]          + b_ih0[d];
    float giz = W_ih0[(size_t)(DD + d)*VV + tok]   + b_ih0[DD + d];
    float gin = W_ih0[(size_t)(2*DD + d)*VV + tok] + b_ih0[2*DD + d];
    float r_ = sigmoidf_(gir + GHX[(0*8 + dl)*64 + bb]);
    float z_ = sigmoidf_(giz + GHX[(1*8 + dl)*64 + bb]);
    float n_ = tanhf(gin + r_*GHX[(2*8 + dl)*64 + bb]);
    float h0old = TILE[bb*516 + d];
    h0buf1[(size_t)bb*DD + d] = (1.f - z_)*n_ + z_*h0old;
  } else {
    wave_dots_g(TILE, W_ih1, b_ih1, gibuf0, bid - 64, wv, lane);
  }
}

// ======= chain: h0(t+2) [0..63] | h1(t) [64..127] | GI1(t+1) [128..191] =======
__launch_bounds__(512, 1)
__global__ void k_chain(const float* __restrict__ h0rd,   // h0(t+1)
                        float*       __restrict__ h0wr,   // <- h0(t+2)
                        const float* __restrict__ h1src,  // h1(t-1)
                        float*       __restrict__ h1dst,  // <- h1(t) (in h1all)
                        const float* __restrict__ gird,   // GI1(t)
                        float*       __restrict__ giwr,   // <- GI1(t+1)
                        const int*   __restrict__ targets,
                        const float* __restrict__ W_ih0, const float* __restrict__ W_hh0,
                        const float* __restrict__ b_ih0, const float* __restrict__ b_hh0,
                        const float* __restrict__ W_hh1, const float* __restrict__ b_hh1,
                        const float* __restrict__ W_ih1, const float* __restrict__ b_ih1,
                        int t) {
  __shared__ float SM[34560];
  float* const TILE = SM;
  float* const GHX  = SM + 33024;
  const int tid = threadIdx.x, bid = blockIdx.x;
  const int lane = tid & 63, wv = tid >> 6;
  const int dl = tid >> 6, bb = tid & 63;

  if (bid < 64) {
    if (t <= 197) {
      const int d = bid*8 + dl;
      stage64(h0rd, TILE, wv, lane);
      __syncthreads();
      wave_dots(TILE, W_hh0, b_hh0, GHX, bid, wv, lane);
      __syncthreads();
      const int tok = targets[bb*TT + (t + 1)];
      float gir = W_ih0[(size_t)d*VV + tok]          + b_ih0[d];
      float giz = W_ih0[(size_t)(DD + d)*VV + tok]   + b_ih0[DD + d];
      float gin = W_ih0[(size_t)(2*DD + d)*VV + tok] + b_ih0[2*DD + d];
      float r_ = sigmoidf_(gir + GHX[(0*8 + dl)*64 + bb]);
      float z_ = sigmoidf_(giz + GHX[(1*8 + dl)*64 + bb]);
      float n_ = tanhf(gin + r_*GHX[(2*8 + dl)*64 + bb]);
      float h0old = TILE[bb*516 + d];
      h0wr[(size_t)bb*DD + d] = (1.f - z_)*n_ + z_*h0old;
    }
  } else if (bid < 128) {
    const int w_id = bid - 64;
    const int d = w_id*8 + dl;
    stage64(h1src, TILE, wv, lane);
    __syncthreads();
    wave_dots(TILE, W_hh1, b_hh1, GHX, w_id, wv, lane);
    float h1old = TILE[bb*516 + d];
    __syncthreads();
    float gir = gird[(size_t)(0*DD + d)*64 + bb];
    float giz = gird[(size_t)(1*DD + d)*64 + bb];
    float gin = gird[(size_t)(2*DD + d)*64 + bb];
    float r_ = sigmoidf_(gir + GHX[(0*8 + dl)*64 + bb]);
    float z_ = sigmoidf_(giz + GHX[(1*8 + dl)*64 + bb]);
    float n_ = tanhf(gin + r_*GHX[(2*8 + dl)*64 + bb]);
    h1dst[(size_t)bb*DD + d] = (1.f - z_)*n_ + z_*h1old;
  } else {
    if (t <= 198) {
      stage64(h0rd, TILE, wv, lane);
      __syncthreads();
      wave_dots_g(TILE, W_ih1, b_ih1, giwr, bid - 128, wv, lane);
    }
  }
}

// ======= batched attention: block = (b, 40-t tile); mem streamed once per tile =======
__launch_bounds__(512, 1)
__global__ void k_attn_all(const float* __restrict__ h1a, const float* __restrict__ mem,
                           float* __restrict__ call) {
  __shared__ float SM[2*16*520 + 8*80];   // MT dbuf + SCR[8][5][16]
  float* const SCR = SM + 2*16*520;
  const int tid = threadIdx.x, bid = blockIdx.x;
  const int lane = tid & 63, wv = tid >> 6;
  const int b  = bid / 5;
  const int tt = bid % 5;
  const int r0 = wv*5;

  // Q rows in registers
  f4 qa[5], qb[5];
  #pragma unroll
  for (int r = 0; r < 5; ++r) {
    const size_t base = ((size_t)(tt*40 + r0 + r)*BB + b)*DD + lane*8;
    qa[r] = *(const f4*)(h1a + base);
    qb[r] = *(const f4*)(h1a + base + 4);
  }
  f4 aa[5], ab[5];
  float m[5], l[5];
  #pragma unroll
  for (int r = 0; r < 5; ++r) { aa[r] = (f4)0.f; ab[r] = (f4)0.f; m[r] = -3e38f; l[r] = 0.f; }

  const float* msrc = mem + (size_t)b*SS*DD;
  // stage tile 0 (16 rows; wave stages rows wv*2, wv*2+1)
  #pragma unroll
  for (int rr = 0; rr < 2; ++rr) {
    const int row = wv*2 + rr;
    const float* g = msrc + (size_t)row*DD + lane*4;
    gl_lds16(g,       SM + row*520);
    gl_lds16(g + 256, SM + row*520 + 256);
  }
  __syncthreads();

  int buf = 0;
  for (int tl = 0; tl < 64; ++tl) {
    if (tl + 1 < 64) {
      float* nb = SM + (buf^1)*16*520;
      #pragma unroll
      for (int rr = 0; rr < 2; ++rr) {
        const int row = wv*2 + rr;
        const float* g = msrc + (size_t)(tl+1)*16*DD + (size_t)row*DD + lane*4;
        gl_lds16(g,       nb + row*520);
        gl_lds16(g + 256, nb + row*520 + 256);
      }
    }
    const float* mt = SM + buf*16*520;

    // pass 1: scores -> SCR (per-wave region)
    for (int s = 0; s < 16; ++s) {
      const f4 ma = *(const f4*)&mt[s*520 + lane*8];
      const f4 mb = *(const f4*)&mt[s*520 + lane*8 + 4];
      float p[5];
      #pragma unroll
      for (int r = 0; r < 5; ++r) p[r] = dot4(ma, qa[r]) + dot4(mb, qb[r]);
      #pragma unroll
      for (int off = 32; off; off >>= 1) {
        #pragma unroll
        for (int r = 0; r < 5; ++r) p[r] += __shfl_xor(p[r], off);
      }
      if (lane == 0) {
        #pragma unroll
        for (int r = 0; r < 5; ++r) SCR[wv*80 + r*16 + s] = p[r];
      }
    }
    // pass 2: per-row tile max, rescale, accumulate
    float mnew[5], esc[5];
    #pragma unroll
    for (int r = 0; r < 5; ++r) {
      float mx = -3e38f;
      #pragma unroll
      for (int s = 0; s < 16; ++s) mx = fmaxf(mx, SCR[wv*80 + r*16 + s]);
      mnew[r] = fmaxf(m[r], mx);
      esc[r]  = __expf(m[r] - mnew[r]);
      aa[r] *= esc[r]; ab[r] *= esc[r]; l[r] *= esc[r];
      m[r] = mnew[r];
    }
    for (int s = 0; s < 16; ++s) {
      const f4 ma = *(const f4*)&mt[s*520 + lane*8];
      const f4 mb = *(const f4*)&mt[s*520 + lane*8 + 4];
      #pragma unroll
      for (int r = 0; r < 5; ++r) {
        const float w = __expf(SCR[wv*80 + r*16 + s] - m[r]);
        aa[r] += w*ma; ab[r] += w*mb; l[r] += w;
      }
    }
    __syncthreads();
    buf ^= 1;
  }

  #pragma unroll
  for (int r = 0; r < 5; ++r) {
    const float inv = 1.f / l[r];
    const size_t base = ((size_t)(tt*40 + r0 + r)*BB + b)*DD + lane*8;
    *(f4*)(call + base)     = aa[r]*inv;
    *(f4*)(call + base + 4) = ab[r]*inv;
  }
}

// ======= output projection + logits: block = 64 (t,b) rows =======
__launch_bounds__(512, 1)
__global__ void k_outproj(const float* __restrict__ call, const float* __restrict__ h1a,
                          const float* __restrict__ W_out, const float* __restrict__ W_tok,
                          const float* __restrict__ b_tok, float* __restrict__ out) {
  __shared__ float SM[4352 + 33024];       // XR[64][68] + AH[64][516]
  float* const XR = SM;
  float* const AH = SM + 4352;
  const int tid = threadIdx.x, bid = blockIdx.x;
  const int lane = tid & 63, wv = tid >> 6;
  const int rowbase = bid * 64;

  float acc[8][8];
  #pragma unroll
  for (int r = 0; r < 8; ++r)
    #pragma unroll
    for (int j = 0; j < 8; ++j) acc[r][j] = 0.f;

  for (int kc = 0; kc < 16; ++kc) {
    __syncthreads();
    // stage X chunk [64 rows][64 k] (X = [c | q])
    {
      const int row = tid >> 3;
      const int kp  = (tid & 7) * 8;
      const int k   = kc*64 + kp;
      const size_t grow = (size_t)(rowbase + row) * DD;
      const float* src = (k < DD) ? (call + grow + k) : (h1a + grow + (k - DD));
      f4 v0 = *(const f4*)src;
      f4 v1 = *(const f4*)(src + 4);
      *(f4*)&XR[row*68 + kp]     = v0;
      *(f4*)&XR[row*68 + kp + 4] = v1;
    }
    __syncthreads();
    // compute: thread = rows wv*8..+7 x cols lane*8..+7
    for (int k4 = 0; k4 < 16; ++k4) {
      f4 w4[8];
      #pragma unroll
      for (int j = 0; j < 8; ++j)
        w4[j] = *(const f4*)&W_out[(size_t)(lane*8 + j)*(2*DD) + kc*64 + k4*4];
      #pragma unroll
      for (int r = 0; r < 8; ++r) {
        const f4 x4 = *(const f4*)&XR[(wv*8 + r)*68 + k4*4];
        #pragma unroll
        for (int j = 0; j < 8; ++j) acc[r][j] += dot4(x4, w4[j]);
      }
    }
  }
  // tanh -> AH
  #pragma unroll
  for (int r = 0; r < 8; ++r) {
    f4 t0, t1;
    t0.x = tanhf(acc[r][0]); t0.y = tanhf(acc[r][1]); t0.z = tanhf(acc[r][2]); t0.w = tanhf(acc[r][3]);
    t1.x = tanhf(acc[r][4]); t1.y = tanhf(acc[r][5]); t1.z = tanhf(acc[r][6]); t1.w = tanhf(acc[r][7]);
    *(f4*)&AH[(wv*8 + r)*516 + lane*8]     = t0;
    *(f4*)&AH[(wv*8 + r)*516 + lane*8 + 4] = t1;
  }
  __syncthreads();
  // logits: 64 rows x 30 v
  const int v = tid & 31;
  const int rq = tid >> 5;
  if (v < VV) {
    for (int it = 0; it < 4; ++it) {
      const int row = rq + it*16;
      float s = 0.f;
      const f4* ar = (const f4*)&AH[row*516];
      const f4* wt = (const f4*)&W_tok[(size_t)v*DD];
      #pragma unroll 4
      for (int k4 = 0; k4 < 128; ++k4) s += dot4(ar[k4], wt[k4]);
      const int gr = rowbase + row;
      const int t = gr >> 6, b = gr & 63;
      out[((size_t)b*TT + t)*VV + v] = s + b_tok[v];
    }
  }
}

extern "C" void kernel_launch(void* const* d_in, const int* in_sizes, int n_in,
                              void* d_out, int out_size, void* d_ws, size_t ws_size,
                              hipStream_t stream) {
  const float* h_init = (const float*)d_in[0];
  const int*   targets= (const int*)d_in[1];
  const float* mem    = (const float*)d_in[2];
  const float* W_ih0  = (const float*)d_in[3];
  const float* W_hh0  = (const float*)d_in[4];
  const float* b_ih0  = (const float*)d_in[5];
  const float* b_hh0  = (const float*)d_in[6];
  const float* W_ih1  = (const float*)d_in[7];
  const float* W_hh1  = (const float*)d_in[8];
  const float* b_ih1  = (const float*)d_in[9];
  const float* b_hh1  = (const float*)d_in[10];
  const float* W_out  = (const float*)d_in[11];
  const float* W_tok  = (const float*)d_in[12];
  const float* b_tok  = (const float*)d_in[13];
  float* out = (float*)d_out;
  float* ws  = (float*)d_ws;

  float* h0b  = ws + WS_H0;                  // [2][64][512]
  float* gib  = ws + WS_GI;                  // [2][1536*64]
  float* h1a  = ws + WS_H1A;                 // [200][64][512]
  float* call = ws + WS_CALL;                // [200][64][512]

  // prologue: h0(0); then {h0(1) | GI1(0)}
  hipLaunchKernelGGL(k_gru0, dim3(64), dim3(512), 0, stream,
                     h_init, targets, W_ih0, W_hh0, b_ih0, b_hh0, h0b, 0);
  hipLaunchKernelGGL(k_pro1, dim3(128), dim3(512), 0, stream,
                     h0b, targets, W_ih0, W_hh0, b_ih0, b_hh0,
                     W_ih1, b_ih1, h0b + BBDD, gib);

  // chain: L(t) -> h1(t), h0(t+2), GI1(t+1)
  for (int t = 0; t < TT; ++t) {
    const float* h0rd = h0b + (size_t)((t + 1) & 1)*BBDD;
    float*       h0wr = h0b + (size_t)(t & 1)*BBDD;
    const float* h1src= (t == 0) ? (h_init + BBDD) : (h1a + (size_t)(t - 1)*BBDD);
    float*       h1dst= h1a + (size_t)t*BBDD;
    const float* gird = gib + (size_t)(t & 1)*(1536*64);
    float*       giwr = gib + (size_t)((t + 1) & 1)*(1536*64);
    hipLaunchKernelGGL(k_chain, dim3(192), dim3(512), 0, stream,
                       h0rd, h0wr, h1src, h1dst, gird, giwr, targets,
                       W_ih0, W_hh0, b_ih0, b_hh0, W_hh1, b_hh1, W_ih1, b_ih1, t);
  }

  // batched attention over all 200 steps (mem streamed 5x total)
  hipLaunchKernelGGL(k_attn_all, dim3(320), dim3(512), 0, stream, h1a, mem, call);

  // output projection + logits (direct stores, full coverage)
  hipLaunchKernelGGL(k_outproj, dim3(200), dim3(512), 0, stream,
                     call, h1a, W_out, W_tok, b_tok, out);
}